// Round 19
// baseline (961.129 us; speedup 1.0000x reference)
//
#include <hip/hip_runtime.h>
#include <math.h>

#define NN 2000
#define T1C 12
#define BBC 2
#define HHC 128
#define NHD 4
#define DFD 32
#define LLC 4
#define DEC 16
#define TEC 16
#define CINC 12
#define E0C 32000
#define EEC 34000
#define BTC 24
#define MROWS 48000
#define EPSLN 1e-5f
#define SCALEQK 0.17677669529663687f

typedef __attribute__((ext_vector_type(8))) short short8;
typedef __attribute__((ext_vector_type(4))) float f32x4;

// ---------------- helpers ----------------

__device__ __forceinline__ unsigned short f2b(float f)
{
    unsigned u = __float_as_uint(f);
    return (unsigned short)((u + 0x7FFF + ((u >> 16) & 1)) >> 16);
}

__device__ __forceinline__ float b2f(unsigned short h)
{
    return __uint_as_float(((unsigned)h) << 16);
}

// ---------------- weight conversions ----------------

__global__ __launch_bounds__(256) void convwp_k(const float* __restrict__ W, unsigned short* __restrict__ Bp,
                                                int LN_, int K, int N, int noff, int Ntot)
{
    int idx = blockIdx.x * blockDim.x + threadIdx.x;
    int total = LN_ * K * N;
    if (idx >= total) return;
    int l = idx / (K * N);
    int r = idx - l * (K * N);
    int k = r / N;
    int n = r - k * N + noff;
    size_t off = (size_t)l * K * Ntot +
                 ((size_t)((n >> 4) * (K >> 5) + (k >> 5)) << 9) +
                 (((k >> 3) & 3) << 7) + ((n & 15) << 3) + (k & 7);
    Bp[off] = f2b(W[idx]);
}

// W12P[l][c][k] (c=0..127 output col, k=0..127) = e1w[l][c<64? k : k+128][c&63]
__global__ __launch_bounds__(256) void convw12_k(const float* __restrict__ e1w, unsigned short* __restrict__ W12P)
{
    int idx = blockIdx.x * blockDim.x + threadIdx.x;
    if (idx >= LLC * 128 * 128) return;
    int l = idx >> 14;
    int r = idx & 16383;
    int c = r >> 7, k = r & 127;
    int sk = (c < 64) ? k : k + 128;
    int sc = c & 63;
    W12P[idx] = f2b(e1w[((size_t)l * 272 + sk) * 64 + sc]);
}

// WoT[l][c][k] = Wo[l][k][c]
__global__ __launch_bounds__(256) void convwoT_k(const float* __restrict__ Wo, unsigned short* __restrict__ WoT)
{
    int idx = blockIdx.x * blockDim.x + threadIdx.x;
    if (idx >= LLC * 128 * 128) return;
    int l = idx >> 14;
    int r = idx & 16383;
    int c = r >> 7, k = r & 127;
    WoT[idx] = f2b(Wo[((size_t)l * 128 + k) * 128 + c]);
}

// ---------------- gemm2: 128x128-tile LDS-staged MFMA GEMM ----------------
// EPI: 0=none 1=gelu 2=res-add 3=res+LN 5=res+LN + transpose back to [B,N,T1,H]
// QKV=1 (EPI==5 only): after epilogue, run the next layer's temporal-QKV GEMM
// (K=128, N=384) from the staged bf16 output, writing outQ at transposed rows.

template<int K, int EPI, int OUTM, int QKV>
__global__ __launch_bounds__(256) void gemm2_k(
    const unsigned short* __restrict__ A, const unsigned short* __restrict__ Bp,
    const float* __restrict__ bias, float* __restrict__ C, unsigned short* __restrict__ Cb,
    const float* __restrict__ res, const float* __restrict__ gam, const float* __restrict__ bet,
    const float* __restrict__ trep,
    const unsigned short* __restrict__ Wqkv, const float* __restrict__ abq,
    unsigned short* __restrict__ outQ,
    int M, int Ntot)
{
    __shared__ unsigned short A_s[128 * 16 * 8];
    __shared__ float red2[2][128][2];
    __shared__ int rowp_s[128];

    int tid = threadIdx.x;
    int w = tid >> 6, lane = tid & 63;
    int wr = w & 1, wc = w >> 1;
    int quad = lane >> 4, lr = lane & 15;

    const unsigned short* abase = A + (size_t)blockIdx.x * 128 * K;
    int ntg0 = blockIdx.y * 8 + wc * 4;

    f32x4 acc[4][4];
#pragma unroll
    for (int mt = 0; mt < 4; mt++)
#pragma unroll
        for (int nt = 0; nt < 4; nt++) acc[mt][nt] = (f32x4){0.f, 0.f, 0.f, 0.f};

#pragma unroll
    for (int kb = 0; kb < K; kb += 128) {
        if (kb) __syncthreads();
#pragma unroll
        for (int j = 0; j < 8; j++) {
            int s = j * 256 + tid;
            int row = s >> 4, ks = s & 15;
            int ko = ks ^ (row & 15);
            uint4 d = *(const uint4*)(abase + (size_t)row * K + kb + ko * 8);
            *(uint4*)(A_s + s * 8) = d;
        }
        __syncthreads();
#pragma unroll
        for (int k0 = 0; k0 < 128; k0 += 32) {
            short8 af[4], bf[4];
#pragma unroll
            for (int mt = 0; mt < 4; mt++) {
                int row_l = wr * 64 + mt * 16 + lr;
                int koct = (k0 >> 3) + quad;
                int slot = row_l * 16 + (koct ^ lr);
                af[mt] = *(const short8*)(A_s + slot * 8);
            }
#pragma unroll
            for (int nt = 0; nt < 4; nt++) {
                size_t off = ((size_t)(ntg0 + nt) * (K >> 5) + ((kb + k0) >> 5)) * 512 + lane * 8;
                bf[nt] = *(const short8*)(Bp + off);
            }
#pragma unroll
            for (int mt = 0; mt < 4; mt++)
#pragma unroll
                for (int nt = 0; nt < 4; nt++)
                    acc[mt][nt] = __builtin_amdgcn_mfma_f32_16x16x32_bf16(af[mt], bf[nt], acc[mt][nt], 0, 0, 0);
        }
    }

    int rbase = blockIdx.x * 128 + wr * 64;
    int cbase = blockIdx.y * 128 + wc * 64;

    if constexpr (EPI != 3 && EPI != 5) {
#pragma unroll
        for (int mt = 0; mt < 4; mt++) {
#pragma unroll
            for (int nt = 0; nt < 4; nt++) {
                int colg = cbase + nt * 16 + lr;
                float bv = bias ? bias[colg] : 0.f;
#pragma unroll
                for (int i = 0; i < 4; i++) {
                    int row = rbase + mt * 16 + quad * 4 + i;
                    float x = acc[mt][nt][i] + bv;
                    if constexpr (EPI == 1) x = 0.5f * x * (1.f + erff(x * 0.70710678118654752f));
                    if constexpr (EPI == 2) x = res[(size_t)row * Ntot + colg] + x;
                    if constexpr (OUTM & 1) C[(size_t)row * Ntot + colg] = x;
                    if constexpr (OUTM & 2) Cb[(size_t)row * Ntot + colg] = f2b(x);
                }
            }
        }
    } else {
        float s[4][4], s2l[4][4];
#pragma unroll
        for (int mt = 0; mt < 4; mt++)
#pragma unroll
            for (int i = 0; i < 4; i++) { s[mt][i] = 0.f; s2l[mt][i] = 0.f; }
#pragma unroll
        for (int mt = 0; mt < 4; mt++) {
#pragma unroll
            for (int nt = 0; nt < 4; nt++) {
                int colg = cbase + nt * 16 + lr;
                float bv = bias[colg];
#pragma unroll
                for (int i = 0; i < 4; i++) {
                    int row = rbase + mt * 16 + quad * 4 + i;
                    float x = acc[mt][nt][i] + bv + res[(size_t)row * 128 + colg];
                    acc[mt][nt][i] = x;
                    s[mt][i] += x;
                    s2l[mt][i] += x * x;
                }
            }
        }
#pragma unroll
        for (int m = 1; m < 16; m <<= 1) {
#pragma unroll
            for (int mt = 0; mt < 4; mt++)
#pragma unroll
                for (int i = 0; i < 4; i++) {
                    s[mt][i]  += __shfl_xor(s[mt][i], m, 64);
                    s2l[mt][i] += __shfl_xor(s2l[mt][i], m, 64);
                }
        }
        if (lr == 0) {
#pragma unroll
            for (int mt = 0; mt < 4; mt++)
#pragma unroll
                for (int i = 0; i < 4; i++) {
                    int rl = wr * 64 + mt * 16 + quad * 4 + i;
                    red2[wc][rl][0] = s[mt][i];
                    red2[wc][rl][1] = s2l[mt][i];
                }
        }
        __syncthreads();
#pragma unroll
        for (int mt = 0; mt < 4; mt++) {
#pragma unroll
            for (int i = 0; i < 4; i++) {
                int rl = wr * 64 + mt * 16 + quad * 4 + i;
                float st  = red2[0][rl][0] + red2[1][rl][0];
                float s2t = red2[0][rl][1] + red2[1][rl][1];
                float mu = st * (1.f / 128.f);
                float rstd = rsqrtf(s2t * (1.f / 128.f) - mu * mu + EPSLN);
                int row = rbase + mt * 16 + quad * 4 + i;
                if constexpr (EPI == 5) {
                    int bt = row / NN, n = row - bt * NN;
                    int b = bt / T1C, t = bt - b * T1C;
                    size_t rowp = ((size_t)(b * NN + n)) * T1C + t;
                    if (QKV && lr == 0) rowp_s[rl] = (int)rowp;
#pragma unroll
                    for (int nt = 0; nt < 4; nt++) {
                        int colg = cbase + nt * 16 + lr;
                        float y = (acc[mt][nt][i] - mu) * rstd * gam[colg] + bet[colg];
                        C[rowp * 128 + colg] = y;
                        if constexpr (OUTM & 2) Cb[rowp * 128 + colg] = f2b(y);
                        if constexpr (QKV) {
                            int cchunk = colg >> 3, celem = colg & 7;
                            int ks = cchunk ^ (rl & 15);
                            A_s[(rl * 16 + ks) * 8 + celem] = f2b(y);
                        }
                    }
                } else {
#pragma unroll
                    for (int nt = 0; nt < 4; nt++) {
                        int colg = cbase + nt * 16 + lr;
                        float y = (acc[mt][nt][i] - mu) * rstd * gam[colg] + bet[colg];
                        if constexpr (OUTM & 1) C[(size_t)row * 128 + colg] = y;
                        if constexpr (OUTM & 2) Cb[(size_t)row * 128 + colg] = f2b(y);
                    }
                }
            }
        }
    }

    if constexpr (QKV) {
        __syncthreads();
        // temporal-QKV GEMM for next layer: 128 rows x 384 cols from staged bf16.
        // wave: rows wr*64..+63 (4 mt), cols wc*192 (3 groups of 4 tiles).
#pragma unroll
        for (int g3 = 0; g3 < 3; g3++) {
            f32x4 qacc[4][4];
#pragma unroll
            for (int mt = 0; mt < 4; mt++)
#pragma unroll
                for (int nt = 0; nt < 4; nt++) qacc[mt][nt] = (f32x4){0.f, 0.f, 0.f, 0.f};
#pragma unroll
            for (int k0 = 0; k0 < 128; k0 += 32) {
                short8 af[4], bf[4];
#pragma unroll
                for (int mt = 0; mt < 4; mt++) {
                    int row_l = wr * 64 + mt * 16 + lr;
                    int koct = (k0 >> 3) + quad;
                    int slot = row_l * 16 + (koct ^ lr);
                    af[mt] = *(const short8*)(A_s + slot * 8);
                }
#pragma unroll
                for (int nt = 0; nt < 4; nt++) {
                    size_t off = ((size_t)(wc * 12 + g3 * 4 + nt) * 4 + (k0 >> 5)) * 512 + lane * 8;
                    bf[nt] = *(const short8*)(Wqkv + off);
                }
#pragma unroll
                for (int mt = 0; mt < 4; mt++)
#pragma unroll
                    for (int nt = 0; nt < 4; nt++)
                        qacc[mt][nt] = __builtin_amdgcn_mfma_f32_16x16x32_bf16(af[mt], bf[nt], qacc[mt][nt], 0, 0, 0);
            }
#pragma unroll
            for (int nt = 0; nt < 4; nt++) {
                int col = (wc * 12 + g3 * 4 + nt) * 16 + lr;
                float bv = abq[col];
#pragma unroll
                for (int mt = 0; mt < 4; mt++) {
#pragma unroll
                    for (int i = 0; i < 4; i++) {
                        int row = rowp_s[wr * 64 + mt * 16 + quad * 4 + i];
                        outQ[(size_t)row * 384 + col] = f2b(qacc[mt][nt][i] + bv);
                    }
                }
            }
        }
    }
}

template<int K, int EPI, int OUTM>
static void run_gemm2(const unsigned short* A, const unsigned short* Bp, const float* bias,
                      float* C, unsigned short* Cb, const float* res, const float* g, const float* be,
                      const float* trep, int M, int Ntot, hipStream_t stream)
{
    dim3 grid(M / 128, Ntot / 128);
    gemm2_k<K, EPI, OUTM, 0><<<grid, 256, 0, stream>>>(A, Bp, bias, C, Cb, res, g, be, trep,
                                                       nullptr, nullptr, nullptr, M, Ntot);
}

template<int QKV>
static void run_gemm2_ln_qkv(const unsigned short* A, const unsigned short* Bp, const float* bias,
                             float* C, const float* res, const float* g, const float* be,
                             const unsigned short* Wqkv, const float* abq, unsigned short* outQ,
                             hipStream_t stream)
{
    dim3 grid(MROWS / 128, 1);
    gemm2_k<128, 5, 1, QKV><<<grid, 256, 0, stream>>>(A, Bp, bias, C, nullptr, res, g, be, nullptr,
                                                      Wqkv, abq, outQ, MROWS, 128);
}

// ---------------- fused Wo+LN+FFN+LN + graph-QKV GEMM (32-row tile) ----------------

__global__ __launch_bounds__(256) void offn_k(
    const unsigned short* __restrict__ A,      // attn out bf16 [MROWS][128]
    const unsigned short* __restrict__ Wp,     // WoP layer slice (K=128, Ntot=128 packed)
    const float* __restrict__ ob_l,
    const float* __restrict__ resh,            // h_prev (f32)
    const float* __restrict__ tng_l, const float* __restrict__ tnb_l,
    const unsigned short* __restrict__ F1p,    // f1P layer slice (K=128, N=256 packed)
    const unsigned short* __restrict__ F2p,    // f2P layer slice (K=256, N=128 packed)
    const float* __restrict__ f1b_l, const float* __restrict__ f2b_l,
    const float* __restrict__ fng_l, const float* __restrict__ fnb_l,
    const float* __restrict__ trep,
    const unsigned short* __restrict__ Wqkv,   // WqkvP layer slice (K=128, Ntot=384 packed)
    float* __restrict__ C,                     // hBT (f32, transposed)
    unsigned short* __restrict__ Qc, unsigned short* __restrict__ Kc, unsigned short* __restrict__ Vc)
{
    __shared__ unsigned short A_s[32 * 16 * 8];
    __shared__ unsigned short M_s[32 * 16 * 8];
    __shared__ float red2[2][32][2];

    int tid = threadIdx.x;
    int w = tid >> 6, lane = tid & 63;
    int wr = w & 1, wc = w >> 1;
    int quad = lane >> 4, lr = lane & 15;

    const unsigned short* abase = A + (size_t)blockIdx.x * 32 * 128;

#pragma unroll
    for (int j = 0; j < 2; j++) {
        int s = j * 256 + tid;
        int row = s >> 4, ks = s & 15;
        int ko = ks ^ (row & 15);
        uint4 d = *(const uint4*)(abase + (size_t)row * 128 + ko * 8);
        *(uint4*)(A_s + s * 8) = d;
    }
    __syncthreads();

    // ---- Wo GEMM (K=128) ----
    f32x4 wacc[4];
#pragma unroll
    for (int nt = 0; nt < 4; nt++) wacc[nt] = (f32x4){0.f, 0.f, 0.f, 0.f};
#pragma unroll
    for (int k0 = 0; k0 < 128; k0 += 32) {
        int row_l = wr * 16 + lr;
        int koct = (k0 >> 3) + quad;
        int slot = row_l * 16 + (koct ^ lr);
        short8 af = *(const short8*)(A_s + slot * 8);
        short8 bf[4];
#pragma unroll
        for (int nt = 0; nt < 4; nt++) {
            size_t off = ((size_t)(wc * 4 + nt) * 4 + (k0 >> 5)) * 512 + lane * 8;
            bf[nt] = *(const short8*)(Wp + off);
        }
#pragma unroll
        for (int nt = 0; nt < 4; nt++)
            wacc[nt] = __builtin_amdgcn_mfma_f32_16x16x32_bf16(af, bf[nt], wacc[nt], 0, 0, 0);
    }

    int rbase = blockIdx.x * 32 + wr * 16;
    int cbase = wc * 64;

    // ---- temporal-LN epilogue: y kept in registers, bf16(y) staged into A_s ----
    float yv[4][4];
    {
        float s1[4], s2v[4];
#pragma unroll
        for (int i = 0; i < 4; i++) { s1[i] = 0.f; s2v[i] = 0.f; }
#pragma unroll
        for (int nt = 0; nt < 4; nt++) {
            int colg = cbase + nt * 16 + lr;
            float bv = ob_l[colg];
#pragma unroll
            for (int i = 0; i < 4; i++) {
                int row = rbase + quad * 4 + i;
                float x = wacc[nt][i] + bv + resh[(size_t)row * 128 + colg];
                yv[nt][i] = x;
                s1[i] += x;
                s2v[i] += x * x;
            }
        }
#pragma unroll
        for (int m = 1; m < 16; m <<= 1) {
#pragma unroll
            for (int i = 0; i < 4; i++) {
                s1[i]  += __shfl_xor(s1[i], m, 64);
                s2v[i] += __shfl_xor(s2v[i], m, 64);
            }
        }
        if (lr == 0) {
#pragma unroll
            for (int i = 0; i < 4; i++) {
                int rl = wr * 16 + quad * 4 + i;
                red2[wc][rl][0] = s1[i];
                red2[wc][rl][1] = s2v[i];
            }
        }
        __syncthreads();
#pragma unroll
        for (int i = 0; i < 4; i++) {
            int rl = wr * 16 + quad * 4 + i;
            float st  = red2[0][rl][0] + red2[1][rl][0];
            float s2t = red2[0][rl][1] + red2[1][rl][1];
            float mu = st * (1.f / 128.f);
            float rstd = rsqrtf(s2t * (1.f / 128.f) - mu * mu + EPSLN);
            int row = wr * 16 + quad * 4 + i;
#pragma unroll
            for (int nt = 0; nt < 4; nt++) {
                int col = cbase + nt * 16 + lr;
                float y = (yv[nt][i] - mu) * rstd * tng_l[col] + tnb_l[col];
                yv[nt][i] = y;
                int cchunk = col >> 3, celem = col & 7;
                int ks = cchunk ^ (row & 15);
                A_s[(row * 16 + ks) * 8 + celem] = f2b(y);
            }
        }
    }
    __syncthreads();

    // ---- FFN: f1 + gelu + f2 ----
    f32x4 facc[4];
#pragma unroll
    for (int nt = 0; nt < 4; nt++) facc[nt] = (f32x4){0.f, 0.f, 0.f, 0.f};

#pragma unroll
    for (int half = 0; half < 2; half++) {
        f32x4 macc[4];
#pragma unroll
        for (int nt = 0; nt < 4; nt++) macc[nt] = (f32x4){0.f, 0.f, 0.f, 0.f};
#pragma unroll
        for (int k0 = 0; k0 < 128; k0 += 32) {
            int row_l = wr * 16 + lr;
            int koct = (k0 >> 3) + quad;
            int slot = row_l * 16 + (koct ^ lr);
            short8 af = *(const short8*)(A_s + slot * 8);
            short8 bf[4];
#pragma unroll
            for (int nt = 0; nt < 4; nt++) {
                size_t off = ((size_t)(half * 8 + wc * 4 + nt) * 4 + (k0 >> 5)) * 512 + lane * 8;
                bf[nt] = *(const short8*)(F1p + off);
            }
#pragma unroll
            for (int nt = 0; nt < 4; nt++)
                macc[nt] = __builtin_amdgcn_mfma_f32_16x16x32_bf16(af, bf[nt], macc[nt], 0, 0, 0);
        }
        if (half) __syncthreads();
#pragma unroll
        for (int nt = 0; nt < 4; nt++) {
            int col = wc * 64 + nt * 16 + lr;
            float bv = f1b_l[half * 128 + col];
            int cchunk = col >> 3, celem = col & 7;
#pragma unroll
            for (int i = 0; i < 4; i++) {
                int row = wr * 16 + quad * 4 + i;
                float x = macc[nt][i] + bv;
                x = 0.5f * x * (1.f + erff(x * 0.70710678118654752f));
                int ks = cchunk ^ (row & 15);
                M_s[(row * 16 + ks) * 8 + celem] = f2b(x);
            }
        }
        __syncthreads();
#pragma unroll
        for (int k0 = 0; k0 < 128; k0 += 32) {
            int row_l = wr * 16 + lr;
            int koct = (k0 >> 3) + quad;
            int slot = row_l * 16 + (koct ^ lr);
            short8 af = *(const short8*)(M_s + slot * 8);
            short8 bf[4];
#pragma unroll
            for (int nt = 0; nt < 4; nt++) {
                size_t off = ((size_t)(wc * 4 + nt) * 8 + ((half * 128 + k0) >> 5)) * 512 + lane * 8;
                bf[nt] = *(const short8*)(F2p + off);
            }
#pragma unroll
            for (int nt = 0; nt < 4; nt++)
                facc[nt] = __builtin_amdgcn_mfma_f32_16x16x32_bf16(af, bf[nt], facc[nt], 0, 0, 0);
        }
    }

    // ---- final epilogue: res(yv) + LN + t_re; write hBT (f32) + stage bf16 into A_s ----
    float s[4], s2l[4];
#pragma unroll
    for (int i = 0; i < 4; i++) { s[i] = 0.f; s2l[i] = 0.f; }
#pragma unroll
    for (int nt = 0; nt < 4; nt++) {
        int colg = cbase + nt * 16 + lr;
        float bv = f2b_l[colg];
#pragma unroll
        for (int i = 0; i < 4; i++) {
            float x = facc[nt][i] + bv + yv[nt][i];
            facc[nt][i] = x;
            s[i] += x;
            s2l[i] += x * x;
        }
    }
#pragma unroll
    for (int m = 1; m < 16; m <<= 1) {
#pragma unroll
        for (int i = 0; i < 4; i++) {
            s[i]  += __shfl_xor(s[i], m, 64);
            s2l[i] += __shfl_xor(s2l[i], m, 64);
        }
    }
    if (lr == 0) {
#pragma unroll
        for (int i = 0; i < 4; i++) {
            int rl = wr * 16 + quad * 4 + i;
            red2[wc][rl][0] = s[i];
            red2[wc][rl][1] = s2l[i];
        }
    }
    __syncthreads();
    size_t rowp4[4];
#pragma unroll
    for (int i = 0; i < 4; i++) {
        int rl = wr * 16 + quad * 4 + i;
        float st  = red2[0][rl][0] + red2[1][rl][0];
        float s2t = red2[0][rl][1] + red2[1][rl][1];
        float mu = st * (1.f / 128.f);
        float rstd = rsqrtf(s2t * (1.f / 128.f) - mu * mu + EPSLN);
        int row = rbase + quad * 4 + i;
        int t = row % T1C;
        int bn = row / T1C;
        int b = bn / NN;
        int n = bn - b * NN;
        size_t rowp = (size_t)(b * T1C + t) * NN + n;
        rowp4[i] = rowp;
        const float* trow = trep + t * HHC;
        int rloc = wr * 16 + quad * 4 + i;
#pragma unroll
        for (int nt = 0; nt < 4; nt++) {
            int colg = cbase + nt * 16 + lr;
            float y = (facc[nt][i] - mu) * rstd * fng_l[colg] + fnb_l[colg] + trow[colg];
            C[rowp * 128 + colg] = y;
            int cchunk = colg >> 3, celem = colg & 7;
            int ks = cchunk ^ (rloc & 15);
            A_s[(rloc * 16 + ks) * 8 + celem] = f2b(y);
        }
    }
    __syncthreads();

    // ---- graph QKV GEMM: each wave 16 rows (wr) x 192 cols (wc), 3 groups of 4 tiles ----
#pragma unroll
    for (int g3 = 0; g3 < 3; g3++) {
        f32x4 qacc[4];
#pragma unroll
        for (int nt = 0; nt < 4; nt++) qacc[nt] = (f32x4){0.f, 0.f, 0.f, 0.f};
#pragma unroll
        for (int k0 = 0; k0 < 128; k0 += 32) {
            int row_l = wr * 16 + lr;
            int koct = (k0 >> 3) + quad;
            int slot = row_l * 16 + (koct ^ lr);
            short8 af = *(const short8*)(A_s + slot * 8);
            short8 bf[4];
#pragma unroll
            for (int nt = 0; nt < 4; nt++) {
                size_t off = ((size_t)(wc * 12 + g3 * 4 + nt) * 4 + (k0 >> 5)) * 512 + lane * 8;
                bf[nt] = *(const short8*)(Wqkv + off);
            }
#pragma unroll
            for (int nt = 0; nt < 4; nt++)
                qacc[nt] = __builtin_amdgcn_mfma_f32_16x16x32_bf16(af, bf[nt], qacc[nt], 0, 0, 0);
        }
#pragma unroll
        for (int nt = 0; nt < 4; nt++) {
            int colg = wc * 192 + (g3 * 4 + nt) * 16 + lr;
            unsigned short* dstbuf;
            int col;
            if (colg < 128)      { dstbuf = Qc; col = colg; }
            else if (colg < 256) { dstbuf = Kc; col = colg - 128; }
            else                 { dstbuf = Vc; col = colg - 256; }
#pragma unroll
            for (int i = 0; i < 4; i++)
                dstbuf[rowp4[i] * 128 + col] = f2b(qacc[nt][i]);
        }
    }
}

// ---------------- fused hm chain: hm = f2b(mBb@WoT + mA + bo) -> P12 = hm@W12 ----------------

__global__ __launch_bounds__(256) void gemm_hm12_k(
    const unsigned short* __restrict__ A,    // mBb
    const unsigned short* __restrict__ WT,   // WoT layer slice [c][k]
    const float* __restrict__ mA, const float* __restrict__ bo,
    const unsigned short* __restrict__ W12,  // W12P layer slice [c][k]
    float* __restrict__ P12)
{
    __shared__ unsigned short A_s[32 * 16 * 8];
    const int M = NN, K = 128;
    int tid = threadIdx.x;
    int w = tid >> 6, lane = tid & 63;
    int wr = w & 1, wc = w >> 1;
    int r0 = blockIdx.x * 32 + wr * 16;
    int c0 = wc * 64;
    int lr = lane & 15, quad = lane >> 4;
    int kq = quad * 8;
    int arow = r0 + lr; if (arow >= M) arow = M - 1;
    const unsigned short* ap = A + (size_t)arow * K + kq;
    const unsigned short* wp = WT + (size_t)(c0 + lr) * K + kq;

    // phase 1: mBb @ WoT
    f32x4 acc[4];
#pragma unroll
    for (int t = 0; t < 4; t++) acc[t] = (f32x4){0.f, 0.f, 0.f, 0.f};
    for (int k0 = 0; k0 < K; k0 += 32) {
        short8 a = *(const short8*)(ap + k0);
#pragma unroll
        for (int t = 0; t < 4; t++) {
            short8 b = *(const short8*)(wp + (size_t)t * 16 * K + k0);
            acc[t] = __builtin_amdgcn_mfma_f32_16x16x32_bf16(a, b, acc[t], 0, 0, 0);
        }
    }
    // epilogue: + mA + bo -> f2b, staged into LDS (swizzled A-fragment layout)
#pragma unroll
    for (int t = 0; t < 4; t++) {
        int col = c0 + t * 16 + lr;
        int cchunk = col >> 3, celem = col & 7;
#pragma unroll
        for (int i = 0; i < 4; i++) {
            int row = r0 + quad * 4 + i;
            int rr = row < M ? row : M - 1;
            float x = acc[t][i] + mA[(size_t)rr * 128 + col] + bo[col];
            int rloc = wr * 16 + quad * 4 + i;
            int ks = cchunk ^ (rloc & 15);
            A_s[(rloc * 16 + ks) * 8 + celem] = f2b(x);
        }
    }
    __syncthreads();

    // phase 2: P12 = hm @ W12
    f32x4 acc2[4];
#pragma unroll
    for (int t = 0; t < 4; t++) acc2[t] = (f32x4){0.f, 0.f, 0.f, 0.f};
    const unsigned short* wp2 = W12 + (size_t)(c0 + lr) * 128 + kq;
#pragma unroll
    for (int k0 = 0; k0 < 128; k0 += 32) {
        int row_l = wr * 16 + lr;
        int koct = (k0 >> 3) + quad;
        int slot = row_l * 16 + (koct ^ lr);
        short8 af = *(const short8*)(A_s + slot * 8);
#pragma unroll
        for (int t = 0; t < 4; t++) {
            short8 b = *(const short8*)(wp2 + (size_t)t * 16 * 128 + k0);
            acc2[t] = __builtin_amdgcn_mfma_f32_16x16x32_bf16(af, b, acc2[t], 0, 0, 0);
        }
    }
#pragma unroll
    for (int t = 0; t < 4; t++) {
        int col = c0 + t * 16 + lr;
#pragma unroll
        for (int i = 0; i < 4; i++) {
            int row = r0 + quad * 4 + i;
            if (row < M) P12[(size_t)row * 128 + col] = acc2[t][i];
        }
    }
}

// ---------------- fused per-edge MLP (+ next-layer edge coefficients) ----------------

__global__ __launch_bounds__(256) void emlp_k(const float* __restrict__ P12,
                                              const int* __restrict__ dst, const int* __restrict__ src,
                                              const float* __restrict__ e1wE, const float* __restrict__ e1b_l,
                                              const float* __restrict__ e2w_l, const float* __restrict__ e2b_l,
                                              const float* __restrict__ g, const float* __restrict__ be,
                                              float* __restrict__ e,
                                              const int* __restrict__ epos,
                                              const float* __restrict__ WemN, const float* __restrict__ bemN,
                                              const float* __restrict__ WeaN, const float* __restrict__ beaN,
                                              float* __restrict__ ec, int doEc)
{
    __shared__ float tl[4][64];
    int wv = threadIdx.x >> 6, l = threadIdx.x & 63;
    int r = blockIdx.x * 4 + wv;           // EEC = 34000 = 8500*4, no remainder
    int d = dst[r], s = src[r];
    const float* ep = e + (size_t)r * DEC;
    float t = P12[(size_t)d * 128 + l] + P12[(size_t)s * 128 + 64 + l] + e1b_l[l];
#pragma unroll
    for (int k = 0; k < DEC; k++) t += ep[k] * e1wE[k * 64 + l];
    t = 0.5f * t * (1.f + erff(t * 0.70710678118654752f));
    tl[wv][l] = t;
    __syncthreads();
    int c = l & 15, kq = l >> 4;
    float p = 0.f;
#pragma unroll
    for (int j = 0; j < 16; j++) p += tl[wv][kq * 16 + j] * e2w_l[(kq * 16 + j) * 16 + c];
    p += __shfl_xor(p, 16, 64);
    p += __shfl_xor(p, 32, 64);
    float x = p + e2b_l[c] + ep[c];
    float s1 = x, s2 = x * x;
#pragma unroll
    for (int m = 1; m < 16; m <<= 1) {
        s1 += __shfl_xor(s1, m, 64);
        s2 += __shfl_xor(s2, m, 64);
    }
    float mu = s1 * (1.f / 16.f);
    float rstd = rsqrtf(s2 * (1.f / 16.f) - mu * mu + EPSLN);
    float y = (x - mu) * rstd * g[c] + be[c];
    if (l < 16) e[(size_t)r * DEC + c] = y;

    if (doEc) {
        int hh = l >> 4;      // head = replica group 0..3
        float pem = y * WemN[c * NHD + hh];
        float pea = y * WeaN[c * NHD + hh];
#pragma unroll
        for (int m = 1; m < 16; m <<= 1) {
            pem += __shfl_xor(pem, m, 64);
            pea += __shfl_xor(pea, m, 64);
        }
        if (c == 0) {
            int pos = epos[r];
            ec[(size_t)pos * 8 + hh * 2]     = (pem + bemN[hh] + 1.f) * SCALEQK;
            ec[(size_t)pos * 8 + hh * 2 + 1] = pea + beaN[hh];
        }
    }
}

// ---------------- graph precompute ----------------

__global__ __launch_bounds__(256) void zero_deg_k(int* __restrict__ degi)
{
    int i = blockIdx.x * blockDim.x + threadIdx.x;
    if (i < NN) degi[i] = 0;
}

__global__ __launch_bounds__(256) void build_edges_k(const int* __restrict__ eidx,
                                                     int* __restrict__ dst, int* __restrict__ src,
                                                     int* __restrict__ degi)
{
    int e = blockIdx.x * blockDim.x + threadIdx.x;
    if (e >= EEC) return;
    int d, s;
    if (e < E0C) { d = eidx[e]; s = eidx[E0C + e]; }
    else { d = e - E0C; s = e - E0C; }
    dst[e] = d;
    src[e] = s;
    atomicAdd(&degi[d], 1);
}

__global__ __launch_bounds__(256) void scan_k(const int* __restrict__ degi, int* __restrict__ rowptr,
                                              int* __restrict__ cursor, float* __restrict__ degmaxf)
{
    __shared__ int ssum[256];
    __shared__ int smx[256];
    int tid = threadIdx.x;
    int vals[8];
    int s = 0, mx = 0;
    int base = tid * 8;
#pragma unroll
    for (int j = 0; j < 8; j++) {
        int idx = base + j;
        int v = (idx < NN) ? degi[idx] : 0;
        vals[j] = v; s += v; mx = max(mx, v);
    }
    ssum[tid] = s; smx[tid] = mx;
    __syncthreads();
    for (int off = 1; off < 256; off <<= 1) {
        int t = (tid >= off) ? ssum[tid - off] : 0;
        __syncthreads();
        ssum[tid] += t;
        __syncthreads();
    }
    for (int off = 128; off > 0; off >>= 1) {
        if (tid < off) smx[tid] = max(smx[tid], smx[tid + off]);
        __syncthreads();
    }
    if (tid == 0) *degmaxf = fmaxf((float)smx[0], 1.f);
    int running = ssum[tid] - s;
#pragma unroll
    for (int j = 0; j < 8; j++) {
        int idx = base + j;
        if (idx < NN) { rowptr[idx] = running; cursor[idx] = running; running += vals[j]; }
    }
    if (tid == 255) rowptr[NN] = ssum[255];
}

__global__ __launch_bounds__(256) void feat_k(const int* __restrict__ dst, const int* __restrict__ src,
                                              const int* __restrict__ degi, const float* __restrict__ degmaxf,
                                              int* __restrict__ cursor, int* __restrict__ srcCSR,
                                              int* __restrict__ epos,
                                              const float* __restrict__ We, const float* __restrict__ bE,
                                              float* __restrict__ e)
{
    int ei = blockIdx.x * blockDim.x + threadIdx.x;
    if (ei >= EEC) return;
    int d = dst[ei], s = src[ei];
    int pos = atomicAdd(&cursor[d], 1);
    srcCSR[pos] = s;
    epos[ei] = pos;
    float dm = *degmaxf;
    float degd = (float)degi[d], degs = (float)degi[s];
    float f0 = 1.f / fmaxf(degd, 1.f);
    float f1 = degs / dm, f2 = degd / dm;
#pragma unroll
    for (int c = 0; c < DEC; c++)
        e[ei * DEC + c] = bE[c] + f0 * We[c] + f1 * We[DEC + c] + f2 * We[2 * DEC + c];
}

// ---------------- embedding: wave-per-row, shfl-only reduction ----------------

__global__ __launch_bounds__(256) void embed_k(const float* __restrict__ Xk, const float* __restrict__ temb,
                                               const float* __restrict__ Win, const float* __restrict__ bin,
                                               const float* __restrict__ g, const float* __restrict__ be,
                                               const float* __restrict__ stepemb, const int* __restrict__ kidx,
                                               float* __restrict__ h, unsigned short* __restrict__ hb)
{
    int row = blockIdx.x * 4 + (threadIdx.x >> 6);
    int l = threadIdx.x & 63;
    int t = row % T1C;
    int bn = row / T1C;
    int b = bn / NN;
    const float* xk = Xk + (size_t)row * CINC;
    const float* tp = temb + t * TEC;
    float acc0 = bin[l], acc1 = bin[l + 64];
#pragma unroll
    for (int k = 0; k < CINC; k++) {
        float xv = xk[k];
        acc0 += xv * Win[k * HHC + l];
        acc1 += xv * Win[k * HHC + l + 64];
    }
#pragma unroll
    for (int k = 0; k < TEC; k++) {
        float xv = tp[k];
        acc0 += xv * Win[(CINC + k) * HHC + l];
        acc1 += xv * Win[(CINC + k) * HHC + l + 64];
    }
    float s = acc0 + acc1, s2 = acc0 * acc0 + acc1 * acc1;
#pragma unroll
    for (int m = 32; m >= 1; m >>= 1) {
        s  += __shfl_xor(s, m, 64);
        s2 += __shfl_xor(s2, m, 64);
    }
    float mu = s * (1.f / 128.f);
    float rstd = rsqrtf(s2 * (1.f / 128.f) - mu * mu + EPSLN);
    const float* se = stepemb + (size_t)kidx[b] * HHC;
    float v0 = (acc0 - mu) * rstd * g[l] + be[l] + se[l];
    float v1 = (acc1 - mu) * rstd * g[l + 64] + be[l + 64] + se[l + 64];
    size_t ob = (size_t)row * HHC;
    h[ob + l] = v0;
    h[ob + l + 64] = v1;
    hb[ob + l] = f2b(v0);
    hb[ob + l + 64] = f2b(v1);
}

__global__ __launch_bounds__(128) void tre_k(const float* __restrict__ temb, const float* __restrict__ Wtr,
                                             const float* __restrict__ btr, float* __restrict__ tre)
{
    int t = blockIdx.x, c = threadIdx.x;
    float acc = btr[c];
#pragma unroll
    for (int k = 0; k < TEC; k++) acc += temb[t * TEC + k] * Wtr[k * HHC + c];
    tre[t * HHC + c] = acc;
}

// ---------------- temporal attention: raw-bf16 LDS staging ----------------

__global__ __launch_bounds__(128) void temporal_attn_k(const unsigned short* __restrict__ qkvb,
                                                       unsigned short* __restrict__ outb)
{
    int bn = blockIdx.x;
    __shared__ unsigned short qkv_s[T1C][408];
    __shared__ float s[NHD][T1C][T1C];
    int tid = threadIdx.x;
    int hh = tid >> 5, lane = tid & 31;
    const unsigned short* base = qkvb + (size_t)bn * T1C * 384;
    for (int cIdx = tid; cIdx < 576; cIdx += 128) {
        uint4 d = *(const uint4*)(base + cIdx * 8);
        int t = cIdx / 48;
        int c0 = (cIdx - t * 48) * 8;
        *(uint4*)(&qkv_s[t][c0]) = d;
    }
    __syncthreads();
    for (int idx = lane; idx < T1C * T1C; idx += 32) {
        int tq = idx / T1C, tk = idx - tq * T1C;
        const unsigned* qp = (const unsigned*)&qkv_s[tq][hh * 32];
        const unsigned* kp = (const unsigned*)&qkv_s[tk][128 + hh * 32];
        float acc = 0.f;
#pragma unroll
        for (int d = 0; d < 16; d++) {
            unsigned a = qp[d], b = kp[d];
            acc += __uint_as_float(a << 16) * __uint_as_float(b << 16);
            acc += __uint_as_float(a & 0xFFFF0000u) * __uint_as_float(b & 0xFFFF0000u);
        }
        s[hh][tq][tk] = acc * SCALEQK;
    }
    __syncthreads();
    if (tid < NHD * T1C) {
        int h2 = tid / T1C, tq = tid - h2 * T1C;
        float mx = -1e30f;
#pragma unroll
        for (int j = 0; j < T1C; j++) mx = fmaxf(mx, s[h2][tq][j]);
        float sum = 0.f;
#pragma unroll
        for (int j = 0; j < T1C; j++) { float ex = __expf(s[h2][tq][j] - mx); s[h2][tq][j] = ex; sum += ex; }
        float inv = 1.f / sum;
#pragma unroll
        for (int j = 0; j < T1C; j++) s[h2][tq][j] *= inv;
    }
    __syncthreads();
    int oc = hh * 32 + lane;
#pragma unroll
    for (int t = 0; t < T1C; t++) {
        float acc = 0.f;
#pragma unroll
        for (int tk = 0; tk < T1C; tk++) acc += s[hh][t][tk] * b2f(qkv_s[tk][256 + oc]);
        outb[((size_t)bn * T1C + t) * HHC + oc] = f2b(acc);
    }
}

// ---------------- graph attention ----------------

// per-CSR-edge coefficients (layer 0 only; later layers fused into emlp_k)
__global__ __launch_bounds__(256) void emea_k(const float* __restrict__ e, const int* __restrict__ epos,
                                              const float* __restrict__ Wem, const float* __restrict__ bem,
                                              const float* __restrict__ Wea, const float* __restrict__ bea,
                                              float* __restrict__ ec)
{
    int r = blockIdx.x * blockDim.x + threadIdx.x;
    if (r >= EEC) return;
    float ev[DEC];
#pragma unroll
    for (int k = 0; k < DEC; k++) ev[k] = e[r * DEC + k];
    int pos = epos[r];
#pragma unroll
    for (int hh = 0; hh < NHD; hh++) {
        float a = bem[hh], b2 = bea[hh];
#pragma unroll
        for (int k = 0; k < DEC; k++) { a += ev[k] * Wem[k * NHD + hh]; b2 += ev[k] * Wea[k * NHD + hh]; }
        ec[(size_t)pos * 8 + hh * 2]     = (a + 1.f) * SCALEQK;
        ec[(size_t)pos * 8 + hh * 2 + 1] = b2;
    }
}

// fused score+aggregate over CSR, wave-per-(bt,n): 4 waves/block share one bt
__global__ __launch_bounds__(256) void sagg_k(const unsigned short* __restrict__ Q,
                                              const unsigned short* __restrict__ K,
                                              const unsigned short* __restrict__ V,
                                              const int* __restrict__ rowptr, const int* __restrict__ srcCSR,
                                              const float* __restrict__ ec, unsigned short* __restrict__ outb)
{
    int wv = threadIdx.x >> 6;
    int lane = threadIdx.x & 63;
    int blk = blockIdx.x;
    int bt = blk % BTC;
    int n  = (blk / BTC) * 4 + wv;
    int cg = lane & 15;
    int es = lane >> 4;       // 0..3
    int hh = cg >> 2;
    size_t base = (size_t)bt * NN;
    uint4 qd = *(const uint4*)(Q + (base + n) * HHC + cg * 8);
    unsigned qv[4] = {qd.x, qd.y, qd.z, qd.w};
    float q[8];
#pragma unroll
    for (int jj = 0; jj < 4; jj++) {
        q[2 * jj]     = __uint_as_float(qv[jj] << 16);
        q[2 * jj + 1] = __uint_as_float(qv[jj] & 0xFFFF0000u);
    }
    int s0 = rowptr[n], s1 = rowptr[n + 1];
    float acc[8];
#pragma unroll
    for (int j = 0; j < 8; j++) acc[j] = 0.f;
    float den = 0.f;
    for (int i = s0 + es; i < s1; i += 4) {
        int sn = srcCSR[i];
        uint4 kd = *(const uint4*)(K + (base + sn) * HHC + cg * 8);
        uint4 vd = *(const uint4*)(V + (base + sn) * HHC + cg * 8);
        float2 c2 = *(const float2*)(ec + (size_t)i * 8 + hh * 2);
        unsigned kv[4] = {kd.x, kd.y, kd.z, kd.w};
        float p = 0.f;
#pragma unroll
        for (int jj = 0; jj < 4; jj++) {
            p += q[2 * jj]     * __uint_as_float(kv[jj] << 16);
            p += q[2 * jj + 1] * __uint_as_float(kv[jj] & 0xFFFF0000u);
        }
        p += __shfl_xor(p, 1, 64);
        p += __shfl_xor(p, 2, 64);
        float w = __expf(p * c2.x + c2.y);
        unsigned vv[4] = {vd.x, vd.y, vd.z, vd.w};
#pragma unroll
        for (int jj = 0; jj < 4; jj++) {
            acc[2 * jj]     += w * __uint_as_float(vv[jj] << 16);
            acc[2 * jj + 1] += w * __uint_as_float(vv[jj] & 0xFFFF0000u);
        }
        den += w;
    }
#pragma unroll
    for (int j = 0; j < 8; j++) {
        acc[j] += __shfl_xor(acc[j], 16, 64);
        acc[j] += __shfl_xor(acc[j], 32, 64);
    }
    den += __shfl_xor(den, 16, 64);
    den += __shfl_xor(den, 32, 64);
    if (es == 0) {
        float inv = den + 1e-9f;
        unsigned short r[8];
#pragma unroll
        for (int j = 0; j < 8; j++) r[j] = f2b(acc[j] / inv);
        *(uint4*)(outb + (base + n) * HHC + cg * 8) = *(uint4*)r;
    }
}

// means over bt of hBT (f32, pre-residual base) and agg output (bf16)
__global__ __launch_bounds__(128) void hmean2_k(const float* __restrict__ hBT,
                                                const unsigned short* __restrict__ aggb,
                                                float* __restrict__ mA, unsigned short* __restrict__ mBb)
{
    int n = blockIdx.x, c = threadIdx.x;
    float sA = 0.f, sB = 0.f;
#pragma unroll
    for (int bt = 0; bt < BTC; bt++) {
        size_t off = ((size_t)bt * NN + n) * HHC + c;
        sA += hBT[off];
        sB += b2f(aggb[off]);
    }
    mA[n * HHC + c] = sA * (1.f / BTC);
    mBb[n * HHC + c] = f2b(sB * (1.f / BTC));
}

// ---------------- output head: one wave per row ----------------

__global__ __launch_bounds__(256) void out_k(const float* __restrict__ h, const float* __restrict__ Wout,
                                             const float* __restrict__ bout, float* __restrict__ out)
{
    int row = blockIdx.x * 4 + (threadIdx.x >> 6);
    int lane = threadIdx.x & 63;
    const float* hp = h + (size_t)row * HHC;
    float x0 = hp[lane], x1 = hp[lane + 64];
    float w00 = Wout[lane * 4 + 0], w01 = Wout[lane * 4 + 1];
    float w02 = Wout[lane * 4 + 2], w03 = Wout[lane * 4 + 3];
    float w10 = Wout[(lane + 64) * 4 + 0], w11 = Wout[(lane + 64) * 4 + 1];
    float w12 = Wout[(lane + 64) * 4 + 2], w13 = Wout[(lane + 64) * 4 + 3];
    float p0 = x0 * w00 + x1 * w10;
    float p1 = x0 * w01 + x1 * w11;
    float p2 = x0 * w02 + x1 * w12;
    float p3 = x0 * w03 + x1 * w13;
#pragma unroll
    for (int m = 32; m >= 1; m >>= 1) {
        p0 += __shfl_xor(p0, m, 64);
        p1 += __shfl_xor(p1, m, 64);
        p2 += __shfl_xor(p2, m, 64);
        p3 += __shfl_xor(p3, m, 64);
    }
    if (lane == 0) {
        float l0 = p0 + bout[0], l1 = p1 + bout[1], l2 = p2 + bout[2], l3 = p3 + bout[3];
        float mx = fmaxf(fmaxf(l0, l1), fmaxf(l2, l3));
        float e0 = __expf(l0 - mx), e1 = __expf(l1 - mx), e2 = __expf(l2 - mx), e3 = __expf(l3 - mx);
        float inv = 1.f / (e0 + e1 + e2 + e3);
        float4 o = {e0 * inv, e1 * inv, e2 * inv, e3 * inv};
        *(float4*)(out + (size_t)row * 4) = o;
    }
}

// ---------------- launch ----------------

extern "C" void kernel_launch(void* const* d_in, const int* in_sizes, int n_in,
                              void* d_out, int out_size, void* d_ws, size_t ws_size,
                              hipStream_t stream)
{
    const float* Xk      = (const float*)d_in[0];
    const float* temb    = (const float*)d_in[1];
    const float* stepemb = (const float*)d_in[2];
    const float* Wtr     = (const float*)d_in[3];
    const float* btr     = (const float*)d_in[4];
    const float* Win     = (const float*)d_in[5];
    const float* bin     = (const float*)d_in[6];
    const float* gin     = (const float*)d_in[7];
    const float* bein    = (const float*)d_in[8];
    const float* We      = (const float*)d_in[9];
    const float* bE      = (const float*)d_in[10];
    const float* aw      = (const float*)d_in[11];
    const float* ab      = (const float*)d_in[12];
    const float* ow      = (const float*)d_in[13];
    const float* ob      = (const float*)d_in[14];
    const float* tng     = (const float*)d_in[15];
    const float* tnb     = (const float*)d_in[16];
    const float* f1w     = (const float*)d_in[17];
    const float* f1b     = (const float*)d_in[18];
    const float* f2w     = (const float*)d_in[19];
    const float* f2b_    = (const float*)d_in[20];
    const float* fng     = (const float*)d_in[21];
    const float* fnb     = (const float*)d_in[22];
    const float* Wq      = (const float*)d_in[23];
    const float* Wk      = (const float*)d_in[24];
    const float* Wv      = (const float*)d_in[25];
    const float* Wo      = (const float*)d_in[26];
    const float* bo      = (const float*)d_in[27];
    const float* Wem     = (const float*)d_in[28];
    const float* bem     = (const float*)d_in[29];
    const float* Wea     = (const float*)d_in[30];
    const float* bea     = (const float*)d_in[31];
    const float* e1w     = (const float*)d_in[32];
    const float* e1b     = (const float*)d_in[33];
    const float* e2w     = (const float*)d_in[34];
    const float* e2b     = (const float*)d_in[35];
    const float* gng     = (const float*)d_in[36];
    const float* gnb     = (const float*)d_in[37];
    const float* eng     = (const float*)d_in[38];
    const float* enb     = (const float*)d_in[39];
    const float* Wout    = (const float*)d_in[40];
    const float* bout    = (const float*)d_in[41];
    const int*   kidx    = (const int*)d_in[42];
    const int*   eidx    = (const int*)d_in[43];
    float* outp = (float*)d_out;

    char* wsp = (char*)d_ws;
    auto alloc = [&](size_t nbytes) -> void* {
        void* p = (void*)wsp;
        wsp += (nbytes + 255) & ~(size_t)255;
        return p;
    };
    float* h     = (float*)alloc((size_t)MROWS * HHC * 4);
    unsigned short* hb = (unsigned short*)alloc((size_t)MROWS * HHC * 2);
    float* hBT   = (float*)alloc((size_t)MROWS * HHC * 4);
    float* bufC  = (float*)alloc((size_t)MROWS * 384 * 4);
    unsigned short* bufDb = (unsigned short*)alloc((size_t)MROWS * HHC * 2);
    float* ebuf  = (float*)alloc((size_t)EEC * DEC * 4);
    float* ec    = (float*)alloc((size_t)EEC * NHD * 2 * 4);
    float* P12   = (float*)alloc((size_t)NN * HHC * 4);
    float* mA    = (float*)alloc((size_t)NN * HHC * 4);
    unsigned short* mBb = (unsigned short*)alloc((size_t)NN * HHC * 2);
    float* tre   = (float*)alloc((size_t)T1C * HHC * 4);
    float* degmaxf = (float*)alloc(4);
    int* degi   = (int*)alloc((size_t)NN * 4);
    int* dst    = (int*)alloc((size_t)EEC * 4);
    int* srcA   = (int*)alloc((size_t)EEC * 4);
    int* srcCSR = (int*)alloc((size_t)EEC * 4);
    int* epos   = (int*)alloc((size_t)EEC * 4);
    int* rowptr = (int*)alloc((size_t)(NN + 1) * 4);
    int* cursor = (int*)alloc((size_t)NN * 4);
    unsigned short* awP   = (unsigned short*)alloc((size_t)LLC * 384 * 128 * 2);
    unsigned short* owP   = (unsigned short*)alloc((size_t)LLC * 128 * 128 * 2);
    unsigned short* f1P   = (unsigned short*)alloc((size_t)LLC * 256 * 128 * 2);
    unsigned short* f2P   = (unsigned short*)alloc((size_t)LLC * 128 * 256 * 2);
    unsigned short* WqkvP = (unsigned short*)alloc((size_t)LLC * 384 * 128 * 2);
    unsigned short* WoP   = (unsigned short*)alloc((size_t)LLC * 128 * 128 * 2);
    unsigned short* WoT   = (unsigned short*)alloc((size_t)LLC * 128 * 128 * 2);
    unsigned short* W12P  = (unsigned short*)alloc((size_t)LLC * 128 * 128 * 2);

    unsigned short* bufCb = (unsigned short*)bufC;
    unsigned short* Qc    = (unsigned short*)bufC;
    unsigned short* Kc    = Qc + (size_t)MROWS * HHC;
    unsigned short* Vc    = Kc + (size_t)MROWS * HHC;

    {
        auto cwp = [&](const float* W, unsigned short* Bp, int K, int N, int noff, int Ntot) {
            int total = LLC * K * N;
            convwp_k<<<(total + 255) / 256, 256, 0, stream>>>(W, Bp, LLC, K, N, noff, Ntot);
        };
        cwp(aw,  awP, 128, 384, 0, 384);
        cwp(ow,  owP, 128, 128, 0, 128);
        cwp(f1w, f1P, 128, 256, 0, 256);
        cwp(f2w, f2P, 256, 128, 0, 128);
        cwp(Wq,  WqkvP, 128, 128, 0,   384);
        cwp(Wk,  WqkvP, 128, 128, 128, 384);
        cwp(Wv,  WqkvP, 128, 128, 256, 384);
        cwp(Wo,  WoP, 128, 128, 0, 128);
        convwoT_k<<<(LLC * 128 * 128 + 255) / 256, 256, 0, stream>>>(Wo, WoT);
        convw12_k<<<(LLC * 128 * 128 + 255) / 256, 256, 0, stream>>>(e1w, W12P);
    }

    zero_deg_k<<<(NN + 255) / 256, 256, 0, stream>>>(degi);
    build_edges_k<<<(EEC + 255) / 256, 256, 0, stream>>>(eidx, dst, srcA, degi);
    scan_k<<<1, 256, 0, stream>>>(degi, rowptr, cursor, degmaxf);
    feat_k<<<(EEC + 255) / 256, 256, 0, stream>>>(dst, srcA, degi, degmaxf, cursor, srcCSR, epos, We, bE, ebuf);

    embed_k<<<MROWS / 4, 256, 0, stream>>>(Xk, temb, Win, bin, gin, bein, stepemb, kidx, h, hb);
    tre_k<<<T1C, 128, 0, stream>>>(temb, Wtr, btr, tre);

    // layer-0 edge coefficients (layers 1..3 are produced by the fused emlp)
    emea_k<<<(EEC + 255) / 256, 256, 0, stream>>>(ebuf, epos, Wem, bem, Wea, bea, ec);

    // layer-0 temporal qkv (layers 1..3 are produced by the fused EPI5 gemm)
    run_gemm2<128, 0, 2>(hb, awP, ab, nullptr, bufCb, nullptr, nullptr, nullptr, nullptr, MROWS, 384, stream);

    for (int l = 0; l < LLC; l++) {
        const unsigned short* owP_l   = owP   + (size_t)l * 128 * 128;
        const unsigned short* f1P_l   = f1P   + (size_t)l * 256 * 128;
        const unsigned short* f2P_l   = f2P   + (size_t)l * 128 * 256;
        const unsigned short* WqkvP_l = WqkvP + (size_t)l * 384 * 128;
        const unsigned short* WoP_l   = WoP   + (size_t)l * 128 * 128;
        const unsigned short* WoT_l   = WoT   + (size_t)l * 128 * 128;
        const unsigned short* W12P_l  = W12P  + (size_t)l * 128 * 128;
        const float* ob_l  = ob  + (size_t)l * HHC;
        const float* tng_l = tng + (size_t)l * HHC;
        const float* tnb_l = tnb + (size_t)l * HHC;
        const float* f1b_l = f1b + (size_t)l * 256;
        const float* f2b_l = f2b_ + (size_t)l * HHC;
        const float* fng_l = fng + (size_t)l * HHC;
        const float* fnb_l = fnb + (size_t)l * HHC;
        const float* bo_l  = bo  + (size_t)l * HHC;
        const float* e1wE_l = e1w + ((size_t)l * 272 + 256) * 64;
        const float* e1b_l = e1b + (size_t)l * 64;
        const float* e2w_l = e2w + (size_t)l * 64 * DEC;
        const float* e2b_l = e2b + (size_t)l * DEC;
        const float* gng_l = gng + (size_t)l * HHC;
        const float* gnb_l = gnb + (size_t)l * HHC;
        const float* eng_l = eng + (size_t)l * DEC;
        const float* enb_l = enb + (size_t)l * DEC;
        int ln = (l + 1 < LLC) ? l + 1 : l;
        const float* WemN = Wem + (size_t)ln * DEC * NHD;
        const float* bemN = bem + (size_t)ln * NHD;
        const float* WeaN = Wea + (size_t)ln * DEC * NHD;
        const float* beaN = bea + (size_t)ln * NHD;
        int doEc = (l + 1 < LLC) ? 1 : 0;
        const unsigned short* awP_n = awP + (size_t)ln * 384 * 128;
        const float* ab_n = ab + (size_t)ln * 3 * HHC;

        // temporal attention (qkv in bf16, produced by prev layer's fused EPI5 / layer-0 standalone)
        temporal_attn_k<<<BBC * NN, 128, 0, stream>>>(bufCb, bufDb);
        // fused Wo-proj + temporal LN + FFN + final LN + t_re + transpose + graph-QKV GEMM
        offn_k<<<MROWS / 32, 256, 0, stream>>>(bufDb, owP_l, ob_l, h, tng_l, tnb_l,
                                               f1P_l, f2P_l, f1b_l, f2b_l, fng_l, fnb_l,
                                               tre, WqkvP_l, hBT, Qc, Kc, Vc);
        // fused score + weighted aggregate (wave-per-(bt,n), 4 waves/block share bt)
        sagg_k<<<BTC * (NN / 4), 256, 0, stream>>>(Qc, Kc, Vc, rowptr, srcCSR, ec, bufDb);
        // hmean by linearity: mean(hBT) + mean(agg) @ Wo + bo
        hmean2_k<<<NN, 128, 0, stream>>>(hBT, bufDb, mA, mBb);
        // Wo + residual + final LN + transpose back to [B,N,T1,H] (+ next-layer temporal QKV)
        if (l + 1 < LLC)
            run_gemm2_ln_qkv<1>(bufDb, WoP_l, bo_l, h, hBT, gng_l, gnb_l, awP_n, ab_n, bufCb, stream);
        else
            run_gemm2_ln_qkv<0>(bufDb, WoP_l, bo_l, h, hBT, gng_l, gnb_l, nullptr, nullptr, nullptr, stream);
        // fused edge head: (mBb@WoT + mA + bo) -> bf16 -> @W12 -> P12 (LDS-staged)
        gemm_hm12_k<<<(NN + 31) / 32, 256, 0, stream>>>(mBb, WoT_l, mA, bo_l, W12P_l, P12);
        // per-edge MLP (in-place on ebuf) + next-layer edge coefficients
        emlp_k<<<EEC / 4, 256, 0, stream>>>(P12, dst, srcA, e1wE_l, e1b_l, e2w_l, e2b_l, eng_l, enb_l, ebuf,
                                            epos, WemN, bemN, WeaN, beaN, ec, doEc);
    }

    out_k<<<MROWS / 4, 256, 0, stream>>>(h, Wout, bout, outp);
}

// Round 20
// 925.609 us; speedup vs baseline: 1.0384x; 1.0384x over previous
//
#include <hip/hip_runtime.h>
#include <math.h>

#define NN 2000
#define T1C 12
#define BBC 2
#define HHC 128
#define NHD 4
#define DFD 32
#define LLC 4
#define DEC 16
#define TEC 16
#define CINC 12
#define E0C 32000
#define EEC 34000
#define BTC 24
#define MROWS 48000
#define EPSLN 1e-5f
#define SCALEQK 0.17677669529663687f

typedef __attribute__((ext_vector_type(8))) short short8;
typedef __attribute__((ext_vector_type(4))) float f32x4;

// ---------------- helpers ----------------

__device__ __forceinline__ unsigned short f2b(float f)
{
    unsigned u = __float_as_uint(f);
    return (unsigned short)((u + 0x7FFF + ((u >> 16) & 1)) >> 16);
}

__device__ __forceinline__ float b2f(unsigned short h)
{
    return __uint_as_float(((unsigned)h) << 16);
}

// ---------------- weight conversions ----------------

__global__ __launch_bounds__(256) void convwp_k(const float* __restrict__ W, unsigned short* __restrict__ Bp,
                                                int LN_, int K, int N, int noff, int Ntot)
{
    int idx = blockIdx.x * blockDim.x + threadIdx.x;
    int total = LN_ * K * N;
    if (idx >= total) return;
    int l = idx / (K * N);
    int r = idx - l * (K * N);
    int k = r / N;
    int n = r - k * N + noff;
    size_t off = (size_t)l * K * Ntot +
                 ((size_t)((n >> 4) * (K >> 5) + (k >> 5)) << 9) +
                 (((k >> 3) & 3) << 7) + ((n & 15) << 3) + (k & 7);
    Bp[off] = f2b(W[idx]);
}

// W12P[l][c][k] (c=0..127 output col, k=0..127) = e1w[l][c<64? k : k+128][c&63]
__global__ __launch_bounds__(256) void convw12_k(const float* __restrict__ e1w, unsigned short* __restrict__ W12P)
{
    int idx = blockIdx.x * blockDim.x + threadIdx.x;
    if (idx >= LLC * 128 * 128) return;
    int l = idx >> 14;
    int r = idx & 16383;
    int c = r >> 7, k = r & 127;
    int sk = (c < 64) ? k : k + 128;
    int sc = c & 63;
    W12P[idx] = f2b(e1w[((size_t)l * 272 + sk) * 64 + sc]);
}

// WoT[l][c][k] = Wo[l][k][c]
__global__ __launch_bounds__(256) void convwoT_k(const float* __restrict__ Wo, unsigned short* __restrict__ WoT)
{
    int idx = blockIdx.x * blockDim.x + threadIdx.x;
    if (idx >= LLC * 128 * 128) return;
    int l = idx >> 14;
    int r = idx & 16383;
    int c = r >> 7, k = r & 127;
    WoT[idx] = f2b(Wo[((size_t)l * 128 + k) * 128 + c]);
}

// ---------------- gemm2: 128x128-tile LDS-staged MFMA GEMM ----------------
// EPI: 0=none 1=gelu 2=res-add 3=res+LN 4=res+LN+t_re+transpose to [BT,N,H]
//      5=res+LN + transpose back to [B,N,T1,H]

template<int K, int EPI, int OUTM>
__global__ __launch_bounds__(256) void gemm2_k(
    const unsigned short* __restrict__ A, const unsigned short* __restrict__ Bp,
    const float* __restrict__ bias, float* __restrict__ C, unsigned short* __restrict__ Cb,
    const float* __restrict__ res, const float* __restrict__ gam, const float* __restrict__ bet,
    const float* __restrict__ trep,
    int M, int Ntot)
{
    __shared__ unsigned short A_s[128 * 16 * 8];
    __shared__ float red2[2][128][2];

    int tid = threadIdx.x;
    int w = tid >> 6, lane = tid & 63;
    int wr = w & 1, wc = w >> 1;
    int quad = lane >> 4, lr = lane & 15;

    const unsigned short* abase = A + (size_t)blockIdx.x * 128 * K;
    int ntg0 = blockIdx.y * 8 + wc * 4;

    f32x4 acc[4][4];
#pragma unroll
    for (int mt = 0; mt < 4; mt++)
#pragma unroll
        for (int nt = 0; nt < 4; nt++) acc[mt][nt] = (f32x4){0.f, 0.f, 0.f, 0.f};

#pragma unroll
    for (int kb = 0; kb < K; kb += 128) {
        if (kb) __syncthreads();
#pragma unroll
        for (int j = 0; j < 8; j++) {
            int s = j * 256 + tid;
            int row = s >> 4, ks = s & 15;
            int ko = ks ^ (row & 15);
            uint4 d = *(const uint4*)(abase + (size_t)row * K + kb + ko * 8);
            *(uint4*)(A_s + s * 8) = d;
        }
        __syncthreads();
#pragma unroll
        for (int k0 = 0; k0 < 128; k0 += 32) {
            short8 af[4], bf[4];
#pragma unroll
            for (int mt = 0; mt < 4; mt++) {
                int row_l = wr * 64 + mt * 16 + lr;
                int koct = (k0 >> 3) + quad;
                int slot = row_l * 16 + (koct ^ lr);
                af[mt] = *(const short8*)(A_s + slot * 8);
            }
#pragma unroll
            for (int nt = 0; nt < 4; nt++) {
                size_t off = ((size_t)(ntg0 + nt) * (K >> 5) + ((kb + k0) >> 5)) * 512 + lane * 8;
                bf[nt] = *(const short8*)(Bp + off);
            }
#pragma unroll
            for (int mt = 0; mt < 4; mt++)
#pragma unroll
                for (int nt = 0; nt < 4; nt++)
                    acc[mt][nt] = __builtin_amdgcn_mfma_f32_16x16x32_bf16(af[mt], bf[nt], acc[mt][nt], 0, 0, 0);
        }
    }

    int rbase = blockIdx.x * 128 + wr * 64;
    int cbase = blockIdx.y * 128 + wc * 64;

    if constexpr (EPI != 3 && EPI != 4 && EPI != 5) {
#pragma unroll
        for (int mt = 0; mt < 4; mt++) {
#pragma unroll
            for (int nt = 0; nt < 4; nt++) {
                int colg = cbase + nt * 16 + lr;
                float bv = bias ? bias[colg] : 0.f;
#pragma unroll
                for (int i = 0; i < 4; i++) {
                    int row = rbase + mt * 16 + quad * 4 + i;
                    float x = acc[mt][nt][i] + bv;
                    if constexpr (EPI == 1) x = 0.5f * x * (1.f + erff(x * 0.70710678118654752f));
                    if constexpr (EPI == 2) x = res[(size_t)row * Ntot + colg] + x;
                    if constexpr (OUTM & 1) C[(size_t)row * Ntot + colg] = x;
                    if constexpr (OUTM & 4)
                        Cb[(size_t)blockIdx.y * M * 128 + (size_t)row * 128 + (wc * 64 + nt * 16 + lr)] = f2b(x);
                    else if constexpr (OUTM & 2)
                        Cb[(size_t)row * Ntot + colg] = f2b(x);
                }
            }
        }
    } else {
        float s[4][4], s2l[4][4];
#pragma unroll
        for (int mt = 0; mt < 4; mt++)
#pragma unroll
            for (int i = 0; i < 4; i++) { s[mt][i] = 0.f; s2l[mt][i] = 0.f; }
#pragma unroll
        for (int mt = 0; mt < 4; mt++) {
#pragma unroll
            for (int nt = 0; nt < 4; nt++) {
                int colg = cbase + nt * 16 + lr;
                float bv = bias[colg];
#pragma unroll
                for (int i = 0; i < 4; i++) {
                    int row = rbase + mt * 16 + quad * 4 + i;
                    float x = acc[mt][nt][i] + bv + res[(size_t)row * 128 + colg];
                    acc[mt][nt][i] = x;
                    s[mt][i] += x;
                    s2l[mt][i] += x * x;
                }
            }
        }
#pragma unroll
        for (int m = 1; m < 16; m <<= 1) {
#pragma unroll
            for (int mt = 0; mt < 4; mt++)
#pragma unroll
                for (int i = 0; i < 4; i++) {
                    s[mt][i]  += __shfl_xor(s[mt][i], m, 64);
                    s2l[mt][i] += __shfl_xor(s2l[mt][i], m, 64);
                }
        }
        if (lr == 0) {
#pragma unroll
            for (int mt = 0; mt < 4; mt++)
#pragma unroll
                for (int i = 0; i < 4; i++) {
                    int rl = wr * 64 + mt * 16 + quad * 4 + i;
                    red2[wc][rl][0] = s[mt][i];
                    red2[wc][rl][1] = s2l[mt][i];
                }
        }
        __syncthreads();
#pragma unroll
        for (int mt = 0; mt < 4; mt++) {
#pragma unroll
            for (int i = 0; i < 4; i++) {
                int rl = wr * 64 + mt * 16 + quad * 4 + i;
                float st  = red2[0][rl][0] + red2[1][rl][0];
                float s2t = red2[0][rl][1] + red2[1][rl][1];
                float mu = st * (1.f / 128.f);
                float rstd = rsqrtf(s2t * (1.f / 128.f) - mu * mu + EPSLN);
                int row = rbase + mt * 16 + quad * 4 + i;
                if constexpr (EPI == 4) {
                    int t = row % T1C;
                    int bn = row / T1C;
                    int b = bn / NN;
                    int n = bn - b * NN;
                    size_t rowp = (size_t)(b * T1C + t) * NN + n;
                    const float* trow = trep + t * HHC;
#pragma unroll
                    for (int nt = 0; nt < 4; nt++) {
                        int colg = cbase + nt * 16 + lr;
                        float y = (acc[mt][nt][i] - mu) * rstd * gam[colg] + bet[colg] + trow[colg];
                        C[rowp * 128 + colg] = y;
                        Cb[rowp * 128 + colg] = f2b(y);
                    }
                } else if constexpr (EPI == 5) {
                    int bt = row / NN, n = row - bt * NN;
                    int b = bt / T1C, t = bt - b * T1C;
                    size_t rowp = ((size_t)(b * NN + n)) * T1C + t;
#pragma unroll
                    for (int nt = 0; nt < 4; nt++) {
                        int colg = cbase + nt * 16 + lr;
                        float y = (acc[mt][nt][i] - mu) * rstd * gam[colg] + bet[colg];
                        C[rowp * 128 + colg] = y;
                        Cb[rowp * 128 + colg] = f2b(y);
                    }
                } else {
#pragma unroll
                    for (int nt = 0; nt < 4; nt++) {
                        int colg = cbase + nt * 16 + lr;
                        float y = (acc[mt][nt][i] - mu) * rstd * gam[colg] + bet[colg];
                        if constexpr (OUTM & 1) C[(size_t)row * 128 + colg] = y;
                        if constexpr (OUTM & 2) Cb[(size_t)row * 128 + colg] = f2b(y);
                    }
                }
            }
        }
    }
}

template<int K, int EPI, int OUTM>
static void run_gemm2(const unsigned short* A, const unsigned short* Bp, const float* bias,
                      float* C, unsigned short* Cb, const float* res, const float* g, const float* be,
                      const float* trep, int M, int Ntot, hipStream_t stream)
{
    dim3 grid(M / 128, Ntot / 128);
    gemm2_k<K, EPI, OUTM><<<grid, 256, 0, stream>>>(A, Bp, bias, C, Cb, res, g, be, trep, M, Ntot);
}

// ---------------- fused Wo+LN+FFN+LN + graph-QKV GEMM (32-row tile) ----------------

__global__ __launch_bounds__(256) void offn_k(
    const unsigned short* __restrict__ A,      // attn out bf16 [MROWS][128]
    const unsigned short* __restrict__ Wp,     // WoP layer slice (K=128, Ntot=128 packed)
    const float* __restrict__ ob_l,
    const float* __restrict__ resh,            // h_prev (f32)
    const float* __restrict__ tng_l, const float* __restrict__ tnb_l,
    const unsigned short* __restrict__ F1p,    // f1P layer slice (K=128, N=256 packed)
    const unsigned short* __restrict__ F2p,    // f2P layer slice (K=256, N=128 packed)
    const float* __restrict__ f1b_l, const float* __restrict__ f2b_l,
    const float* __restrict__ fng_l, const float* __restrict__ fnb_l,
    const float* __restrict__ trep,
    const unsigned short* __restrict__ Wqkv,   // WqkvP layer slice (K=128, Ntot=384 packed)
    float* __restrict__ C,                     // hBT (f32, transposed)
    unsigned short* __restrict__ Qc, unsigned short* __restrict__ Kc, unsigned short* __restrict__ Vc)
{
    __shared__ unsigned short A_s[32 * 16 * 8];
    __shared__ unsigned short M_s[32 * 16 * 8];
    __shared__ float red2[2][32][2];

    int tid = threadIdx.x;
    int w = tid >> 6, lane = tid & 63;
    int wr = w & 1, wc = w >> 1;
    int quad = lane >> 4, lr = lane & 15;

    const unsigned short* abase = A + (size_t)blockIdx.x * 32 * 128;

#pragma unroll
    for (int j = 0; j < 2; j++) {
        int s = j * 256 + tid;
        int row = s >> 4, ks = s & 15;
        int ko = ks ^ (row & 15);
        uint4 d = *(const uint4*)(abase + (size_t)row * 128 + ko * 8);
        *(uint4*)(A_s + s * 8) = d;
    }
    __syncthreads();

    // ---- Wo GEMM (K=128) ----
    f32x4 wacc[4];
#pragma unroll
    for (int nt = 0; nt < 4; nt++) wacc[nt] = (f32x4){0.f, 0.f, 0.f, 0.f};
#pragma unroll
    for (int k0 = 0; k0 < 128; k0 += 32) {
        int row_l = wr * 16 + lr;
        int koct = (k0 >> 3) + quad;
        int slot = row_l * 16 + (koct ^ lr);
        short8 af = *(const short8*)(A_s + slot * 8);
        short8 bf[4];
#pragma unroll
        for (int nt = 0; nt < 4; nt++) {
            size_t off = ((size_t)(wc * 4 + nt) * 4 + (k0 >> 5)) * 512 + lane * 8;
            bf[nt] = *(const short8*)(Wp + off);
        }
#pragma unroll
        for (int nt = 0; nt < 4; nt++)
            wacc[nt] = __builtin_amdgcn_mfma_f32_16x16x32_bf16(af, bf[nt], wacc[nt], 0, 0, 0);
    }

    int rbase = blockIdx.x * 32 + wr * 16;
    int cbase = wc * 64;

    // ---- temporal-LN epilogue: y kept in registers, bf16(y) staged into A_s ----
    float yv[4][4];
    {
        float s1[4], s2v[4];
#pragma unroll
        for (int i = 0; i < 4; i++) { s1[i] = 0.f; s2v[i] = 0.f; }
#pragma unroll
        for (int nt = 0; nt < 4; nt++) {
            int colg = cbase + nt * 16 + lr;
            float bv = ob_l[colg];
#pragma unroll
            for (int i = 0; i < 4; i++) {
                int row = rbase + quad * 4 + i;
                float x = wacc[nt][i] + bv + resh[(size_t)row * 128 + colg];
                yv[nt][i] = x;
                s1[i] += x;
                s2v[i] += x * x;
            }
        }
#pragma unroll
        for (int m = 1; m < 16; m <<= 1) {
#pragma unroll
            for (int i = 0; i < 4; i++) {
                s1[i]  += __shfl_xor(s1[i], m, 64);
                s2v[i] += __shfl_xor(s2v[i], m, 64);
            }
        }
        if (lr == 0) {
#pragma unroll
            for (int i = 0; i < 4; i++) {
                int rl = wr * 16 + quad * 4 + i;
                red2[wc][rl][0] = s1[i];
                red2[wc][rl][1] = s2v[i];
            }
        }
        __syncthreads();
#pragma unroll
        for (int i = 0; i < 4; i++) {
            int rl = wr * 16 + quad * 4 + i;
            float st  = red2[0][rl][0] + red2[1][rl][0];
            float s2t = red2[0][rl][1] + red2[1][rl][1];
            float mu = st * (1.f / 128.f);
            float rstd = rsqrtf(s2t * (1.f / 128.f) - mu * mu + EPSLN);
            int row = wr * 16 + quad * 4 + i;
#pragma unroll
            for (int nt = 0; nt < 4; nt++) {
                int col = cbase + nt * 16 + lr;
                float y = (yv[nt][i] - mu) * rstd * tng_l[col] + tnb_l[col];
                yv[nt][i] = y;
                int cchunk = col >> 3, celem = col & 7;
                int ks = cchunk ^ (row & 15);
                A_s[(row * 16 + ks) * 8 + celem] = f2b(y);
            }
        }
    }
    __syncthreads();

    // ---- FFN: f1 + gelu + f2 ----
    f32x4 facc[4];
#pragma unroll
    for (int nt = 0; nt < 4; nt++) facc[nt] = (f32x4){0.f, 0.f, 0.f, 0.f};

#pragma unroll
    for (int half = 0; half < 2; half++) {
        f32x4 macc[4];
#pragma unroll
        for (int nt = 0; nt < 4; nt++) macc[nt] = (f32x4){0.f, 0.f, 0.f, 0.f};
#pragma unroll
        for (int k0 = 0; k0 < 128; k0 += 32) {
            int row_l = wr * 16 + lr;
            int koct = (k0 >> 3) + quad;
            int slot = row_l * 16 + (koct ^ lr);
            short8 af = *(const short8*)(A_s + slot * 8);
            short8 bf[4];
#pragma unroll
            for (int nt = 0; nt < 4; nt++) {
                size_t off = ((size_t)(half * 8 + wc * 4 + nt) * 4 + (k0 >> 5)) * 512 + lane * 8;
                bf[nt] = *(const short8*)(F1p + off);
            }
#pragma unroll
            for (int nt = 0; nt < 4; nt++)
                macc[nt] = __builtin_amdgcn_mfma_f32_16x16x32_bf16(af, bf[nt], macc[nt], 0, 0, 0);
        }
        if (half) __syncthreads();
#pragma unroll
        for (int nt = 0; nt < 4; nt++) {
            int col = wc * 64 + nt * 16 + lr;
            float bv = f1b_l[half * 128 + col];
            int cchunk = col >> 3, celem = col & 7;
#pragma unroll
            for (int i = 0; i < 4; i++) {
                int row = wr * 16 + quad * 4 + i;
                float x = macc[nt][i] + bv;
                x = 0.5f * x * (1.f + erff(x * 0.70710678118654752f));
                int ks = cchunk ^ (row & 15);
                M_s[(row * 16 + ks) * 8 + celem] = f2b(x);
            }
        }
        __syncthreads();
#pragma unroll
        for (int k0 = 0; k0 < 128; k0 += 32) {
            int row_l = wr * 16 + lr;
            int koct = (k0 >> 3) + quad;
            int slot = row_l * 16 + (koct ^ lr);
            short8 af = *(const short8*)(M_s + slot * 8);
            short8 bf[4];
#pragma unroll
            for (int nt = 0; nt < 4; nt++) {
                size_t off = ((size_t)(wc * 4 + nt) * 8 + ((half * 128 + k0) >> 5)) * 512 + lane * 8;
                bf[nt] = *(const short8*)(F2p + off);
            }
#pragma unroll
            for (int nt = 0; nt < 4; nt++)
                facc[nt] = __builtin_amdgcn_mfma_f32_16x16x32_bf16(af, bf[nt], facc[nt], 0, 0, 0);
        }
    }

    // ---- final epilogue: res(yv) + LN + t_re; write hBT (f32) + stage bf16 into A_s ----
    float s[4], s2l[4];
#pragma unroll
    for (int i = 0; i < 4; i++) { s[i] = 0.f; s2l[i] = 0.f; }
#pragma unroll
    for (int nt = 0; nt < 4; nt++) {
        int colg = cbase + nt * 16 + lr;
        float bv = f2b_l[colg];
#pragma unroll
        for (int i = 0; i < 4; i++) {
            float x = facc[nt][i] + bv + yv[nt][i];
            facc[nt][i] = x;
            s[i] += x;
            s2l[i] += x * x;
        }
    }
#pragma unroll
    for (int m = 1; m < 16; m <<= 1) {
#pragma unroll
        for (int i = 0; i < 4; i++) {
            s[i]  += __shfl_xor(s[i], m, 64);
            s2l[i] += __shfl_xor(s2l[i], m, 64);
        }
    }
    if (lr == 0) {
#pragma unroll
        for (int i = 0; i < 4; i++) {
            int rl = wr * 16 + quad * 4 + i;
            red2[wc][rl][0] = s[i];
            red2[wc][rl][1] = s2l[i];
        }
    }
    __syncthreads();
    size_t rowp4[4];
#pragma unroll
    for (int i = 0; i < 4; i++) {
        int rl = wr * 16 + quad * 4 + i;
        float st  = red2[0][rl][0] + red2[1][rl][0];
        float s2t = red2[0][rl][1] + red2[1][rl][1];
        float mu = st * (1.f / 128.f);
        float rstd = rsqrtf(s2t * (1.f / 128.f) - mu * mu + EPSLN);
        int row = rbase + quad * 4 + i;
        int t = row % T1C;
        int bn = row / T1C;
        int b = bn / NN;
        int n = bn - b * NN;
        size_t rowp = (size_t)(b * T1C + t) * NN + n;
        rowp4[i] = rowp;
        const float* trow = trep + t * HHC;
        int rloc = wr * 16 + quad * 4 + i;
#pragma unroll
        for (int nt = 0; nt < 4; nt++) {
            int colg = cbase + nt * 16 + lr;
            float y = (facc[nt][i] - mu) * rstd * fng_l[colg] + fnb_l[colg] + trow[colg];
            C[rowp * 128 + colg] = y;
            int cchunk = colg >> 3, celem = colg & 7;
            int ks = cchunk ^ (rloc & 15);
            A_s[(rloc * 16 + ks) * 8 + celem] = f2b(y);
        }
    }
    __syncthreads();

    // ---- graph QKV GEMM: each wave 16 rows (wr) x 192 cols (wc), 3 groups of 4 tiles ----
#pragma unroll
    for (int g3 = 0; g3 < 3; g3++) {
        f32x4 qacc[4];
#pragma unroll
        for (int nt = 0; nt < 4; nt++) qacc[nt] = (f32x4){0.f, 0.f, 0.f, 0.f};
#pragma unroll
        for (int k0 = 0; k0 < 128; k0 += 32) {
            int row_l = wr * 16 + lr;
            int koct = (k0 >> 3) + quad;
            int slot = row_l * 16 + (koct ^ lr);
            short8 af = *(const short8*)(A_s + slot * 8);
            short8 bf[4];
#pragma unroll
            for (int nt = 0; nt < 4; nt++) {
                size_t off = ((size_t)(wc * 12 + g3 * 4 + nt) * 4 + (k0 >> 5)) * 512 + lane * 8;
                bf[nt] = *(const short8*)(Wqkv + off);
            }
#pragma unroll
            for (int nt = 0; nt < 4; nt++)
                qacc[nt] = __builtin_amdgcn_mfma_f32_16x16x32_bf16(af, bf[nt], qacc[nt], 0, 0, 0);
        }
#pragma unroll
        for (int nt = 0; nt < 4; nt++) {
            int colg = wc * 192 + (g3 * 4 + nt) * 16 + lr;
            unsigned short* dstbuf;
            int col;
            if (colg < 128)      { dstbuf = Qc; col = colg; }
            else if (colg < 256) { dstbuf = Kc; col = colg - 128; }
            else                 { dstbuf = Vc; col = colg - 256; }
#pragma unroll
            for (int i = 0; i < 4; i++)
                dstbuf[rowp4[i] * 128 + col] = f2b(qacc[nt][i]);
        }
    }
}

// ---------------- fused hm chain: hm = f2b(mBb@WoT + mA + bo) -> P12 = hm@W12 ----------------

__global__ __launch_bounds__(256) void gemm_hm12_k(
    const unsigned short* __restrict__ A,    // mBb
    const unsigned short* __restrict__ WT,   // WoT layer slice [c][k]
    const float* __restrict__ mA, const float* __restrict__ bo,
    const unsigned short* __restrict__ W12,  // W12P layer slice [c][k]
    float* __restrict__ P12)
{
    __shared__ unsigned short A_s[32 * 16 * 8];
    const int M = NN, K = 128;
    int tid = threadIdx.x;
    int w = tid >> 6, lane = tid & 63;
    int wr = w & 1, wc = w >> 1;
    int r0 = blockIdx.x * 32 + wr * 16;
    int c0 = wc * 64;
    int lr = lane & 15, quad = lane >> 4;
    int kq = quad * 8;
    int arow = r0 + lr; if (arow >= M) arow = M - 1;
    const unsigned short* ap = A + (size_t)arow * K + kq;
    const unsigned short* wp = WT + (size_t)(c0 + lr) * K + kq;

    // phase 1: mBb @ WoT
    f32x4 acc[4];
#pragma unroll
    for (int t = 0; t < 4; t++) acc[t] = (f32x4){0.f, 0.f, 0.f, 0.f};
    for (int k0 = 0; k0 < K; k0 += 32) {
        short8 a = *(const short8*)(ap + k0);
#pragma unroll
        for (int t = 0; t < 4; t++) {
            short8 b = *(const short8*)(wp + (size_t)t * 16 * K + k0);
            acc[t] = __builtin_amdgcn_mfma_f32_16x16x32_bf16(a, b, acc[t], 0, 0, 0);
        }
    }
    // epilogue: + mA + bo -> f2b, staged into LDS (swizzled A-fragment layout)
#pragma unroll
    for (int t = 0; t < 4; t++) {
        int col = c0 + t * 16 + lr;
        int cchunk = col >> 3, celem = col & 7;
#pragma unroll
        for (int i = 0; i < 4; i++) {
            int row = r0 + quad * 4 + i;
            int rr = row < M ? row : M - 1;
            float x = acc[t][i] + mA[(size_t)rr * 128 + col] + bo[col];
            int rloc = wr * 16 + quad * 4 + i;
            int ks = cchunk ^ (rloc & 15);
            A_s[(rloc * 16 + ks) * 8 + celem] = f2b(x);
        }
    }
    __syncthreads();

    // phase 2: P12 = hm @ W12
    f32x4 acc2[4];
#pragma unroll
    for (int t = 0; t < 4; t++) acc2[t] = (f32x4){0.f, 0.f, 0.f, 0.f};
    const unsigned short* wp2 = W12 + (size_t)(c0 + lr) * 128 + kq;
#pragma unroll
    for (int k0 = 0; k0 < 128; k0 += 32) {
        int row_l = wr * 16 + lr;
        int koct = (k0 >> 3) + quad;
        int slot = row_l * 16 + (koct ^ lr);
        short8 af = *(const short8*)(A_s + slot * 8);
#pragma unroll
        for (int t = 0; t < 4; t++) {
            short8 b = *(const short8*)(wp2 + (size_t)t * 16 * 128 + k0);
            acc2[t] = __builtin_amdgcn_mfma_f32_16x16x32_bf16(af, b, acc2[t], 0, 0, 0);
        }
    }
#pragma unroll
    for (int t = 0; t < 4; t++) {
        int col = c0 + t * 16 + lr;
#pragma unroll
        for (int i = 0; i < 4; i++) {
            int row = r0 + quad * 4 + i;
            if (row < M) P12[(size_t)row * 128 + col] = acc2[t][i];
        }
    }
}

// ---------------- fused per-edge MLP (+ next-layer edge coefficients) ----------------

__global__ __launch_bounds__(256) void emlp_k(const float* __restrict__ P12,
                                              const int* __restrict__ dst, const int* __restrict__ src,
                                              const float* __restrict__ e1wE, const float* __restrict__ e1b_l,
                                              const float* __restrict__ e2w_l, const float* __restrict__ e2b_l,
                                              const float* __restrict__ g, const float* __restrict__ be,
                                              float* __restrict__ e,
                                              const int* __restrict__ epos,
                                              const float* __restrict__ WemN, const float* __restrict__ bemN,
                                              const float* __restrict__ WeaN, const float* __restrict__ beaN,
                                              float* __restrict__ ec, int doEc)
{
    __shared__ float tl[4][64];
    int wv = threadIdx.x >> 6, l = threadIdx.x & 63;
    int r = blockIdx.x * 4 + wv;           // EEC = 34000 = 8500*4, no remainder
    int d = dst[r], s = src[r];
    const float* ep = e + (size_t)r * DEC;
    float t = P12[(size_t)d * 128 + l] + P12[(size_t)s * 128 + 64 + l] + e1b_l[l];
#pragma unroll
    for (int k = 0; k < DEC; k++) t += ep[k] * e1wE[k * 64 + l];
    t = 0.5f * t * (1.f + erff(t * 0.70710678118654752f));
    tl[wv][l] = t;
    __syncthreads();
    int c = l & 15, kq = l >> 4;
    float p = 0.f;
#pragma unroll
    for (int j = 0; j < 16; j++) p += tl[wv][kq * 16 + j] * e2w_l[(kq * 16 + j) * 16 + c];
    p += __shfl_xor(p, 16, 64);
    p += __shfl_xor(p, 32, 64);
    float x = p + e2b_l[c] + ep[c];
    float s1 = x, s2 = x * x;
#pragma unroll
    for (int m = 1; m < 16; m <<= 1) {
        s1 += __shfl_xor(s1, m, 64);
        s2 += __shfl_xor(s2, m, 64);
    }
    float mu = s1 * (1.f / 16.f);
    float rstd = rsqrtf(s2 * (1.f / 16.f) - mu * mu + EPSLN);
    float y = (x - mu) * rstd * g[c] + be[c];
    if (l < 16) e[(size_t)r * DEC + c] = y;

    if (doEc) {
        int hh = l >> 4;      // head = replica group 0..3
        float pem = y * WemN[c * NHD + hh];
        float pea = y * WeaN[c * NHD + hh];
#pragma unroll
        for (int m = 1; m < 16; m <<= 1) {
            pem += __shfl_xor(pem, m, 64);
            pea += __shfl_xor(pea, m, 64);
        }
        if (c == 0) {
            int pos = epos[r];
            ec[(size_t)pos * 8 + hh * 2]     = (pem + bemN[hh] + 1.f) * SCALEQK;
            ec[(size_t)pos * 8 + hh * 2 + 1] = pea + beaN[hh];
        }
    }
}

// ---------------- graph precompute ----------------

__global__ __launch_bounds__(256) void zero_deg_k(int* __restrict__ degi)
{
    int i = blockIdx.x * blockDim.x + threadIdx.x;
    if (i < NN) degi[i] = 0;
}

__global__ __launch_bounds__(256) void build_edges_k(const int* __restrict__ eidx,
                                                     int* __restrict__ dst, int* __restrict__ src,
                                                     int* __restrict__ degi)
{
    int e = blockIdx.x * blockDim.x + threadIdx.x;
    if (e >= EEC) return;
    int d, s;
    if (e < E0C) { d = eidx[e]; s = eidx[E0C + e]; }
    else { d = e - E0C; s = e - E0C; }
    dst[e] = d;
    src[e] = s;
    atomicAdd(&degi[d], 1);
}

__global__ __launch_bounds__(256) void scan_k(const int* __restrict__ degi, int* __restrict__ rowptr,
                                              int* __restrict__ cursor, float* __restrict__ degmaxf)
{
    __shared__ int ssum[256];
    __shared__ int smx[256];
    int tid = threadIdx.x;
    int vals[8];
    int s = 0, mx = 0;
    int base = tid * 8;
#pragma unroll
    for (int j = 0; j < 8; j++) {
        int idx = base + j;
        int v = (idx < NN) ? degi[idx] : 0;
        vals[j] = v; s += v; mx = max(mx, v);
    }
    ssum[tid] = s; smx[tid] = mx;
    __syncthreads();
    for (int off = 1; off < 256; off <<= 1) {
        int t = (tid >= off) ? ssum[tid - off] : 0;
        __syncthreads();
        ssum[tid] += t;
        __syncthreads();
    }
    for (int off = 128; off > 0; off >>= 1) {
        if (tid < off) smx[tid] = max(smx[tid], smx[tid + off]);
        __syncthreads();
    }
    if (tid == 0) *degmaxf = fmaxf((float)smx[0], 1.f);
    int running = ssum[tid] - s;
#pragma unroll
    for (int j = 0; j < 8; j++) {
        int idx = base + j;
        if (idx < NN) { rowptr[idx] = running; cursor[idx] = running; running += vals[j]; }
    }
    if (tid == 255) rowptr[NN] = ssum[255];
}

__global__ __launch_bounds__(256) void feat_k(const int* __restrict__ dst, const int* __restrict__ src,
                                              const int* __restrict__ degi, const float* __restrict__ degmaxf,
                                              int* __restrict__ cursor, int* __restrict__ srcCSR,
                                              int* __restrict__ epos,
                                              const float* __restrict__ We, const float* __restrict__ bE,
                                              float* __restrict__ e)
{
    int ei = blockIdx.x * blockDim.x + threadIdx.x;
    if (ei >= EEC) return;
    int d = dst[ei], s = src[ei];
    int pos = atomicAdd(&cursor[d], 1);
    srcCSR[pos] = s;
    epos[ei] = pos;
    float dm = *degmaxf;
    float degd = (float)degi[d], degs = (float)degi[s];
    float f0 = 1.f / fmaxf(degd, 1.f);
    float f1 = degs / dm, f2 = degd / dm;
#pragma unroll
    for (int c = 0; c < DEC; c++)
        e[ei * DEC + c] = bE[c] + f0 * We[c] + f1 * We[DEC + c] + f2 * We[2 * DEC + c];
}

// ---------------- embedding: wave-per-row, shfl-only reduction ----------------

__global__ __launch_bounds__(256) void embed_k(const float* __restrict__ Xk, const float* __restrict__ temb,
                                               const float* __restrict__ Win, const float* __restrict__ bin,
                                               const float* __restrict__ g, const float* __restrict__ be,
                                               const float* __restrict__ stepemb, const int* __restrict__ kidx,
                                               float* __restrict__ h, unsigned short* __restrict__ hb)
{
    int row = blockIdx.x * 4 + (threadIdx.x >> 6);
    int l = threadIdx.x & 63;
    int t = row % T1C;
    int bn = row / T1C;
    int b = bn / NN;
    const float* xk = Xk + (size_t)row * CINC;
    const float* tp = temb + t * TEC;
    float acc0 = bin[l], acc1 = bin[l + 64];
#pragma unroll
    for (int k = 0; k < CINC; k++) {
        float xv = xk[k];
        acc0 += xv * Win[k * HHC + l];
        acc1 += xv * Win[k * HHC + l + 64];
    }
#pragma unroll
    for (int k = 0; k < TEC; k++) {
        float xv = tp[k];
        acc0 += xv * Win[(CINC + k) * HHC + l];
        acc1 += xv * Win[(CINC + k) * HHC + l + 64];
    }
    float s = acc0 + acc1, s2 = acc0 * acc0 + acc1 * acc1;
#pragma unroll
    for (int m = 32; m >= 1; m >>= 1) {
        s  += __shfl_xor(s, m, 64);
        s2 += __shfl_xor(s2, m, 64);
    }
    float mu = s * (1.f / 128.f);
    float rstd = rsqrtf(s2 * (1.f / 128.f) - mu * mu + EPSLN);
    const float* se = stepemb + (size_t)kidx[b] * HHC;
    float v0 = (acc0 - mu) * rstd * g[l] + be[l] + se[l];
    float v1 = (acc1 - mu) * rstd * g[l + 64] + be[l + 64] + se[l + 64];
    size_t ob = (size_t)row * HHC;
    h[ob + l] = v0;
    h[ob + l + 64] = v1;
    hb[ob + l] = f2b(v0);
    hb[ob + l + 64] = f2b(v1);
}

__global__ __launch_bounds__(128) void tre_k(const float* __restrict__ temb, const float* __restrict__ Wtr,
                                             const float* __restrict__ btr, float* __restrict__ tre)
{
    int t = blockIdx.x, c = threadIdx.x;
    float acc = btr[c];
#pragma unroll
    for (int k = 0; k < TEC; k++) acc += temb[t * TEC + k] * Wtr[k * HHC + c];
    tre[t * HHC + c] = acc;
}

// ---------------- temporal attention: raw-bf16 LDS staging ----------------

__global__ __launch_bounds__(128) void temporal_attn_k(const unsigned short* __restrict__ qkvb,
                                                       unsigned short* __restrict__ outb)
{
    int bn = blockIdx.x;
    __shared__ unsigned short qkv_s[T1C][408];
    __shared__ float s[NHD][T1C][T1C];
    int tid = threadIdx.x;
    int hh = tid >> 5, lane = tid & 31;
    const unsigned short* base = qkvb + (size_t)bn * T1C * 384;
    for (int cIdx = tid; cIdx < 576; cIdx += 128) {
        uint4 d = *(const uint4*)(base + cIdx * 8);
        int t = cIdx / 48;
        int c0 = (cIdx - t * 48) * 8;
        *(uint4*)(&qkv_s[t][c0]) = d;
    }
    __syncthreads();
    for (int idx = lane; idx < T1C * T1C; idx += 32) {
        int tq = idx / T1C, tk = idx - tq * T1C;
        const unsigned* qp = (const unsigned*)&qkv_s[tq][hh * 32];
        const unsigned* kp = (const unsigned*)&qkv_s[tk][128 + hh * 32];
        float acc = 0.f;
#pragma unroll
        for (int d = 0; d < 16; d++) {
            unsigned a = qp[d], b = kp[d];
            acc += __uint_as_float(a << 16) * __uint_as_float(b << 16);
            acc += __uint_as_float(a & 0xFFFF0000u) * __uint_as_float(b & 0xFFFF0000u);
        }
        s[hh][tq][tk] = acc * SCALEQK;
    }
    __syncthreads();
    if (tid < NHD * T1C) {
        int h2 = tid / T1C, tq = tid - h2 * T1C;
        float mx = -1e30f;
#pragma unroll
        for (int j = 0; j < T1C; j++) mx = fmaxf(mx, s[h2][tq][j]);
        float sum = 0.f;
#pragma unroll
        for (int j = 0; j < T1C; j++) { float ex = __expf(s[h2][tq][j] - mx); s[h2][tq][j] = ex; sum += ex; }
        float inv = 1.f / sum;
#pragma unroll
        for (int j = 0; j < T1C; j++) s[h2][tq][j] *= inv;
    }
    __syncthreads();
    int oc = hh * 32 + lane;
#pragma unroll
    for (int t = 0; t < T1C; t++) {
        float acc = 0.f;
#pragma unroll
        for (int tk = 0; tk < T1C; tk++) acc += s[hh][t][tk] * b2f(qkv_s[tk][256 + oc]);
        outb[((size_t)bn * T1C + t) * HHC + oc] = f2b(acc);
    }
}

// ---------------- graph attention ----------------

// per-CSR-edge coefficients (layer 0 only; later layers fused into emlp_k)
__global__ __launch_bounds__(256) void emea_k(const float* __restrict__ e, const int* __restrict__ epos,
                                              const float* __restrict__ Wem, const float* __restrict__ bem,
                                              const float* __restrict__ Wea, const float* __restrict__ bea,
                                              float* __restrict__ ec)
{
    int r = blockIdx.x * blockDim.x + threadIdx.x;
    if (r >= EEC) return;
    float ev[DEC];
#pragma unroll
    for (int k = 0; k < DEC; k++) ev[k] = e[r * DEC + k];
    int pos = epos[r];
#pragma unroll
    for (int hh = 0; hh < NHD; hh++) {
        float a = bem[hh], b2 = bea[hh];
#pragma unroll
        for (int k = 0; k < DEC; k++) { a += ev[k] * Wem[k * NHD + hh]; b2 += ev[k] * Wea[k * NHD + hh]; }
        ec[(size_t)pos * 8 + hh * 2]     = (a + 1.f) * SCALEQK;
        ec[(size_t)pos * 8 + hh * 2 + 1] = b2;
    }
}

// fused score+aggregate over CSR, wave-per-(bt,n): 4 waves/block share one bt
__global__ __launch_bounds__(256) void sagg_k(const unsigned short* __restrict__ Q,
                                              const unsigned short* __restrict__ K,
                                              const unsigned short* __restrict__ V,
                                              const int* __restrict__ rowptr, const int* __restrict__ srcCSR,
                                              const float* __restrict__ ec, unsigned short* __restrict__ outb)
{
    int wv = threadIdx.x >> 6;
    int lane = threadIdx.x & 63;
    int blk = blockIdx.x;
    int bt = blk % BTC;
    int n  = (blk / BTC) * 4 + wv;
    int cg = lane & 15;
    int es = lane >> 4;       // 0..3
    int hh = cg >> 2;
    size_t base = (size_t)bt * NN;
    uint4 qd = *(const uint4*)(Q + (base + n) * HHC + cg * 8);
    unsigned qv[4] = {qd.x, qd.y, qd.z, qd.w};
    float q[8];
#pragma unroll
    for (int jj = 0; jj < 4; jj++) {
        q[2 * jj]     = __uint_as_float(qv[jj] << 16);
        q[2 * jj + 1] = __uint_as_float(qv[jj] & 0xFFFF0000u);
    }
    int s0 = rowptr[n], s1 = rowptr[n + 1];
    float acc[8];
#pragma unroll
    for (int j = 0; j < 8; j++) acc[j] = 0.f;
    float den = 0.f;
    for (int i = s0 + es; i < s1; i += 4) {
        int sn = srcCSR[i];
        uint4 kd = *(const uint4*)(K + (base + sn) * HHC + cg * 8);
        uint4 vd = *(const uint4*)(V + (base + sn) * HHC + cg * 8);
        float2 c2 = *(const float2*)(ec + (size_t)i * 8 + hh * 2);
        unsigned kv[4] = {kd.x, kd.y, kd.z, kd.w};
        float p = 0.f;
#pragma unroll
        for (int jj = 0; jj < 4; jj++) {
            p += q[2 * jj]     * __uint_as_float(kv[jj] << 16);
            p += q[2 * jj + 1] * __uint_as_float(kv[jj] & 0xFFFF0000u);
        }
        p += __shfl_xor(p, 1, 64);
        p += __shfl_xor(p, 2, 64);
        float w = __expf(p * c2.x + c2.y);
        unsigned vv[4] = {vd.x, vd.y, vd.z, vd.w};
#pragma unroll
        for (int jj = 0; jj < 4; jj++) {
            acc[2 * jj]     += w * __uint_as_float(vv[jj] << 16);
            acc[2 * jj + 1] += w * __uint_as_float(vv[jj] & 0xFFFF0000u);
        }
        den += w;
    }
#pragma unroll
    for (int j = 0; j < 8; j++) {
        acc[j] += __shfl_xor(acc[j], 16, 64);
        acc[j] += __shfl_xor(acc[j], 32, 64);
    }
    den += __shfl_xor(den, 16, 64);
    den += __shfl_xor(den, 32, 64);
    if (es == 0) {
        float inv = den + 1e-9f;
        unsigned short r[8];
#pragma unroll
        for (int j = 0; j < 8; j++) r[j] = f2b(acc[j] / inv);
        *(uint4*)(outb + (base + n) * HHC + cg * 8) = *(uint4*)r;
    }
}

// means over bt of hBT (f32, pre-residual base) and agg output (bf16)
__global__ __launch_bounds__(128) void hmean2_k(const float* __restrict__ hBT,
                                                const unsigned short* __restrict__ aggb,
                                                float* __restrict__ mA, unsigned short* __restrict__ mBb)
{
    int n = blockIdx.x, c = threadIdx.x;
    float sA = 0.f, sB = 0.f;
#pragma unroll
    for (int bt = 0; bt < BTC; bt++) {
        size_t off = ((size_t)bt * NN + n) * HHC + c;
        sA += hBT[off];
        sB += b2f(aggb[off]);
    }
    mA[n * HHC + c] = sA * (1.f / BTC);
    mBb[n * HHC + c] = f2b(sB * (1.f / BTC));
}

// ---------------- output head: one wave per row ----------------

__global__ __launch_bounds__(256) void out_k(const float* __restrict__ h, const float* __restrict__ Wout,
                                             const float* __restrict__ bout, float* __restrict__ out)
{
    int row = blockIdx.x * 4 + (threadIdx.x >> 6);
    int lane = threadIdx.x & 63;
    const float* hp = h + (size_t)row * HHC;
    float x0 = hp[lane], x1 = hp[lane + 64];
    float w00 = Wout[lane * 4 + 0], w01 = Wout[lane * 4 + 1];
    float w02 = Wout[lane * 4 + 2], w03 = Wout[lane * 4 + 3];
    float w10 = Wout[(lane + 64) * 4 + 0], w11 = Wout[(lane + 64) * 4 + 1];
    float w12 = Wout[(lane + 64) * 4 + 2], w13 = Wout[(lane + 64) * 4 + 3];
    float p0 = x0 * w00 + x1 * w10;
    float p1 = x0 * w01 + x1 * w11;
    float p2 = x0 * w02 + x1 * w12;
    float p3 = x0 * w03 + x1 * w13;
#pragma unroll
    for (int m = 32; m >= 1; m >>= 1) {
        p0 += __shfl_xor(p0, m, 64);
        p1 += __shfl_xor(p1, m, 64);
        p2 += __shfl_xor(p2, m, 64);
        p3 += __shfl_xor(p3, m, 64);
    }
    if (lane == 0) {
        float l0 = p0 + bout[0], l1 = p1 + bout[1], l2 = p2 + bout[2], l3 = p3 + bout[3];
        float mx = fmaxf(fmaxf(l0, l1), fmaxf(l2, l3));
        float e0 = __expf(l0 - mx), e1 = __expf(l1 - mx), e2 = __expf(l2 - mx), e3 = __expf(l3 - mx);
        float inv = 1.f / (e0 + e1 + e2 + e3);
        float4 o = {e0 * inv, e1 * inv, e2 * inv, e3 * inv};
        *(float4*)(out + (size_t)row * 4) = o;
    }
}

// ---------------- launch ----------------

extern "C" void kernel_launch(void* const* d_in, const int* in_sizes, int n_in,
                              void* d_out, int out_size, void* d_ws, size_t ws_size,
                              hipStream_t stream)
{
    const float* Xk      = (const float*)d_in[0];
    const float* temb    = (const float*)d_in[1];
    const float* stepemb = (const float*)d_in[2];
    const float* Wtr     = (const float*)d_in[3];
    const float* btr     = (const float*)d_in[4];
    const float* Win     = (const float*)d_in[5];
    const float* bin     = (const float*)d_in[6];
    const float* gin     = (const float*)d_in[7];
    const float* bein    = (const float*)d_in[8];
    const float* We      = (const float*)d_in[9];
    const float* bE      = (const float*)d_in[10];
    const float* aw      = (const float*)d_in[11];
    const float* ab      = (const float*)d_in[12];
    const float* ow      = (const float*)d_in[13];
    const float* ob      = (const float*)d_in[14];
    const float* tng     = (const float*)d_in[15];
    const float* tnb     = (const float*)d_in[16];
    const float* f1w     = (const float*)d_in[17];
    const float* f1b     = (const float*)d_in[18];
    const float* f2w     = (const float*)d_in[19];
    const float* f2b_    = (const float*)d_in[20];
    const float* fng     = (const float*)d_in[21];
    const float* fnb     = (const float*)d_in[22];
    const float* Wq      = (const float*)d_in[23];
    const float* Wk      = (const float*)d_in[24];
    const float* Wv      = (const float*)d_in[25];
    const float* Wo      = (const float*)d_in[26];
    const float* bo      = (const float*)d_in[27];
    const float* Wem     = (const float*)d_in[28];
    const float* bem     = (const float*)d_in[29];
    const float* Wea     = (const float*)d_in[30];
    const float* bea     = (const float*)d_in[31];
    const float* e1w     = (const float*)d_in[32];
    const float* e1b     = (const float*)d_in[33];
    const float* e2w     = (const float*)d_in[34];
    const float* e2b     = (const float*)d_in[35];
    const float* gng     = (const float*)d_in[36];
    const float* gnb     = (const float*)d_in[37];
    const float* eng     = (const float*)d_in[38];
    const float* enb     = (const float*)d_in[39];
    const float* Wout    = (const float*)d_in[40];
    const float* bout    = (const float*)d_in[41];
    const int*   kidx    = (const int*)d_in[42];
    const int*   eidx    = (const int*)d_in[43];
    float* outp = (float*)d_out;

    char* wsp = (char*)d_ws;
    auto alloc = [&](size_t nbytes) -> void* {
        void* p = (void*)wsp;
        wsp += (nbytes + 255) & ~(size_t)255;
        return p;
    };
    float* h     = (float*)alloc((size_t)MROWS * HHC * 4);
    unsigned short* hb = (unsigned short*)alloc((size_t)MROWS * HHC * 2);
    float* hBT   = (float*)alloc((size_t)MROWS * HHC * 4);
    float* bufC  = (float*)alloc((size_t)MROWS * 384 * 4);
    unsigned short* bufDb = (unsigned short*)alloc((size_t)MROWS * HHC * 2);
    float* ebuf  = (float*)alloc((size_t)EEC * DEC * 4);
    float* ec    = (float*)alloc((size_t)EEC * NHD * 2 * 4);
    float* P12   = (float*)alloc((size_t)NN * HHC * 4);
    float* mA    = (float*)alloc((size_t)NN * HHC * 4);
    unsigned short* mBb = (unsigned short*)alloc((size_t)NN * HHC * 2);
    float* tre   = (float*)alloc((size_t)T1C * HHC * 4);
    float* degmaxf = (float*)alloc(4);
    int* degi   = (int*)alloc((size_t)NN * 4);
    int* dst    = (int*)alloc((size_t)EEC * 4);
    int* srcA   = (int*)alloc((size_t)EEC * 4);
    int* srcCSR = (int*)alloc((size_t)EEC * 4);
    int* epos   = (int*)alloc((size_t)EEC * 4);
    int* rowptr = (int*)alloc((size_t)(NN + 1) * 4);
    int* cursor = (int*)alloc((size_t)NN * 4);
    unsigned short* awP   = (unsigned short*)alloc((size_t)LLC * 384 * 128 * 2);
    unsigned short* owP   = (unsigned short*)alloc((size_t)LLC * 128 * 128 * 2);
    unsigned short* f1P   = (unsigned short*)alloc((size_t)LLC * 256 * 128 * 2);
    unsigned short* f2P   = (unsigned short*)alloc((size_t)LLC * 128 * 256 * 2);
    unsigned short* WqkvP = (unsigned short*)alloc((size_t)LLC * 384 * 128 * 2);
    unsigned short* WoP   = (unsigned short*)alloc((size_t)LLC * 128 * 128 * 2);
    unsigned short* WoT   = (unsigned short*)alloc((size_t)LLC * 128 * 128 * 2);
    unsigned short* W12P  = (unsigned short*)alloc((size_t)LLC * 128 * 128 * 2);

    unsigned short* bufCb = (unsigned short*)bufC;
    unsigned short* Qc    = (unsigned short*)bufC;
    unsigned short* Kc    = Qc + (size_t)MROWS * HHC;
    unsigned short* Vc    = Kc + (size_t)MROWS * HHC;

    {
        auto cwp = [&](const float* W, unsigned short* Bp, int K, int N, int noff, int Ntot) {
            int total = LLC * K * N;
            convwp_k<<<(total + 255) / 256, 256, 0, stream>>>(W, Bp, LLC, K, N, noff, Ntot);
        };
        cwp(aw,  awP, 128, 384, 0, 384);
        cwp(ow,  owP, 128, 128, 0, 128);
        cwp(f1w, f1P, 128, 256, 0, 256);
        cwp(f2w, f2P, 256, 128, 0, 128);
        cwp(Wq,  WqkvP, 128, 128, 0,   384);
        cwp(Wk,  WqkvP, 128, 128, 128, 384);
        cwp(Wv,  WqkvP, 128, 128, 256, 384);
        cwp(Wo,  WoP, 128, 128, 0, 128);
        convwoT_k<<<(LLC * 128 * 128 + 255) / 256, 256, 0, stream>>>(Wo, WoT);
        convw12_k<<<(LLC * 128 * 128 + 255) / 256, 256, 0, stream>>>(e1w, W12P);
    }

    zero_deg_k<<<(NN + 255) / 256, 256, 0, stream>>>(degi);
    build_edges_k<<<(EEC + 255) / 256, 256, 0, stream>>>(eidx, dst, srcA, degi);
    scan_k<<<1, 256, 0, stream>>>(degi, rowptr, cursor, degmaxf);
    feat_k<<<(EEC + 255) / 256, 256, 0, stream>>>(dst, srcA, degi, degmaxf, cursor, srcCSR, epos, We, bE, ebuf);

    embed_k<<<MROWS / 4, 256, 0, stream>>>(Xk, temb, Win, bin, gin, bein, stepemb, kidx, h, hb);
    tre_k<<<T1C, 128, 0, stream>>>(temb, Wtr, btr, tre);

    // layer-0 edge coefficients (layers 1..3 are produced by the fused emlp)
    emea_k<<<(EEC + 255) / 256, 256, 0, stream>>>(ebuf, epos, Wem, bem, Wea, bea, ec);

    for (int l = 0; l < LLC; l++) {
        const unsigned short* awP_l   = awP   + (size_t)l * 384 * 128;
        const unsigned short* owP_l   = owP   + (size_t)l * 128 * 128;
        const unsigned short* f1P_l   = f1P   + (size_t)l * 256 * 128;
        const unsigned short* f2P_l   = f2P   + (size_t)l * 128 * 256;
        const unsigned short* WqkvP_l = WqkvP + (size_t)l * 384 * 128;
        const unsigned short* WoP_l   = WoP   + (size_t)l * 128 * 128;
        const unsigned short* WoT_l   = WoT   + (size_t)l * 128 * 128;
        const unsigned short* W12P_l  = W12P  + (size_t)l * 128 * 128;
        const float* ab_l  = ab  + (size_t)l * 3 * HHC;
        const float* ob_l  = ob  + (size_t)l * HHC;
        const float* tng_l = tng + (size_t)l * HHC;
        const float* tnb_l = tnb + (size_t)l * HHC;
        const float* f1b_l = f1b + (size_t)l * 256;
        const float* f2b_l = f2b_ + (size_t)l * HHC;
        const float* fng_l = fng + (size_t)l * HHC;
        const float* fnb_l = fnb + (size_t)l * HHC;
        const float* bo_l  = bo  + (size_t)l * HHC;
        const float* e1wE_l = e1w + ((size_t)l * 272 + 256) * 64;
        const float* e1b_l = e1b + (size_t)l * 64;
        const float* e2w_l = e2w + (size_t)l * 64 * DEC;
        const float* e2b_l = e2b + (size_t)l * DEC;
        const float* gng_l = gng + (size_t)l * HHC;
        const float* gnb_l = gnb + (size_t)l * HHC;
        const float* eng_l = eng + (size_t)l * DEC;
        const float* enb_l = enb + (size_t)l * DEC;
        int ln = (l + 1 < LLC) ? l + 1 : l;
        const float* WemN = Wem + (size_t)ln * DEC * NHD;
        const float* bemN = bem + (size_t)ln * NHD;
        const float* WeaN = Wea + (size_t)ln * DEC * NHD;
        const float* beaN = bea + (size_t)ln * NHD;
        int doEc = (l + 1 < LLC) ? 1 : 0;

        // temporal attention (qkv in bf16)
        run_gemm2<128, 0, 2>(hb, awP_l, ab_l, nullptr, bufCb, nullptr, nullptr, nullptr, nullptr, MROWS, 384, stream);
        temporal_attn_k<<<BBC * NN, 128, 0, stream>>>(bufCb, bufDb);
        // fused Wo-proj + temporal LN + FFN + final LN + t_re + transpose + graph-QKV GEMM
        offn_k<<<MROWS / 32, 256, 0, stream>>>(bufDb, owP_l, ob_l, h, tng_l, tnb_l,
                                               f1P_l, f2P_l, f1b_l, f2b_l, fng_l, fnb_l,
                                               tre, WqkvP_l, hBT, Qc, Kc, Vc);
        // fused score + weighted aggregate (wave-per-(bt,n), 4 waves/block share bt)
        sagg_k<<<BTC * (NN / 4), 256, 0, stream>>>(Qc, Kc, Vc, rowptr, srcCSR, ec, bufDb);
        // hmean by linearity: mean(hBT) + mean(agg) @ Wo + bo
        hmean2_k<<<NN, 128, 0, stream>>>(hBT, bufDb, mA, mBb);
        // Wo + residual + final LN + transpose back to [B,N,T1,H], fused
        run_gemm2<128, 5, 3>(bufDb, WoP_l, bo_l, h, hb, hBT, gng_l, gnb_l, nullptr, MROWS, 128, stream);
        // fused edge head: (mBb@WoT + mA + bo) -> bf16 -> @W12 -> P12 (LDS-staged)
        gemm_hm12_k<<<(NN + 31) / 32, 256, 0, stream>>>(mBb, WoT_l, mA, bo_l, W12P_l, P12);
        // per-edge MLP (in-place on ebuf) + next-layer edge coefficients
        emlp_k<<<EEC / 4, 256, 0, stream>>>(P12, dst, srcA, e1wE_l, e1b_l, e2w_l, e2b_l, eng_l, enb_l, ebuf,
                                            epos, WemN, bemN, WeaN, beaN, ec, doEc);
    }

    out_k<<<MROWS / 4, 256, 0, stream>>>(h, Wout, bout, outp);
}

// Round 22
// 907.640 us; speedup vs baseline: 1.0589x; 1.0198x over previous
//
#include <hip/hip_runtime.h>
#include <math.h>

#define NN 2000
#define T1C 12
#define BBC 2
#define HHC 128
#define NHD 4
#define DFD 32
#define LLC 4
#define DEC 16
#define TEC 16
#define CINC 12
#define E0C 32000
#define EEC 34000
#define BTC 24
#define MROWS 48000
#define EPSLN 1e-5f
#define SCALEQK 0.17677669529663687f

typedef __attribute__((ext_vector_type(8))) short short8;
typedef __attribute__((ext_vector_type(4))) float f32x4;

// ---------------- helpers ----------------

__device__ __forceinline__ unsigned short f2b(float f)
{
    unsigned u = __float_as_uint(f);
    return (unsigned short)((u + 0x7FFF + ((u >> 16) & 1)) >> 16);
}

__device__ __forceinline__ float b2f(unsigned short h)
{
    return __uint_as_float(((unsigned)h) << 16);
}

// ---------------- fused weight conversions + t_re (single dispatch) ----------------

__device__ __forceinline__ void convwp_one(const float* __restrict__ W, unsigned short* __restrict__ Bp,
                                           int idx, int K, int N, int noff, int Ntot)
{
    int l = idx / (K * N);
    int r = idx - l * (K * N);
    int k = r / N;
    int n = r - k * N + noff;
    size_t off = (size_t)l * K * Ntot +
                 ((size_t)((n >> 4) * (K >> 5) + (k >> 5)) << 9) +
                 (((k >> 3) & 3) << 7) + ((n & 15) << 3) + (k & 7);
    Bp[off] = f2b(W[idx]);
}

#define CA_A0 196608
#define CA_A1 (CA_A0 + 65536)
#define CA_A2 (CA_A1 + 131072)
#define CA_A3 (CA_A2 + 131072)
#define CA_A4 (CA_A3 + 65536)
#define CA_A5 (CA_A4 + 65536)
#define CA_A6 (CA_A5 + 65536)
#define CA_A7 (CA_A6 + 65536)
#define CA_A8 (CA_A7 + 65536)
#define CA_A9 (CA_A8 + 65536)
#define CA_A10 (CA_A9 + 1536)

__global__ __launch_bounds__(256) void conv_all_k(
    const float* __restrict__ aw, const float* __restrict__ ow,
    const float* __restrict__ f1w, const float* __restrict__ f2w,
    const float* __restrict__ Wq, const float* __restrict__ Wk, const float* __restrict__ Wv,
    const float* __restrict__ Wo, const float* __restrict__ e1w,
    const float* __restrict__ temb, const float* __restrict__ Wtr, const float* __restrict__ btr,
    unsigned short* __restrict__ awP, unsigned short* __restrict__ owP,
    unsigned short* __restrict__ f1P, unsigned short* __restrict__ f2P,
    unsigned short* __restrict__ WqkvP, unsigned short* __restrict__ WoP,
    unsigned short* __restrict__ WoT, unsigned short* __restrict__ W12P,
    float* __restrict__ tre)
{
    int idx = blockIdx.x * blockDim.x + threadIdx.x;
    if (idx < CA_A0) { convwp_one(aw, awP, idx, 128, 384, 0, 384); return; }
    if (idx < CA_A1) { convwp_one(ow, owP, idx - CA_A0, 128, 128, 0, 128); return; }
    if (idx < CA_A2) { convwp_one(f1w, f1P, idx - CA_A1, 128, 256, 0, 256); return; }
    if (idx < CA_A3) { convwp_one(f2w, f2P, idx - CA_A2, 256, 128, 0, 128); return; }
    if (idx < CA_A4) { convwp_one(Wq, WqkvP, idx - CA_A3, 128, 128, 0, 384); return; }
    if (idx < CA_A5) { convwp_one(Wk, WqkvP, idx - CA_A4, 128, 128, 128, 384); return; }
    if (idx < CA_A6) { convwp_one(Wv, WqkvP, idx - CA_A5, 128, 128, 256, 384); return; }
    if (idx < CA_A7) { convwp_one(Wo, WoP, idx - CA_A6, 128, 128, 0, 128); return; }
    if (idx < CA_A8) {
        int r2 = idx - CA_A7;
        int l = r2 >> 14, rr = r2 & 16383;
        int c = rr >> 7, k = rr & 127;
        WoT[r2] = f2b(Wo[((size_t)l * 128 + k) * 128 + c]);
        return;
    }
    if (idx < CA_A9) {
        int r2 = idx - CA_A8;
        int l = r2 >> 14, rr = r2 & 16383;
        int c = rr >> 7, k = rr & 127;
        int sk = (c < 64) ? k : k + 128;
        int sc = c & 63;
        W12P[r2] = f2b(e1w[((size_t)l * 272 + sk) * 64 + sc]);
        return;
    }
    if (idx < CA_A10) {
        int r2 = idx - CA_A9;
        int t = r2 >> 7, c = r2 & 127;
        float acc = btr[c];
#pragma unroll
        for (int k = 0; k < TEC; k++) acc += temb[t * TEC + k] * Wtr[k * HHC + c];
        tre[t * HHC + c] = acc;
        return;
    }
}

// ---------------- gemm2: 128x128-tile LDS-staged MFMA GEMM ----------------
// EPI: 0=none 1=gelu 2=res-add 3=res+LN 4=res+LN+t_re+transpose to [BT,N,H]
//      5=res+LN + transpose back to [B,N,T1,H]

template<int K, int EPI, int OUTM>
__global__ __launch_bounds__(256) void gemm2_k(
    const unsigned short* __restrict__ A, const unsigned short* __restrict__ Bp,
    const float* __restrict__ bias, float* __restrict__ C, unsigned short* __restrict__ Cb,
    const float* __restrict__ res, const float* __restrict__ gam, const float* __restrict__ bet,
    const float* __restrict__ trep,
    int M, int Ntot)
{
    __shared__ unsigned short A_s[128 * 16 * 8];
    __shared__ float red2[2][128][2];

    int tid = threadIdx.x;
    int w = tid >> 6, lane = tid & 63;
    int wr = w & 1, wc = w >> 1;
    int quad = lane >> 4, lr = lane & 15;

    const unsigned short* abase = A + (size_t)blockIdx.x * 128 * K;
    int ntg0 = blockIdx.y * 8 + wc * 4;

    f32x4 acc[4][4];
#pragma unroll
    for (int mt = 0; mt < 4; mt++)
#pragma unroll
        for (int nt = 0; nt < 4; nt++) acc[mt][nt] = (f32x4){0.f, 0.f, 0.f, 0.f};

#pragma unroll
    for (int kb = 0; kb < K; kb += 128) {
        if (kb) __syncthreads();
#pragma unroll
        for (int j = 0; j < 8; j++) {
            int s = j * 256 + tid;
            int row = s >> 4, ks = s & 15;
            int ko = ks ^ (row & 15);
            uint4 d = *(const uint4*)(abase + (size_t)row * K + kb + ko * 8);
            *(uint4*)(A_s + s * 8) = d;
        }
        __syncthreads();
#pragma unroll
        for (int k0 = 0; k0 < 128; k0 += 32) {
            short8 af[4], bf[4];
#pragma unroll
            for (int mt = 0; mt < 4; mt++) {
                int row_l = wr * 64 + mt * 16 + lr;
                int koct = (k0 >> 3) + quad;
                int slot = row_l * 16 + (koct ^ lr);
                af[mt] = *(const short8*)(A_s + slot * 8);
            }
#pragma unroll
            for (int nt = 0; nt < 4; nt++) {
                size_t off = ((size_t)(ntg0 + nt) * (K >> 5) + ((kb + k0) >> 5)) * 512 + lane * 8;
                bf[nt] = *(const short8*)(Bp + off);
            }
#pragma unroll
            for (int mt = 0; mt < 4; mt++)
#pragma unroll
                for (int nt = 0; nt < 4; nt++)
                    acc[mt][nt] = __builtin_amdgcn_mfma_f32_16x16x32_bf16(af[mt], bf[nt], acc[mt][nt], 0, 0, 0);
        }
    }

    int rbase = blockIdx.x * 128 + wr * 64;
    int cbase = blockIdx.y * 128 + wc * 64;

    if constexpr (EPI != 3 && EPI != 4 && EPI != 5) {
#pragma unroll
        for (int mt = 0; mt < 4; mt++) {
#pragma unroll
            for (int nt = 0; nt < 4; nt++) {
                int colg = cbase + nt * 16 + lr;
                float bv = bias ? bias[colg] : 0.f;
#pragma unroll
                for (int i = 0; i < 4; i++) {
                    int row = rbase + mt * 16 + quad * 4 + i;
                    float x = acc[mt][nt][i] + bv;
                    if constexpr (EPI == 1) x = 0.5f * x * (1.f + erff(x * 0.70710678118654752f));
                    if constexpr (EPI == 2) x = res[(size_t)row * Ntot + colg] + x;
                    if constexpr (OUTM & 1) C[(size_t)row * Ntot + colg] = x;
                    if constexpr (OUTM & 4)
                        Cb[(size_t)blockIdx.y * M * 128 + (size_t)row * 128 + (wc * 64 + nt * 16 + lr)] = f2b(x);
                    else if constexpr (OUTM & 2)
                        Cb[(size_t)row * Ntot + colg] = f2b(x);
                }
            }
        }
    } else {
        float s[4][4], s2l[4][4];
#pragma unroll
        for (int mt = 0; mt < 4; mt++)
#pragma unroll
            for (int i = 0; i < 4; i++) { s[mt][i] = 0.f; s2l[mt][i] = 0.f; }
#pragma unroll
        for (int mt = 0; mt < 4; mt++) {
#pragma unroll
            for (int nt = 0; nt < 4; nt++) {
                int colg = cbase + nt * 16 + lr;
                float bv = bias[colg];
#pragma unroll
                for (int i = 0; i < 4; i++) {
                    int row = rbase + mt * 16 + quad * 4 + i;
                    float x = acc[mt][nt][i] + bv + res[(size_t)row * 128 + colg];
                    acc[mt][nt][i] = x;
                    s[mt][i] += x;
                    s2l[mt][i] += x * x;
                }
            }
        }
#pragma unroll
        for (int m = 1; m < 16; m <<= 1) {
#pragma unroll
            for (int mt = 0; mt < 4; mt++)
#pragma unroll
                for (int i = 0; i < 4; i++) {
                    s[mt][i]  += __shfl_xor(s[mt][i], m, 64);
                    s2l[mt][i] += __shfl_xor(s2l[mt][i], m, 64);
                }
        }
        if (lr == 0) {
#pragma unroll
            for (int mt = 0; mt < 4; mt++)
#pragma unroll
                for (int i = 0; i < 4; i++) {
                    int rl = wr * 64 + mt * 16 + quad * 4 + i;
                    red2[wc][rl][0] = s[mt][i];
                    red2[wc][rl][1] = s2l[mt][i];
                }
        }
        __syncthreads();
#pragma unroll
        for (int mt = 0; mt < 4; mt++) {
#pragma unroll
            for (int i = 0; i < 4; i++) {
                int rl = wr * 64 + mt * 16 + quad * 4 + i;
                float st  = red2[0][rl][0] + red2[1][rl][0];
                float s2t = red2[0][rl][1] + red2[1][rl][1];
                float mu = st * (1.f / 128.f);
                float rstd = rsqrtf(s2t * (1.f / 128.f) - mu * mu + EPSLN);
                int row = rbase + mt * 16 + quad * 4 + i;
                if constexpr (EPI == 4) {
                    int t = row % T1C;
                    int bn = row / T1C;
                    int b = bn / NN;
                    int n = bn - b * NN;
                    size_t rowp = (size_t)(b * T1C + t) * NN + n;
                    const float* trow = trep + t * HHC;
#pragma unroll
                    for (int nt = 0; nt < 4; nt++) {
                        int colg = cbase + nt * 16 + lr;
                        float y = (acc[mt][nt][i] - mu) * rstd * gam[colg] + bet[colg] + trow[colg];
                        C[rowp * 128 + colg] = y;
                        Cb[rowp * 128 + colg] = f2b(y);
                    }
                } else if constexpr (EPI == 5) {
                    int bt = row / NN, n = row - bt * NN;
                    int b = bt / T1C, t = bt - b * T1C;
                    size_t rowp = ((size_t)(b * NN + n)) * T1C + t;
#pragma unroll
                    for (int nt = 0; nt < 4; nt++) {
                        int colg = cbase + nt * 16 + lr;
                        float y = (acc[mt][nt][i] - mu) * rstd * gam[colg] + bet[colg];
                        C[rowp * 128 + colg] = y;
                        Cb[rowp * 128 + colg] = f2b(y);
                    }
                } else {
#pragma unroll
                    for (int nt = 0; nt < 4; nt++) {
                        int colg = cbase + nt * 16 + lr;
                        float y = (acc[mt][nt][i] - mu) * rstd * gam[colg] + bet[colg];
                        if constexpr (OUTM & 1) C[(size_t)row * 128 + colg] = y;
                        if constexpr (OUTM & 2) Cb[(size_t)row * 128 + colg] = f2b(y);
                    }
                }
            }
        }
    }
}

template<int K, int EPI, int OUTM>
static void run_gemm2(const unsigned short* A, const unsigned short* Bp, const float* bias,
                      float* C, unsigned short* Cb, const float* res, const float* g, const float* be,
                      const float* trep, int M, int Ntot, hipStream_t stream)
{
    dim3 grid(M / 128, Ntot / 128);
    gemm2_k<K, EPI, OUTM><<<grid, 256, 0, stream>>>(A, Bp, bias, C, Cb, res, g, be, trep, M, Ntot);
}

// ---------------- fused Wo+LN+FFN+LN + graph-QKV GEMM (32-row tile) ----------------

__global__ __launch_bounds__(256) void offn_k(
    const unsigned short* __restrict__ A,      // attn out bf16 [MROWS][128]
    const unsigned short* __restrict__ Wp,     // WoP layer slice (K=128, Ntot=128 packed)
    const float* __restrict__ ob_l,
    const float* __restrict__ resh,            // h_prev (f32)
    const float* __restrict__ tng_l, const float* __restrict__ tnb_l,
    const unsigned short* __restrict__ F1p,    // f1P layer slice (K=128, N=256 packed)
    const unsigned short* __restrict__ F2p,    // f2P layer slice (K=256, N=128 packed)
    const float* __restrict__ f1b_l, const float* __restrict__ f2b_l,
    const float* __restrict__ fng_l, const float* __restrict__ fnb_l,
    const float* __restrict__ trep,
    const unsigned short* __restrict__ Wqkv,   // WqkvP layer slice (K=128, Ntot=384 packed)
    float* __restrict__ C,                     // hBT (f32, transposed)
    unsigned short* __restrict__ Qc, unsigned short* __restrict__ Kc, unsigned short* __restrict__ Vc)
{
    __shared__ unsigned short A_s[32 * 16 * 8];
    __shared__ unsigned short M_s[32 * 16 * 8];
    __shared__ float red2[2][32][2];

    int tid = threadIdx.x;
    int w = tid >> 6, lane = tid & 63;
    int wr = w & 1, wc = w >> 1;
    int quad = lane >> 4, lr = lane & 15;

    const unsigned short* abase = A + (size_t)blockIdx.x * 32 * 128;

#pragma unroll
    for (int j = 0; j < 2; j++) {
        int s = j * 256 + tid;
        int row = s >> 4, ks = s & 15;
        int ko = ks ^ (row & 15);
        uint4 d = *(const uint4*)(abase + (size_t)row * 128 + ko * 8);
        *(uint4*)(A_s + s * 8) = d;
    }
    __syncthreads();

    // ---- Wo GEMM (K=128) ----
    f32x4 wacc[4];
#pragma unroll
    for (int nt = 0; nt < 4; nt++) wacc[nt] = (f32x4){0.f, 0.f, 0.f, 0.f};
#pragma unroll
    for (int k0 = 0; k0 < 128; k0 += 32) {
        int row_l = wr * 16 + lr;
        int koct = (k0 >> 3) + quad;
        int slot = row_l * 16 + (koct ^ lr);
        short8 af = *(const short8*)(A_s + slot * 8);
        short8 bf[4];
#pragma unroll
        for (int nt = 0; nt < 4; nt++) {
            size_t off = ((size_t)(wc * 4 + nt) * 4 + (k0 >> 5)) * 512 + lane * 8;
            bf[nt] = *(const short8*)(Wp + off);
        }
#pragma unroll
        for (int nt = 0; nt < 4; nt++)
            wacc[nt] = __builtin_amdgcn_mfma_f32_16x16x32_bf16(af, bf[nt], wacc[nt], 0, 0, 0);
    }

    int rbase = blockIdx.x * 32 + wr * 16;
    int cbase = wc * 64;

    // ---- temporal-LN epilogue: y kept in registers, bf16(y) staged into A_s ----
    float yv[4][4];
    {
        float s1[4], s2v[4];
#pragma unroll
        for (int i = 0; i < 4; i++) { s1[i] = 0.f; s2v[i] = 0.f; }
#pragma unroll
        for (int nt = 0; nt < 4; nt++) {
            int colg = cbase + nt * 16 + lr;
            float bv = ob_l[colg];
#pragma unroll
            for (int i = 0; i < 4; i++) {
                int row = rbase + quad * 4 + i;
                float x = wacc[nt][i] + bv + resh[(size_t)row * 128 + colg];
                yv[nt][i] = x;
                s1[i] += x;
                s2v[i] += x * x;
            }
        }
#pragma unroll
        for (int m = 1; m < 16; m <<= 1) {
#pragma unroll
            for (int i = 0; i < 4; i++) {
                s1[i]  += __shfl_xor(s1[i], m, 64);
                s2v[i] += __shfl_xor(s2v[i], m, 64);
            }
        }
        if (lr == 0) {
#pragma unroll
            for (int i = 0; i < 4; i++) {
                int rl = wr * 16 + quad * 4 + i;
                red2[wc][rl][0] = s1[i];
                red2[wc][rl][1] = s2v[i];
            }
        }
        __syncthreads();
#pragma unroll
        for (int i = 0; i < 4; i++) {
            int rl = wr * 16 + quad * 4 + i;
            float st  = red2[0][rl][0] + red2[1][rl][0];
            float s2t = red2[0][rl][1] + red2[1][rl][1];
            float mu = st * (1.f / 128.f);
            float rstd = rsqrtf(s2t * (1.f / 128.f) - mu * mu + EPSLN);
            int row = wr * 16 + quad * 4 + i;
#pragma unroll
            for (int nt = 0; nt < 4; nt++) {
                int col = cbase + nt * 16 + lr;
                float y = (yv[nt][i] - mu) * rstd * tng_l[col] + tnb_l[col];
                yv[nt][i] = y;
                int cchunk = col >> 3, celem = col & 7;
                int ks = cchunk ^ (row & 15);
                A_s[(row * 16 + ks) * 8 + celem] = f2b(y);
            }
        }
    }
    __syncthreads();

    // ---- FFN: f1 + gelu + f2 ----
    f32x4 facc[4];
#pragma unroll
    for (int nt = 0; nt < 4; nt++) facc[nt] = (f32x4){0.f, 0.f, 0.f, 0.f};

#pragma unroll
    for (int half = 0; half < 2; half++) {
        f32x4 macc[4];
#pragma unroll
        for (int nt = 0; nt < 4; nt++) macc[nt] = (f32x4){0.f, 0.f, 0.f, 0.f};
#pragma unroll
        for (int k0 = 0; k0 < 128; k0 += 32) {
            int row_l = wr * 16 + lr;
            int koct = (k0 >> 3) + quad;
            int slot = row_l * 16 + (koct ^ lr);
            short8 af = *(const short8*)(A_s + slot * 8);
            short8 bf[4];
#pragma unroll
            for (int nt = 0; nt < 4; nt++) {
                size_t off = ((size_t)(half * 8 + wc * 4 + nt) * 4 + (k0 >> 5)) * 512 + lane * 8;
                bf[nt] = *(const short8*)(F1p + off);
            }
#pragma unroll
            for (int nt = 0; nt < 4; nt++)
                macc[nt] = __builtin_amdgcn_mfma_f32_16x16x32_bf16(af, bf[nt], macc[nt], 0, 0, 0);
        }
        if (half) __syncthreads();
#pragma unroll
        for (int nt = 0; nt < 4; nt++) {
            int col = wc * 64 + nt * 16 + lr;
            float bv = f1b_l[half * 128 + col];
            int cchunk = col >> 3, celem = col & 7;
#pragma unroll
            for (int i = 0; i < 4; i++) {
                int row = wr * 16 + quad * 4 + i;
                float x = macc[nt][i] + bv;
                x = 0.5f * x * (1.f + erff(x * 0.70710678118654752f));
                int ks = cchunk ^ (row & 15);
                M_s[(row * 16 + ks) * 8 + celem] = f2b(x);
            }
        }
        __syncthreads();
#pragma unroll
        for (int k0 = 0; k0 < 128; k0 += 32) {
            int row_l = wr * 16 + lr;
            int koct = (k0 >> 3) + quad;
            int slot = row_l * 16 + (koct ^ lr);
            short8 af = *(const short8*)(M_s + slot * 8);
            short8 bf[4];
#pragma unroll
            for (int nt = 0; nt < 4; nt++) {
                size_t off = ((size_t)(wc * 4 + nt) * 8 + ((half * 128 + k0) >> 5)) * 512 + lane * 8;
                bf[nt] = *(const short8*)(F2p + off);
            }
#pragma unroll
            for (int nt = 0; nt < 4; nt++)
                facc[nt] = __builtin_amdgcn_mfma_f32_16x16x32_bf16(af, bf[nt], facc[nt], 0, 0, 0);
        }
    }

    // ---- final epilogue: res(yv) + LN + t_re; write hBT (f32) + stage bf16 into A_s ----
    float s[4], s2l[4];
#pragma unroll
    for (int i = 0; i < 4; i++) { s[i] = 0.f; s2l[i] = 0.f; }
#pragma unroll
    for (int nt = 0; nt < 4; nt++) {
        int colg = cbase + nt * 16 + lr;
        float bv = f2b_l[colg];
#pragma unroll
        for (int i = 0; i < 4; i++) {
            float x = facc[nt][i] + bv + yv[nt][i];
            facc[nt][i] = x;
            s[i] += x;
            s2l[i] += x * x;
        }
    }
#pragma unroll
    for (int m = 1; m < 16; m <<= 1) {
#pragma unroll
        for (int i = 0; i < 4; i++) {
            s[i]  += __shfl_xor(s[i], m, 64);
            s2l[i] += __shfl_xor(s2l[i], m, 64);
        }
    }
    if (lr == 0) {
#pragma unroll
        for (int i = 0; i < 4; i++) {
            int rl = wr * 16 + quad * 4 + i;
            red2[wc][rl][0] = s[i];
            red2[wc][rl][1] = s2l[i];
        }
    }
    __syncthreads();
    size_t rowp4[4];
#pragma unroll
    for (int i = 0; i < 4; i++) {
        int rl = wr * 16 + quad * 4 + i;
        float st  = red2[0][rl][0] + red2[1][rl][0];
        float s2t = red2[0][rl][1] + red2[1][rl][1];
        float mu = st * (1.f / 128.f);
        float rstd = rsqrtf(s2t * (1.f / 128.f) - mu * mu + EPSLN);
        int row = rbase + quad * 4 + i;
        int t = row % T1C;
        int bn = row / T1C;
        int b = bn / NN;
        int n = bn - b * NN;
        size_t rowp = (size_t)(b * T1C + t) * NN + n;
        rowp4[i] = rowp;
        const float* trow = trep + t * HHC;
        int rloc = wr * 16 + quad * 4 + i;
#pragma unroll
        for (int nt = 0; nt < 4; nt++) {
            int colg = cbase + nt * 16 + lr;
            float y = (facc[nt][i] - mu) * rstd * fng_l[colg] + fnb_l[colg] + trow[colg];
            C[rowp * 128 + colg] = y;
            int cchunk = colg >> 3, celem = colg & 7;
            int ks = cchunk ^ (rloc & 15);
            A_s[(rloc * 16 + ks) * 8 + celem] = f2b(y);
        }
    }
    __syncthreads();

    // ---- graph QKV GEMM: each wave 16 rows (wr) x 192 cols (wc), 3 groups of 4 tiles ----
#pragma unroll
    for (int g3 = 0; g3 < 3; g3++) {
        f32x4 qacc[4];
#pragma unroll
        for (int nt = 0; nt < 4; nt++) qacc[nt] = (f32x4){0.f, 0.f, 0.f, 0.f};
#pragma unroll
        for (int k0 = 0; k0 < 128; k0 += 32) {
            int row_l = wr * 16 + lr;
            int koct = (k0 >> 3) + quad;
            int slot = row_l * 16 + (koct ^ lr);
            short8 af = *(const short8*)(A_s + slot * 8);
            short8 bf[4];
#pragma unroll
            for (int nt = 0; nt < 4; nt++) {
                size_t off = ((size_t)(wc * 12 + g3 * 4 + nt) * 4 + (k0 >> 5)) * 512 + lane * 8;
                bf[nt] = *(const short8*)(Wqkv + off);
            }
#pragma unroll
            for (int nt = 0; nt < 4; nt++)
                qacc[nt] = __builtin_amdgcn_mfma_f32_16x16x32_bf16(af, bf[nt], qacc[nt], 0, 0, 0);
        }
#pragma unroll
        for (int nt = 0; nt < 4; nt++) {
            int colg = wc * 192 + (g3 * 4 + nt) * 16 + lr;
            unsigned short* dstbuf;
            int col;
            if (colg < 128)      { dstbuf = Qc; col = colg; }
            else if (colg < 256) { dstbuf = Kc; col = colg - 128; }
            else                 { dstbuf = Vc; col = colg - 256; }
#pragma unroll
            for (int i = 0; i < 4; i++)
                dstbuf[rowp4[i] * 128 + col] = f2b(qacc[nt][i]);
        }
    }
}

// ---------------- fused hm chain: hm = f2b(mBb@WoT + mA + bo) -> P12 = hm@W12 ----------------

__global__ __launch_bounds__(256) void gemm_hm12_k(
    const unsigned short* __restrict__ A,    // mBb
    const unsigned short* __restrict__ WT,   // WoT layer slice [c][k]
    const float* __restrict__ mA, const float* __restrict__ bo,
    const unsigned short* __restrict__ W12,  // W12P layer slice [c][k]
    float* __restrict__ P12)
{
    __shared__ unsigned short A_s[32 * 16 * 8];
    const int M = NN, K = 128;
    int tid = threadIdx.x;
    int w = tid >> 6, lane = tid & 63;
    int wr = w & 1, wc = w >> 1;
    int r0 = blockIdx.x * 32 + wr * 16;
    int c0 = wc * 64;
    int lr = lane & 15, quad = lane >> 4;
    int kq = quad * 8;
    int arow = r0 + lr; if (arow >= M) arow = M - 1;
    const unsigned short* ap = A + (size_t)arow * K + kq;
    const unsigned short* wp = WT + (size_t)(c0 + lr) * K + kq;

    // phase 1: mBb @ WoT
    f32x4 acc[4];
#pragma unroll
    for (int t = 0; t < 4; t++) acc[t] = (f32x4){0.f, 0.f, 0.f, 0.f};
    for (int k0 = 0; k0 < K; k0 += 32) {
        short8 a = *(const short8*)(ap + k0);
#pragma unroll
        for (int t = 0; t < 4; t++) {
            short8 b = *(const short8*)(wp + (size_t)t * 16 * K + k0);
            acc[t] = __builtin_amdgcn_mfma_f32_16x16x32_bf16(a, b, acc[t], 0, 0, 0);
        }
    }
    // epilogue: + mA + bo -> f2b, staged into LDS (swizzled A-fragment layout)
#pragma unroll
    for (int t = 0; t < 4; t++) {
        int col = c0 + t * 16 + lr;
        int cchunk = col >> 3, celem = col & 7;
#pragma unroll
        for (int i = 0; i < 4; i++) {
            int row = r0 + quad * 4 + i;
            int rr = row < M ? row : M - 1;
            float x = acc[t][i] + mA[(size_t)rr * 128 + col] + bo[col];
            int rloc = wr * 16 + quad * 4 + i;
            int ks = cchunk ^ (rloc & 15);
            A_s[(rloc * 16 + ks) * 8 + celem] = f2b(x);
        }
    }
    __syncthreads();

    // phase 2: P12 = hm @ W12
    f32x4 acc2[4];
#pragma unroll
    for (int t = 0; t < 4; t++) acc2[t] = (f32x4){0.f, 0.f, 0.f, 0.f};
    const unsigned short* wp2 = W12 + (size_t)(c0 + lr) * 128 + kq;
#pragma unroll
    for (int k0 = 0; k0 < 128; k0 += 32) {
        int row_l = wr * 16 + lr;
        int koct = (k0 >> 3) + quad;
        int slot = row_l * 16 + (koct ^ lr);
        short8 af = *(const short8*)(A_s + slot * 8);
#pragma unroll
        for (int t = 0; t < 4; t++) {
            short8 b = *(const short8*)(wp2 + (size_t)t * 16 * 128 + k0);
            acc2[t] = __builtin_amdgcn_mfma_f32_16x16x32_bf16(af, b, acc2[t], 0, 0, 0);
        }
    }
#pragma unroll
    for (int t = 0; t < 4; t++) {
        int col = c0 + t * 16 + lr;
#pragma unroll
        for (int i = 0; i < 4; i++) {
            int row = r0 + quad * 4 + i;
            if (row < M) P12[(size_t)row * 128 + col] = acc2[t][i];
        }
    }
}

// ---------------- fused per-edge MLP (+ next-layer edge coefficients) ----------------

__global__ __launch_bounds__(256) void emlp_k(const float* __restrict__ P12,
                                              const int* __restrict__ dst, const int* __restrict__ src,
                                              const float* __restrict__ e1wE, const float* __restrict__ e1b_l,
                                              const float* __restrict__ e2w_l, const float* __restrict__ e2b_l,
                                              const float* __restrict__ g, const float* __restrict__ be,
                                              float* __restrict__ e,
                                              const int* __restrict__ epos,
                                              const float* __restrict__ WemN, const float* __restrict__ bemN,
                                              const float* __restrict__ WeaN, const float* __restrict__ beaN,
                                              float* __restrict__ ec, int doEc)
{
    __shared__ float tl[4][64];
    int wv = threadIdx.x >> 6, l = threadIdx.x & 63;
    int r = blockIdx.x * 4 + wv;           // EEC = 34000 = 8500*4, no remainder
    int d = dst[r], s = src[r];
    const float* ep = e + (size_t)r * DEC;
    float t = P12[(size_t)d * 128 + l] + P12[(size_t)s * 128 + 64 + l] + e1b_l[l];
#pragma unroll
    for (int k = 0; k < DEC; k++) t += ep[k] * e1wE[k * 64 + l];
    t = 0.5f * t * (1.f + erff(t * 0.70710678118654752f));
    tl[wv][l] = t;
    __syncthreads();
    int c = l & 15, kq = l >> 4;
    float p = 0.f;
#pragma unroll
    for (int j = 0; j < 16; j++) p += tl[wv][kq * 16 + j] * e2w_l[(kq * 16 + j) * 16 + c];
    p += __shfl_xor(p, 16, 64);
    p += __shfl_xor(p, 32, 64);
    float x = p + e2b_l[c] + ep[c];
    float s1 = x, s2 = x * x;
#pragma unroll
    for (int m = 1; m < 16; m <<= 1) {
        s1 += __shfl_xor(s1, m, 64);
        s2 += __shfl_xor(s2, m, 64);
    }
    float mu = s1 * (1.f / 16.f);
    float rstd = rsqrtf(s2 * (1.f / 16.f) - mu * mu + EPSLN);
    float y = (x - mu) * rstd * g[c] + be[c];
    if (l < 16) e[(size_t)r * DEC + c] = y;

    if (doEc) {
        int hh = l >> 4;      // head = replica group 0..3
        float pem = y * WemN[c * NHD + hh];
        float pea = y * WeaN[c * NHD + hh];
#pragma unroll
        for (int m = 1; m < 16; m <<= 1) {
            pem += __shfl_xor(pem, m, 64);
            pea += __shfl_xor(pea, m, 64);
        }
        if (c == 0) {
            int pos = epos[r];
            ec[(size_t)pos * 8 + hh * 2]     = (pem + bemN[hh] + 1.f) * SCALEQK;
            ec[(size_t)pos * 8 + hh * 2 + 1] = pea + beaN[hh];
        }
    }
}

// ---------------- graph precompute ----------------

__global__ __launch_bounds__(256) void zero_deg_k(int* __restrict__ degi)
{
    int i = blockIdx.x * blockDim.x + threadIdx.x;
    if (i < NN) degi[i] = 0;
}

__global__ __launch_bounds__(256) void build_edges_k(const int* __restrict__ eidx,
                                                     int* __restrict__ dst, int* __restrict__ src,
                                                     int* __restrict__ degi)
{
    int e = blockIdx.x * blockDim.x + threadIdx.x;
    if (e >= EEC) return;
    int d, s;
    if (e < E0C) { d = eidx[e]; s = eidx[E0C + e]; }
    else { d = e - E0C; s = e - E0C; }
    dst[e] = d;
    src[e] = s;
    atomicAdd(&degi[d], 1);
}

__global__ __launch_bounds__(256) void scan_k(const int* __restrict__ degi, int* __restrict__ rowptr,
                                              int* __restrict__ cursor, float* __restrict__ degmaxf)
{
    __shared__ int ssum[256];
    __shared__ int smx[256];
    int tid = threadIdx.x;
    int vals[8];
    int s = 0, mx = 0;
    int base = tid * 8;
#pragma unroll
    for (int j = 0; j < 8; j++) {
        int idx = base + j;
        int v = (idx < NN) ? degi[idx] : 0;
        vals[j] = v; s += v; mx = max(mx, v);
    }
    ssum[tid] = s; smx[tid] = mx;
    __syncthreads();
    for (int off = 1; off < 256; off <<= 1) {
        int t = (tid >= off) ? ssum[tid - off] : 0;
        __syncthreads();
        ssum[tid] += t;
        __syncthreads();
    }
    for (int off = 128; off > 0; off >>= 1) {
        if (tid < off) smx[tid] = max(smx[tid], smx[tid + off]);
        __syncthreads();
    }
    if (tid == 0) *degmaxf = fmaxf((float)smx[0], 1.f);
    int running = ssum[tid] - s;
#pragma unroll
    for (int j = 0; j < 8; j++) {
        int idx = base + j;
        if (idx < NN) { rowptr[idx] = running; cursor[idx] = running; running += vals[j]; }
    }
    if (tid == 255) rowptr[NN] = ssum[255];
}

// feat + layer-0 edge coefficients, fused
__global__ __launch_bounds__(256) void feat_k(const int* __restrict__ dst, const int* __restrict__ src,
                                              const int* __restrict__ degi, const float* __restrict__ degmaxf,
                                              int* __restrict__ cursor, int* __restrict__ srcCSR,
                                              int* __restrict__ epos,
                                              const float* __restrict__ We, const float* __restrict__ bE,
                                              float* __restrict__ e,
                                              const float* __restrict__ Wem0, const float* __restrict__ bem0,
                                              const float* __restrict__ Wea0, const float* __restrict__ bea0,
                                              float* __restrict__ ec)
{
    int ei = blockIdx.x * blockDim.x + threadIdx.x;
    if (ei >= EEC) return;
    int d = dst[ei], s = src[ei];
    int pos = atomicAdd(&cursor[d], 1);
    srcCSR[pos] = s;
    epos[ei] = pos;
    float dm = *degmaxf;
    float degd = (float)degi[d], degs = (float)degi[s];
    float f0 = 1.f / fmaxf(degd, 1.f);
    float f1 = degs / dm, f2 = degd / dm;
    float ev[DEC];
#pragma unroll
    for (int c = 0; c < DEC; c++) {
        float v = bE[c] + f0 * We[c] + f1 * We[DEC + c] + f2 * We[2 * DEC + c];
        ev[c] = v;
        e[ei * DEC + c] = v;
    }
#pragma unroll
    for (int hh = 0; hh < NHD; hh++) {
        float a = bem0[hh], b2 = bea0[hh];
#pragma unroll
        for (int k = 0; k < DEC; k++) { a += ev[k] * Wem0[k * NHD + hh]; b2 += ev[k] * Wea0[k * NHD + hh]; }
        ec[(size_t)pos * 8 + hh * 2]     = (a + 1.f) * SCALEQK;
        ec[(size_t)pos * 8 + hh * 2 + 1] = b2;
    }
}

// ---------------- embedding: wave-per-row, shfl-only reduction ----------------

__global__ __launch_bounds__(256) void embed_k(const float* __restrict__ Xk, const float* __restrict__ temb,
                                               const float* __restrict__ Win, const float* __restrict__ bin,
                                               const float* __restrict__ g, const float* __restrict__ be,
                                               const float* __restrict__ stepemb, const int* __restrict__ kidx,
                                               float* __restrict__ h, unsigned short* __restrict__ hb)
{
    int row = blockIdx.x * 4 + (threadIdx.x >> 6);
    int l = threadIdx.x & 63;
    int t = row % T1C;
    int bn = row / T1C;
    int b = bn / NN;
    const float* xk = Xk + (size_t)row * CINC;
    const float* tp = temb + t * TEC;
    float acc0 = bin[l], acc1 = bin[l + 64];
#pragma unroll
    for (int k = 0; k < CINC; k++) {
        float xv = xk[k];
        acc0 += xv * Win[k * HHC + l];
        acc1 += xv * Win[k * HHC + l + 64];
    }
#pragma unroll
    for (int k = 0; k < TEC; k++) {
        float xv = tp[k];
        acc0 += xv * Win[(CINC + k) * HHC + l];
        acc1 += xv * Win[(CINC + k) * HHC + l + 64];
    }
    float s = acc0 + acc1, s2 = acc0 * acc0 + acc1 * acc1;
#pragma unroll
    for (int m = 32; m >= 1; m >>= 1) {
        s  += __shfl_xor(s, m, 64);
        s2 += __shfl_xor(s2, m, 64);
    }
    float mu = s * (1.f / 128.f);
    float rstd = rsqrtf(s2 * (1.f / 128.f) - mu * mu + EPSLN);
    const float* se = stepemb + (size_t)kidx[b] * HHC;
    float v0 = (acc0 - mu) * rstd * g[l] + be[l] + se[l];
    float v1 = (acc1 - mu) * rstd * g[l + 64] + be[l + 64] + se[l + 64];
    size_t ob = (size_t)row * HHC;
    h[ob + l] = v0;
    h[ob + l + 64] = v1;
    hb[ob + l] = f2b(v0);
    hb[ob + l + 64] = f2b(v1);
}

// ---------------- temporal attention: raw-bf16 LDS staging ----------------

__global__ __launch_bounds__(128) void temporal_attn_k(const unsigned short* __restrict__ qkvb,
                                                       unsigned short* __restrict__ outb)
{
    int bn = blockIdx.x;
    __shared__ unsigned short qkv_s[T1C][408];
    __shared__ float s[NHD][T1C][T1C];
    int tid = threadIdx.x;
    int hh = tid >> 5, lane = tid & 31;
    const unsigned short* base = qkvb + (size_t)bn * T1C * 384;
    for (int cIdx = tid; cIdx < 576; cIdx += 128) {
        uint4 d = *(const uint4*)(base + cIdx * 8);
        int t = cIdx / 48;
        int c0 = (cIdx - t * 48) * 8;
        *(uint4*)(&qkv_s[t][c0]) = d;
    }
    __syncthreads();
    for (int idx = lane; idx < T1C * T1C; idx += 32) {
        int tq = idx / T1C, tk = idx - tq * T1C;
        const unsigned* qp = (const unsigned*)&qkv_s[tq][hh * 32];
        const unsigned* kp = (const unsigned*)&qkv_s[tk][128 + hh * 32];
        float acc = 0.f;
#pragma unroll
        for (int d = 0; d < 16; d++) {
            unsigned a = qp[d], b = kp[d];
            acc += __uint_as_float(a << 16) * __uint_as_float(b << 16);
            acc += __uint_as_float(a & 0xFFFF0000u) * __uint_as_float(b & 0xFFFF0000u);
        }
        s[hh][tq][tk] = acc * SCALEQK;
    }
    __syncthreads();
    if (tid < NHD * T1C) {
        int h2 = tid / T1C, tq = tid - h2 * T1C;
        float mx = -1e30f;
#pragma unroll
        for (int j = 0; j < T1C; j++) mx = fmaxf(mx, s[h2][tq][j]);
        float sum = 0.f;
#pragma unroll
        for (int j = 0; j < T1C; j++) { float ex = __expf(s[h2][tq][j] - mx); s[h2][tq][j] = ex; sum += ex; }
        float inv = 1.f / sum;
#pragma unroll
        for (int j = 0; j < T1C; j++) s[h2][tq][j] *= inv;
    }
    __syncthreads();
    int oc = hh * 32 + lane;
#pragma unroll
    for (int t = 0; t < T1C; t++) {
        float acc = 0.f;
#pragma unroll
        for (int tk = 0; tk < T1C; tk++) acc += s[hh][t][tk] * b2f(qkv_s[tk][256 + oc]);
        outb[((size_t)bn * T1C + t) * HHC + oc] = f2b(acc);
    }
}

// fused score+aggregate over CSR, wave-per-(bt,n): 4 waves/block share one bt
__global__ __launch_bounds__(256) void sagg_k(const unsigned short* __restrict__ Q,
                                              const unsigned short* __restrict__ K,
                                              const unsigned short* __restrict__ V,
                                              const int* __restrict__ rowptr, const int* __restrict__ srcCSR,
                                              const float* __restrict__ ec, unsigned short* __restrict__ outb)
{
    int wv = threadIdx.x >> 6;
    int lane = threadIdx.x & 63;
    int blk = blockIdx.x;
    int bt = blk % BTC;
    int n  = (blk / BTC) * 4 + wv;
    int cg = lane & 15;
    int es = lane >> 4;       // 0..3
    int hh = cg >> 2;
    size_t base = (size_t)bt * NN;
    uint4 qd = *(const uint4*)(Q + (base + n) * HHC + cg * 8);
    unsigned qv[4] = {qd.x, qd.y, qd.z, qd.w};
    float q[8];
#pragma unroll
    for (int jj = 0; jj < 4; jj++) {
        q[2 * jj]     = __uint_as_float(qv[jj] << 16);
        q[2 * jj + 1] = __uint_as_float(qv[jj] & 0xFFFF0000u);
    }
    int s0 = rowptr[n], s1 = rowptr[n + 1];
    float acc[8];
#pragma unroll
    for (int j = 0; j < 8; j++) acc[j] = 0.f;
    float den = 0.f;
    for (int i = s0 + es; i < s1; i += 4) {
        int sn = srcCSR[i];
        uint4 kd = *(const uint4*)(K + (base + sn) * HHC + cg * 8);
        uint4 vd = *(const uint4*)(V + (base + sn) * HHC + cg * 8);
        float2 c2 = *(const float2*)(ec + (size_t)i * 8 + hh * 2);
        unsigned kv[4] = {kd.x, kd.y, kd.z, kd.w};
        float p = 0.f;
#pragma unroll
        for (int jj = 0; jj < 4; jj++) {
            p += q[2 * jj]     * __uint_as_float(kv[jj] << 16);
            p += q[2 * jj + 1] * __uint_as_float(kv[jj] & 0xFFFF0000u);
        }
        p += __shfl_xor(p, 1, 64);
        p += __shfl_xor(p, 2, 64);
        float w = __expf(p * c2.x + c2.y);
        unsigned vv[4] = {vd.x, vd.y, vd.z, vd.w};
#pragma unroll
        for (int jj = 0; jj < 4; jj++) {
            acc[2 * jj]     += w * __uint_as_float(vv[jj] << 16);
            acc[2 * jj + 1] += w * __uint_as_float(vv[jj] & 0xFFFF0000u);
        }
        den += w;
    }
#pragma unroll
    for (int j = 0; j < 8; j++) {
        acc[j] += __shfl_xor(acc[j], 16, 64);
        acc[j] += __shfl_xor(acc[j], 32, 64);
    }
    den += __shfl_xor(den, 16, 64);
    den += __shfl_xor(den, 32, 64);
    if (es == 0) {
        float inv = den + 1e-9f;
        unsigned short r[8];
#pragma unroll
        for (int j = 0; j < 8; j++) r[j] = f2b(acc[j] / inv);
        *(uint4*)(outb + (base + n) * HHC + cg * 8) = *(uint4*)r;
    }
}

// means over bt of hBT (f32, pre-residual base) and agg output (bf16)
__global__ __launch_bounds__(128) void hmean2_k(const float* __restrict__ hBT,
                                                const unsigned short* __restrict__ aggb,
                                                float* __restrict__ mA, unsigned short* __restrict__ mBb)
{
    int n = blockIdx.x, c = threadIdx.x;
    float sA = 0.f, sB = 0.f;
#pragma unroll
    for (int bt = 0; bt < BTC; bt++) {
        size_t off = ((size_t)bt * NN + n) * HHC + c;
        sA += hBT[off];
        sB += b2f(aggb[off]);
    }
    mA[n * HHC + c] = sA * (1.f / BTC);
    mBb[n * HHC + c] = f2b(sB * (1.f / BTC));
}

// ---------------- output head: one wave per row ----------------

__global__ __launch_bounds__(256) void out_k(const float* __restrict__ h, const float* __restrict__ Wout,
                                             const float* __restrict__ bout, float* __restrict__ out)
{
    int row = blockIdx.x * 4 + (threadIdx.x >> 6);
    int lane = threadIdx.x & 63;
    const float* hp = h + (size_t)row * HHC;
    float x0 = hp[lane], x1 = hp[lane + 64];
    float w00 = Wout[lane * 4 + 0], w01 = Wout[lane * 4 + 1];
    float w02 = Wout[lane * 4 + 2], w03 = Wout[lane * 4 + 3];
    float w10 = Wout[(lane + 64) * 4 + 0], w11 = Wout[(lane + 64) * 4 + 1];
    float w12 = Wout[(lane + 64) * 4 + 2], w13 = Wout[(lane + 64) * 4 + 3];
    float p0 = x0 * w00 + x1 * w10;
    float p1 = x0 * w01 + x1 * w11;
    float p2 = x0 * w02 + x1 * w12;
    float p3 = x0 * w03 + x1 * w13;
#pragma unroll
    for (int m = 32; m >= 1; m >>= 1) {
        p0 += __shfl_xor(p0, m, 64);
        p1 += __shfl_xor(p1, m, 64);
        p2 += __shfl_xor(p2, m, 64);
        p3 += __shfl_xor(p3, m, 64);
    }
    if (lane == 0) {
        float l0 = p0 + bout[0], l1 = p1 + bout[1], l2 = p2 + bout[2], l3 = p3 + bout[3];
        float mx = fmaxf(fmaxf(l0, l1), fmaxf(l2, l3));
        float e0 = __expf(l0 - mx), e1 = __expf(l1 - mx), e2 = __expf(l2 - mx), e3 = __expf(l3 - mx);
        float inv = 1.f / (e0 + e1 + e2 + e3);
        float4 o = {e0 * inv, e1 * inv, e2 * inv, e3 * inv};
        *(float4*)(out + (size_t)row * 4) = o;
    }
}

// ---------------- launch ----------------

extern "C" void kernel_launch(void* const* d_in, const int* in_sizes, int n_in,
                              void* d_out, int out_size, void* d_ws, size_t ws_size,
                              hipStream_t stream)
{
    const float* Xk      = (const float*)d_in[0];
    const float* temb    = (const float*)d_in[1];
    const float* stepemb = (const float*)d_in[2];
    const float* Wtr     = (const float*)d_in[3];
    const float* btr     = (const float*)d_in[4];
    const float* Win     = (const float*)d_in[5];
    const float* bin     = (const float*)d_in[6];
    const float* gin     = (const float*)d_in[7];
    const float* bein    = (const float*)d_in[8];
    const float* We      = (const float*)d_in[9];
    const float* bE      = (const float*)d_in[10];
    const float* aw      = (const float*)d_in[11];
    const float* ab      = (const float*)d_in[12];
    const float* ow      = (const float*)d_in[13];
    const float* ob      = (const float*)d_in[14];
    const float* tng     = (const float*)d_in[15];
    const float* tnb     = (const float*)d_in[16];
    const float* f1w     = (const float*)d_in[17];
    const float* f1b     = (const float*)d_in[18];
    const float* f2w     = (const float*)d_in[19];
    const float* f2b_    = (const float*)d_in[20];
    const float* fng     = (const float*)d_in[21];
    const float* fnb     = (const float*)d_in[22];
    const float* Wq      = (const float*)d_in[23];
    const float* Wk      = (const float*)d_in[24];
    const float* Wv      = (const float*)d_in[25];
    const float* Wo      = (const float*)d_in[26];
    const float* bo      = (const float*)d_in[27];
    const float* Wem     = (const float*)d_in[28];
    const float* bem     = (const float*)d_in[29];
    const float* Wea     = (const float*)d_in[30];
    const float* bea     = (const float*)d_in[31];
    const float* e1w     = (const float*)d_in[32];
    const float* e1b     = (const float*)d_in[33];
    const float* e2w     = (const float*)d_in[34];
    const float* e2b     = (const float*)d_in[35];
    const float* gng     = (const float*)d_in[36];
    const float* gnb     = (const float*)d_in[37];
    const float* eng     = (const float*)d_in[38];
    const float* enb     = (const float*)d_in[39];
    const float* Wout    = (const float*)d_in[40];
    const float* bout    = (const float*)d_in[41];
    const int*   kidx    = (const int*)d_in[42];
    const int*   eidx    = (const int*)d_in[43];
    float* outp = (float*)d_out;

    char* wsp = (char*)d_ws;
    auto alloc = [&](size_t nbytes) -> void* {
        void* p = (void*)wsp;
        wsp += (nbytes + 255) & ~(size_t)255;
        return p;
    };
    float* h     = (float*)alloc((size_t)MROWS * HHC * 4);
    unsigned short* hb = (unsigned short*)alloc((size_t)MROWS * HHC * 2);
    float* hBT   = (float*)alloc((size_t)MROWS * HHC * 4);
    float* bufC  = (float*)alloc((size_t)MROWS * 384 * 4);
    unsigned short* bufDb = (unsigned short*)alloc((size_t)MROWS * HHC * 2);
    float* ebuf  = (float*)alloc((size_t)EEC * DEC * 4);
    float* ec    = (float*)alloc((size_t)EEC * NHD * 2 * 4);
    float* P12   = (float*)alloc((size_t)NN * HHC * 4);
    float* mA    = (float*)alloc((size_t)NN * HHC * 4);
    unsigned short* mBb = (unsigned short*)alloc((size_t)NN * HHC * 2);
    float* tre   = (float*)alloc((size_t)T1C * HHC * 4);
    float* degmaxf = (float*)alloc(4);
    int* degi   = (int*)alloc((size_t)NN * 4);
    int* dst    = (int*)alloc((size_t)EEC * 4);
    int* srcA   = (int*)alloc((size_t)EEC * 4);
    int* srcCSR = (int*)alloc((size_t)EEC * 4);
    int* epos   = (int*)alloc((size_t)EEC * 4);
    int* rowptr = (int*)alloc((size_t)(NN + 1) * 4);
    int* cursor = (int*)alloc((size_t)NN * 4);
    unsigned short* awP   = (unsigned short*)alloc((size_t)LLC * 384 * 128 * 2);
    unsigned short* owP   = (unsigned short*)alloc((size_t)LLC * 128 * 128 * 2);
    unsigned short* f1P   = (unsigned short*)alloc((size_t)LLC * 256 * 128 * 2);
    unsigned short* f2P   = (unsigned short*)alloc((size_t)LLC * 128 * 256 * 2);
    unsigned short* WqkvP = (unsigned short*)alloc((size_t)LLC * 384 * 128 * 2);
    unsigned short* WoP   = (unsigned short*)alloc((size_t)LLC * 128 * 128 * 2);
    unsigned short* WoT   = (unsigned short*)alloc((size_t)LLC * 128 * 128 * 2);
    unsigned short* W12P  = (unsigned short*)alloc((size_t)LLC * 128 * 128 * 2);

    unsigned short* bufCb = (unsigned short*)bufC;
    unsigned short* Qc    = (unsigned short*)bufC;
    unsigned short* Kc    = Qc + (size_t)MROWS * HHC;
    unsigned short* Vc    = Kc + (size_t)MROWS * HHC;

    // all weight conversions + t_re in one dispatch
    conv_all_k<<<(CA_A10 + 255) / 256, 256, 0, stream>>>(
        aw, ow, f1w, f2w, Wq, Wk, Wv, Wo, e1w, temb, Wtr, btr,
        awP, owP, f1P, f2P, WqkvP, WoP, WoT, W12P, tre);

    zero_deg_k<<<(NN + 255) / 256, 256, 0, stream>>>(degi);
    build_edges_k<<<(EEC + 255) / 256, 256, 0, stream>>>(eidx, dst, srcA, degi);
    scan_k<<<1, 256, 0, stream>>>(degi, rowptr, cursor, degmaxf);
    // feat + layer-0 edge coefficients fused
    feat_k<<<(EEC + 255) / 256, 256, 0, stream>>>(dst, srcA, degi, degmaxf, cursor, srcCSR, epos, We, bE, ebuf,
                                                  Wem, bem, Wea, bea, ec);

    embed_k<<<MROWS / 4, 256, 0, stream>>>(Xk, temb, Win, bin, gin, bein, stepemb, kidx, h, hb);

    for (int l = 0; l < LLC; l++) {
        const unsigned short* awP_l   = awP   + (size_t)l * 384 * 128;
        const unsigned short* owP_l   = owP   + (size_t)l * 128 * 128;
        const unsigned short* f1P_l   = f1P   + (size_t)l * 256 * 128;
        const unsigned short* f2P_l   = f2P   + (size_t)l * 128 * 256;
        const unsigned short* WqkvP_l = WqkvP + (size_t)l * 384 * 128;
        const unsigned short* WoP_l   = WoP   + (size_t)l * 128 * 128;
        const unsigned short* WoT_l   = WoT   + (size_t)l * 128 * 128;
        const unsigned short* W12P_l  = W12P  + (size_t)l * 128 * 128;
        const float* ab_l  = ab  + (size_t)l * 3 * HHC;
        const float* ob_l  = ob  + (size_t)l * HHC;
        const float* tng_l = tng + (size_t)l * HHC;
        const float* tnb_l = tnb + (size_t)l * HHC;
        const float* f1b_l = f1b + (size_t)l * 256;
        const float* f2b_l = f2b_ + (size_t)l * HHC;
        const float* fng_l = fng + (size_t)l * HHC;
        const float* fnb_l = fnb + (size_t)l * HHC;
        const float* bo_l  = bo  + (size_t)l * HHC;
        const float* e1wE_l = e1w + ((size_t)l * 272 + 256) * 64;
        const float* e1b_l = e1b + (size_t)l * 64;
        const float* e2w_l = e2w + (size_t)l * 64 * DEC;
        const float* e2b_l = e2b + (size_t)l * DEC;
        const float* gng_l = gng + (size_t)l * HHC;
        const float* gnb_l = gnb + (size_t)l * HHC;
        const float* eng_l = eng + (size_t)l * DEC;
        const float* enb_l = enb + (size_t)l * DEC;
        int ln = (l + 1 < LLC) ? l + 1 : l;
        const float* WemN = Wem + (size_t)ln * DEC * NHD;
        const float* bemN = bem + (size_t)ln * NHD;
        const float* WeaN = Wea + (size_t)ln * DEC * NHD;
        const float* beaN = bea + (size_t)ln * NHD;
        int doEc = (l + 1 < LLC) ? 1 : 0;

        // temporal attention (qkv in bf16)
        run_gemm2<128, 0, 2>(hb, awP_l, ab_l, nullptr, bufCb, nullptr, nullptr, nullptr, nullptr, MROWS, 384, stream);
        temporal_attn_k<<<BBC * NN, 128, 0, stream>>>(bufCb, bufDb);
        // fused Wo-proj + temporal LN + FFN + final LN + t_re + transpose + graph-QKV GEMM
        offn_k<<<MROWS / 32, 256, 0, stream>>>(bufDb, owP_l, ob_l, h, tng_l, tnb_l,
                                               f1P_l, f2P_l, f1b_l, f2b_l, fng_l, fnb_l,
                                               tre, WqkvP_l, hBT, Qc, Kc, Vc);
        // fused score + weighted aggregate (wave-per-(bt,n), 4 waves/block share bt)
        sagg_k<<<BTC * (NN / 4), 256, 0, stream>>>(Qc, Kc, Vc, rowptr, srcCSR, ec, bufDb);
        // hmean by linearity: mean(hBT) + mean(agg) @ Wo + bo
        hmean2_k<<<NN, 128, 0, stream>>>(hBT, bufDb, mA, mBb);
        // Wo + residual + final LN + transpose back to [B,N,T1,H], fused
        run_gemm2<128, 5, 3>(bufDb, WoP_l, bo_l, h, hb, hBT, gng_l, gnb_l, nullptr, MROWS, 128, stream);
        // fused edge head: (mBb@WoT + mA + bo) -> bf16 -> @W12 -> P12 (LDS-staged)
        gemm_hm12_k<<<(NN + 31) / 32, 256, 0, stream>>>(mBb, WoT_l, mA, bo_l, W12P_l, P12);
        // per-edge MLP (in-place on ebuf) + next-layer edge coefficients
        emlp_k<<<EEC / 4, 256, 0, stream>>>(P12, dst, srcA, e1wE_l, e1b_l, e2w_l, e2b_l, eng_l, enb_l, ebuf,
                                            epos, WemN, bemN, WeaN, beaN, ec, doEc);
    }

    out_k<<<MROWS / 4, 256, 0, stream>>>(h, Wout, bout, outp);
}

// Round 23
// 893.038 us; speedup vs baseline: 1.0762x; 1.0164x over previous
//
#include <hip/hip_runtime.h>
#include <math.h>

#define NN 2000
#define T1C 12
#define BBC 2
#define HHC 128
#define NHD 4
#define DFD 32
#define LLC 4
#define DEC 16
#define TEC 16
#define CINC 12
#define E0C 32000
#define EEC 34000
#define BTC 24
#define MROWS 48000
#define EPSLN 1e-5f
#define SCALEQK 0.17677669529663687f

typedef __attribute__((ext_vector_type(8))) short short8;
typedef __attribute__((ext_vector_type(4))) float f32x4;

// ---------------- helpers ----------------

__device__ __forceinline__ unsigned short f2b(float f)
{
    unsigned u = __float_as_uint(f);
    return (unsigned short)((u + 0x7FFF + ((u >> 16) & 1)) >> 16);
}

__device__ __forceinline__ float b2f(unsigned short h)
{
    return __uint_as_float(((unsigned)h) << 16);
}

// ---------------- fused weight conversions + t_re (single dispatch) ----------------

__device__ __forceinline__ void convwp_one(const float* __restrict__ W, unsigned short* __restrict__ Bp,
                                           int idx, int K, int N, int noff, int Ntot)
{
    int l = idx / (K * N);
    int r = idx - l * (K * N);
    int k = r / N;
    int n = r - k * N + noff;
    size_t off = (size_t)l * K * Ntot +
                 ((size_t)((n >> 4) * (K >> 5) + (k >> 5)) << 9) +
                 (((k >> 3) & 3) << 7) + ((n & 15) << 3) + (k & 7);
    Bp[off] = f2b(W[idx]);
}

#define CA_A0 196608
#define CA_A1 (CA_A0 + 65536)
#define CA_A2 (CA_A1 + 131072)
#define CA_A3 (CA_A2 + 131072)
#define CA_A4 (CA_A3 + 65536)
#define CA_A5 (CA_A4 + 65536)
#define CA_A6 (CA_A5 + 65536)
#define CA_A7 (CA_A6 + 65536)
#define CA_A8 (CA_A7 + 65536)
#define CA_A9 (CA_A8 + 65536)
#define CA_A10 (CA_A9 + 1536)

__global__ __launch_bounds__(256) void conv_all_k(
    const float* __restrict__ aw, const float* __restrict__ ow,
    const float* __restrict__ f1w, const float* __restrict__ f2w,
    const float* __restrict__ Wq, const float* __restrict__ Wk, const float* __restrict__ Wv,
    const float* __restrict__ Wo, const float* __restrict__ e1w,
    const float* __restrict__ temb, const float* __restrict__ Wtr, const float* __restrict__ btr,
    unsigned short* __restrict__ awP, unsigned short* __restrict__ owP,
    unsigned short* __restrict__ f1P, unsigned short* __restrict__ f2P,
    unsigned short* __restrict__ WqkvP, unsigned short* __restrict__ WoP,
    unsigned short* __restrict__ WoT, unsigned short* __restrict__ W12P,
    float* __restrict__ tre)
{
    int idx = blockIdx.x * blockDim.x + threadIdx.x;
    if (idx < CA_A0) { convwp_one(aw, awP, idx, 128, 384, 0, 384); return; }
    if (idx < CA_A1) { convwp_one(ow, owP, idx - CA_A0, 128, 128, 0, 128); return; }
    if (idx < CA_A2) { convwp_one(f1w, f1P, idx - CA_A1, 128, 256, 0, 256); return; }
    if (idx < CA_A3) { convwp_one(f2w, f2P, idx - CA_A2, 256, 128, 0, 128); return; }
    if (idx < CA_A4) { convwp_one(Wq, WqkvP, idx - CA_A3, 128, 128, 0, 384); return; }
    if (idx < CA_A5) { convwp_one(Wk, WqkvP, idx - CA_A4, 128, 128, 128, 384); return; }
    if (idx < CA_A6) { convwp_one(Wv, WqkvP, idx - CA_A5, 128, 128, 256, 384); return; }
    if (idx < CA_A7) { convwp_one(Wo, WoP, idx - CA_A6, 128, 128, 0, 128); return; }
    if (idx < CA_A8) {
        int r2 = idx - CA_A7;
        int l = r2 >> 14, rr = r2 & 16383;
        int c = rr >> 7, k = rr & 127;
        WoT[r2] = f2b(Wo[((size_t)l * 128 + k) * 128 + c]);
        return;
    }
    if (idx < CA_A9) {
        int r2 = idx - CA_A8;
        int l = r2 >> 14, rr = r2 & 16383;
        int c = rr >> 7, k = rr & 127;
        int sk = (c < 64) ? k : k + 128;
        int sc = c & 63;
        W12P[r2] = f2b(e1w[((size_t)l * 272 + sk) * 64 + sc]);
        return;
    }
    if (idx < CA_A10) {
        int r2 = idx - CA_A9;
        int t = r2 >> 7, c = r2 & 127;
        float acc = btr[c];
#pragma unroll
        for (int k = 0; k < TEC; k++) acc += temb[t * TEC + k] * Wtr[k * HHC + c];
        tre[t * HHC + c] = acc;
        return;
    }
}

// ---------------- gemm2: 128x128-tile LDS-staged MFMA GEMM ----------------
// EPI: 0=none 1=gelu 2=res-add 3=res+LN 5=res+LN + transpose back to [B,N,T1,H]
// OHEAD (EPI==5): fuse the output head (h @ Wout + bout -> softmax) and skip C/Cb.

template<int K, int EPI, int OUTM, int OHEAD>
__global__ __launch_bounds__(256) void gemm2_k(
    const unsigned short* __restrict__ A, const unsigned short* __restrict__ Bp,
    const float* __restrict__ bias, float* __restrict__ C, unsigned short* __restrict__ Cb,
    const float* __restrict__ res, const float* __restrict__ gam, const float* __restrict__ bet,
    const float* __restrict__ trep,
    const float* __restrict__ Wout, const float* __restrict__ bout, float* __restrict__ outp,
    int M, int Ntot)
{
    __shared__ unsigned short A_s[128 * 16 * 8];
    __shared__ float red2[2][128][2];
    __shared__ float outred[2][128][4];
    __shared__ int rowp_s[128];

    int tid = threadIdx.x;
    int w = tid >> 6, lane = tid & 63;
    int wr = w & 1, wc = w >> 1;
    int quad = lane >> 4, lr = lane & 15;

    const unsigned short* abase = A + (size_t)blockIdx.x * 128 * K;
    int ntg0 = blockIdx.y * 8 + wc * 4;

    f32x4 acc[4][4];
#pragma unroll
    for (int mt = 0; mt < 4; mt++)
#pragma unroll
        for (int nt = 0; nt < 4; nt++) acc[mt][nt] = (f32x4){0.f, 0.f, 0.f, 0.f};

#pragma unroll
    for (int kb = 0; kb < K; kb += 128) {
        if (kb) __syncthreads();
#pragma unroll
        for (int j = 0; j < 8; j++) {
            int s = j * 256 + tid;
            int row = s >> 4, ks = s & 15;
            int ko = ks ^ (row & 15);
            uint4 d = *(const uint4*)(abase + (size_t)row * K + kb + ko * 8);
            *(uint4*)(A_s + s * 8) = d;
        }
        __syncthreads();
#pragma unroll
        for (int k0 = 0; k0 < 128; k0 += 32) {
            short8 af[4], bf[4];
#pragma unroll
            for (int mt = 0; mt < 4; mt++) {
                int row_l = wr * 64 + mt * 16 + lr;
                int koct = (k0 >> 3) + quad;
                int slot = row_l * 16 + (koct ^ lr);
                af[mt] = *(const short8*)(A_s + slot * 8);
            }
#pragma unroll
            for (int nt = 0; nt < 4; nt++) {
                size_t off = ((size_t)(ntg0 + nt) * (K >> 5) + ((kb + k0) >> 5)) * 512 + lane * 8;
                bf[nt] = *(const short8*)(Bp + off);
            }
#pragma unroll
            for (int mt = 0; mt < 4; mt++)
#pragma unroll
                for (int nt = 0; nt < 4; nt++)
                    acc[mt][nt] = __builtin_amdgcn_mfma_f32_16x16x32_bf16(af[mt], bf[nt], acc[mt][nt], 0, 0, 0);
        }
    }

    int rbase = blockIdx.x * 128 + wr * 64;
    int cbase = blockIdx.y * 128 + wc * 64;

    if constexpr (EPI != 3 && EPI != 5) {
#pragma unroll
        for (int mt = 0; mt < 4; mt++) {
#pragma unroll
            for (int nt = 0; nt < 4; nt++) {
                int colg = cbase + nt * 16 + lr;
                float bv = bias ? bias[colg] : 0.f;
#pragma unroll
                for (int i = 0; i < 4; i++) {
                    int row = rbase + mt * 16 + quad * 4 + i;
                    float x = acc[mt][nt][i] + bv;
                    if constexpr (EPI == 1) x = 0.5f * x * (1.f + erff(x * 0.70710678118654752f));
                    if constexpr (EPI == 2) x = res[(size_t)row * Ntot + colg] + x;
                    if constexpr (OUTM & 1) C[(size_t)row * Ntot + colg] = x;
                    if constexpr (OUTM & 2) Cb[(size_t)row * Ntot + colg] = f2b(x);
                }
            }
        }
    } else {
        float s[4][4], s2l[4][4];
#pragma unroll
        for (int mt = 0; mt < 4; mt++)
#pragma unroll
            for (int i = 0; i < 4; i++) { s[mt][i] = 0.f; s2l[mt][i] = 0.f; }
#pragma unroll
        for (int mt = 0; mt < 4; mt++) {
#pragma unroll
            for (int nt = 0; nt < 4; nt++) {
                int colg = cbase + nt * 16 + lr;
                float bv = bias[colg];
#pragma unroll
                for (int i = 0; i < 4; i++) {
                    int row = rbase + mt * 16 + quad * 4 + i;
                    float x = acc[mt][nt][i] + bv + res[(size_t)row * 128 + colg];
                    acc[mt][nt][i] = x;
                    s[mt][i] += x;
                    s2l[mt][i] += x * x;
                }
            }
        }
#pragma unroll
        for (int m = 1; m < 16; m <<= 1) {
#pragma unroll
            for (int mt = 0; mt < 4; mt++)
#pragma unroll
                for (int i = 0; i < 4; i++) {
                    s[mt][i]  += __shfl_xor(s[mt][i], m, 64);
                    s2l[mt][i] += __shfl_xor(s2l[mt][i], m, 64);
                }
        }
        if (lr == 0) {
#pragma unroll
            for (int mt = 0; mt < 4; mt++)
#pragma unroll
                for (int i = 0; i < 4; i++) {
                    int rl = wr * 64 + mt * 16 + quad * 4 + i;
                    red2[wc][rl][0] = s[mt][i];
                    red2[wc][rl][1] = s2l[mt][i];
                }
        }
        __syncthreads();
#pragma unroll
        for (int mt = 0; mt < 4; mt++) {
#pragma unroll
            for (int i = 0; i < 4; i++) {
                int rl = wr * 64 + mt * 16 + quad * 4 + i;
                float st  = red2[0][rl][0] + red2[1][rl][0];
                float s2t = red2[0][rl][1] + red2[1][rl][1];
                float mu = st * (1.f / 128.f);
                float rstd = rsqrtf(s2t * (1.f / 128.f) - mu * mu + EPSLN);
                int row = rbase + mt * 16 + quad * 4 + i;
                if constexpr (EPI == 5) {
                    int bt = row / NN, n = row - bt * NN;
                    int b = bt / T1C, t = bt - b * T1C;
                    size_t rowp = ((size_t)(b * NN + n)) * T1C + t;
                    float q0 = 0.f, q1 = 0.f, q2 = 0.f, q3 = 0.f;
                    if (OHEAD && lr == 0) rowp_s[rl] = (int)rowp;
#pragma unroll
                    for (int nt = 0; nt < 4; nt++) {
                        int colg = cbase + nt * 16 + lr;
                        float y = (acc[mt][nt][i] - mu) * rstd * gam[colg] + bet[colg];
                        if constexpr (OUTM & 1) C[rowp * 128 + colg] = y;
                        if constexpr (OUTM & 2) Cb[rowp * 128 + colg] = f2b(y);
                        if constexpr (OHEAD) {
                            q0 += y * Wout[colg * 4 + 0];
                            q1 += y * Wout[colg * 4 + 1];
                            q2 += y * Wout[colg * 4 + 2];
                            q3 += y * Wout[colg * 4 + 3];
                        }
                    }
                    if constexpr (OHEAD) {
#pragma unroll
                        for (int m2 = 1; m2 < 16; m2 <<= 1) {
                            q0 += __shfl_xor(q0, m2, 64);
                            q1 += __shfl_xor(q1, m2, 64);
                            q2 += __shfl_xor(q2, m2, 64);
                            q3 += __shfl_xor(q3, m2, 64);
                        }
                        if (lr == 0) {
                            outred[wc][rl][0] = q0;
                            outred[wc][rl][1] = q1;
                            outred[wc][rl][2] = q2;
                            outred[wc][rl][3] = q3;
                        }
                    }
                } else {
#pragma unroll
                    for (int nt = 0; nt < 4; nt++) {
                        int colg = cbase + nt * 16 + lr;
                        float y = (acc[mt][nt][i] - mu) * rstd * gam[colg] + bet[colg];
                        if constexpr (OUTM & 1) C[(size_t)row * 128 + colg] = y;
                        if constexpr (OUTM & 2) Cb[(size_t)row * 128 + colg] = f2b(y);
                    }
                }
            }
        }
        if constexpr (OHEAD) {
            __syncthreads();
            if (tid < 128) {
                int rl = tid;
                float l0 = outred[0][rl][0] + outred[1][rl][0] + bout[0];
                float l1 = outred[0][rl][1] + outred[1][rl][1] + bout[1];
                float l2 = outred[0][rl][2] + outred[1][rl][2] + bout[2];
                float l3 = outred[0][rl][3] + outred[1][rl][3] + bout[3];
                float mx = fmaxf(fmaxf(l0, l1), fmaxf(l2, l3));
                float e0 = __expf(l0 - mx), e1 = __expf(l1 - mx), e2 = __expf(l2 - mx), e3 = __expf(l3 - mx);
                float inv = 1.f / (e0 + e1 + e2 + e3);
                float4 o = {e0 * inv, e1 * inv, e2 * inv, e3 * inv};
                *(float4*)(outp + (size_t)rowp_s[rl] * 4) = o;
            }
        }
    }
}

template<int K, int EPI, int OUTM>
static void run_gemm2(const unsigned short* A, const unsigned short* Bp, const float* bias,
                      float* C, unsigned short* Cb, const float* res, const float* g, const float* be,
                      const float* trep, int M, int Ntot, hipStream_t stream)
{
    dim3 grid(M / 128, Ntot / 128);
    gemm2_k<K, EPI, OUTM, 0><<<grid, 256, 0, stream>>>(A, Bp, bias, C, Cb, res, g, be, trep,
                                                       nullptr, nullptr, nullptr, M, Ntot);
}

// ---------------- fused Wo+LN+FFN+LN + graph-QKV GEMM (32-row tile) ----------------

__global__ __launch_bounds__(256) void offn_k(
    const unsigned short* __restrict__ A,      // attn out bf16 [MROWS][128]
    const unsigned short* __restrict__ Wp,     // WoP layer slice (K=128, Ntot=128 packed)
    const float* __restrict__ ob_l,
    const float* __restrict__ resh,            // h_prev (f32)
    const float* __restrict__ tng_l, const float* __restrict__ tnb_l,
    const unsigned short* __restrict__ F1p,    // f1P layer slice (K=128, N=256 packed)
    const unsigned short* __restrict__ F2p,    // f2P layer slice (K=256, N=128 packed)
    const float* __restrict__ f1b_l, const float* __restrict__ f2b_l,
    const float* __restrict__ fng_l, const float* __restrict__ fnb_l,
    const float* __restrict__ trep,
    const unsigned short* __restrict__ Wqkv,   // WqkvP layer slice (K=128, Ntot=384 packed)
    float* __restrict__ C,                     // hBT (f32, transposed)
    unsigned short* __restrict__ Qc, unsigned short* __restrict__ Kc, unsigned short* __restrict__ Vc)
{
    __shared__ unsigned short A_s[32 * 16 * 8];
    __shared__ unsigned short M_s[32 * 16 * 8];
    __shared__ float red2[2][32][2];

    int tid = threadIdx.x;
    int w = tid >> 6, lane = tid & 63;
    int wr = w & 1, wc = w >> 1;
    int quad = lane >> 4, lr = lane & 15;

    const unsigned short* abase = A + (size_t)blockIdx.x * 32 * 128;

#pragma unroll
    for (int j = 0; j < 2; j++) {
        int s = j * 256 + tid;
        int row = s >> 4, ks = s & 15;
        int ko = ks ^ (row & 15);
        uint4 d = *(const uint4*)(abase + (size_t)row * 128 + ko * 8);
        *(uint4*)(A_s + s * 8) = d;
    }
    __syncthreads();

    // ---- Wo GEMM (K=128) ----
    f32x4 wacc[4];
#pragma unroll
    for (int nt = 0; nt < 4; nt++) wacc[nt] = (f32x4){0.f, 0.f, 0.f, 0.f};
#pragma unroll
    for (int k0 = 0; k0 < 128; k0 += 32) {
        int row_l = wr * 16 + lr;
        int koct = (k0 >> 3) + quad;
        int slot = row_l * 16 + (koct ^ lr);
        short8 af = *(const short8*)(A_s + slot * 8);
        short8 bf[4];
#pragma unroll
        for (int nt = 0; nt < 4; nt++) {
            size_t off = ((size_t)(wc * 4 + nt) * 4 + (k0 >> 5)) * 512 + lane * 8;
            bf[nt] = *(const short8*)(Wp + off);
        }
#pragma unroll
        for (int nt = 0; nt < 4; nt++)
            wacc[nt] = __builtin_amdgcn_mfma_f32_16x16x32_bf16(af, bf[nt], wacc[nt], 0, 0, 0);
    }

    int rbase = blockIdx.x * 32 + wr * 16;
    int cbase = wc * 64;

    // ---- temporal-LN epilogue: y kept in registers, bf16(y) staged into A_s ----
    float yv[4][4];
    {
        float s1[4], s2v[4];
#pragma unroll
        for (int i = 0; i < 4; i++) { s1[i] = 0.f; s2v[i] = 0.f; }
#pragma unroll
        for (int nt = 0; nt < 4; nt++) {
            int colg = cbase + nt * 16 + lr;
            float bv = ob_l[colg];
#pragma unroll
            for (int i = 0; i < 4; i++) {
                int row = rbase + quad * 4 + i;
                float x = wacc[nt][i] + bv + resh[(size_t)row * 128 + colg];
                yv[nt][i] = x;
                s1[i] += x;
                s2v[i] += x * x;
            }
        }
#pragma unroll
        for (int m = 1; m < 16; m <<= 1) {
#pragma unroll
            for (int i = 0; i < 4; i++) {
                s1[i]  += __shfl_xor(s1[i], m, 64);
                s2v[i] += __shfl_xor(s2v[i], m, 64);
            }
        }
        if (lr == 0) {
#pragma unroll
            for (int i = 0; i < 4; i++) {
                int rl = wr * 16 + quad * 4 + i;
                red2[wc][rl][0] = s1[i];
                red2[wc][rl][1] = s2v[i];
            }
        }
        __syncthreads();
#pragma unroll
        for (int i = 0; i < 4; i++) {
            int rl = wr * 16 + quad * 4 + i;
            float st  = red2[0][rl][0] + red2[1][rl][0];
            float s2t = red2[0][rl][1] + red2[1][rl][1];
            float mu = st * (1.f / 128.f);
            float rstd = rsqrtf(s2t * (1.f / 128.f) - mu * mu + EPSLN);
            int row = wr * 16 + quad * 4 + i;
#pragma unroll
            for (int nt = 0; nt < 4; nt++) {
                int col = cbase + nt * 16 + lr;
                float y = (yv[nt][i] - mu) * rstd * tng_l[col] + tnb_l[col];
                yv[nt][i] = y;
                int cchunk = col >> 3, celem = col & 7;
                int ks = cchunk ^ (row & 15);
                A_s[(row * 16 + ks) * 8 + celem] = f2b(y);
            }
        }
    }
    __syncthreads();

    // ---- FFN: f1 + gelu + f2 ----
    f32x4 facc[4];
#pragma unroll
    for (int nt = 0; nt < 4; nt++) facc[nt] = (f32x4){0.f, 0.f, 0.f, 0.f};

#pragma unroll
    for (int half = 0; half < 2; half++) {
        f32x4 macc[4];
#pragma unroll
        for (int nt = 0; nt < 4; nt++) macc[nt] = (f32x4){0.f, 0.f, 0.f, 0.f};
#pragma unroll
        for (int k0 = 0; k0 < 128; k0 += 32) {
            int row_l = wr * 16 + lr;
            int koct = (k0 >> 3) + quad;
            int slot = row_l * 16 + (koct ^ lr);
            short8 af = *(const short8*)(A_s + slot * 8);
            short8 bf[4];
#pragma unroll
            for (int nt = 0; nt < 4; nt++) {
                size_t off = ((size_t)(half * 8 + wc * 4 + nt) * 4 + (k0 >> 5)) * 512 + lane * 8;
                bf[nt] = *(const short8*)(F1p + off);
            }
#pragma unroll
            for (int nt = 0; nt < 4; nt++)
                macc[nt] = __builtin_amdgcn_mfma_f32_16x16x32_bf16(af, bf[nt], macc[nt], 0, 0, 0);
        }
        if (half) __syncthreads();
#pragma unroll
        for (int nt = 0; nt < 4; nt++) {
            int col = wc * 64 + nt * 16 + lr;
            float bv = f1b_l[half * 128 + col];
            int cchunk = col >> 3, celem = col & 7;
#pragma unroll
            for (int i = 0; i < 4; i++) {
                int row = wr * 16 + quad * 4 + i;
                float x = macc[nt][i] + bv;
                x = 0.5f * x * (1.f + erff(x * 0.70710678118654752f));
                int ks = cchunk ^ (row & 15);
                M_s[(row * 16 + ks) * 8 + celem] = f2b(x);
            }
        }
        __syncthreads();
#pragma unroll
        for (int k0 = 0; k0 < 128; k0 += 32) {
            int row_l = wr * 16 + lr;
            int koct = (k0 >> 3) + quad;
            int slot = row_l * 16 + (koct ^ lr);
            short8 af = *(const short8*)(M_s + slot * 8);
            short8 bf[4];
#pragma unroll
            for (int nt = 0; nt < 4; nt++) {
                size_t off = ((size_t)(wc * 4 + nt) * 8 + ((half * 128 + k0) >> 5)) * 512 + lane * 8;
                bf[nt] = *(const short8*)(F2p + off);
            }
#pragma unroll
            for (int nt = 0; nt < 4; nt++)
                facc[nt] = __builtin_amdgcn_mfma_f32_16x16x32_bf16(af, bf[nt], facc[nt], 0, 0, 0);
        }
    }

    // ---- final epilogue: res(yv) + LN + t_re; write hBT (f32) + stage bf16 into A_s ----
    float s[4], s2l[4];
#pragma unroll
    for (int i = 0; i < 4; i++) { s[i] = 0.f; s2l[i] = 0.f; }
#pragma unroll
    for (int nt = 0; nt < 4; nt++) {
        int colg = cbase + nt * 16 + lr;
        float bv = f2b_l[colg];
#pragma unroll
        for (int i = 0; i < 4; i++) {
            float x = facc[nt][i] + bv + yv[nt][i];
            facc[nt][i] = x;
            s[i] += x;
            s2l[i] += x * x;
        }
    }
#pragma unroll
    for (int m = 1; m < 16; m <<= 1) {
#pragma unroll
        for (int i = 0; i < 4; i++) {
            s[i]  += __shfl_xor(s[i], m, 64);
            s2l[i] += __shfl_xor(s2l[i], m, 64);
        }
    }
    if (lr == 0) {
#pragma unroll
        for (int i = 0; i < 4; i++) {
            int rl = wr * 16 + quad * 4 + i;
            red2[wc][rl][0] = s[i];
            red2[wc][rl][1] = s2l[i];
        }
    }
    __syncthreads();
    size_t rowp4[4];
#pragma unroll
    for (int i = 0; i < 4; i++) {
        int rl = wr * 16 + quad * 4 + i;
        float st  = red2[0][rl][0] + red2[1][rl][0];
        float s2t = red2[0][rl][1] + red2[1][rl][1];
        float mu = st * (1.f / 128.f);
        float rstd = rsqrtf(s2t * (1.f / 128.f) - mu * mu + EPSLN);
        int row = rbase + quad * 4 + i;
        int t = row % T1C;
        int bn = row / T1C;
        int b = bn / NN;
        int n = bn - b * NN;
        size_t rowp = (size_t)(b * T1C + t) * NN + n;
        rowp4[i] = rowp;
        const float* trow = trep + t * HHC;
        int rloc = wr * 16 + quad * 4 + i;
#pragma unroll
        for (int nt = 0; nt < 4; nt++) {
            int colg = cbase + nt * 16 + lr;
            float y = (facc[nt][i] - mu) * rstd * fng_l[colg] + fnb_l[colg] + trow[colg];
            C[rowp * 128 + colg] = y;
            int cchunk = colg >> 3, celem = colg & 7;
            int ks = cchunk ^ (rloc & 15);
            A_s[(rloc * 16 + ks) * 8 + celem] = f2b(y);
        }
    }
    __syncthreads();

    // ---- graph QKV GEMM: each wave 16 rows (wr) x 192 cols (wc), 3 groups of 4 tiles ----
#pragma unroll
    for (int g3 = 0; g3 < 3; g3++) {
        f32x4 qacc[4];
#pragma unroll
        for (int nt = 0; nt < 4; nt++) qacc[nt] = (f32x4){0.f, 0.f, 0.f, 0.f};
#pragma unroll
        for (int k0 = 0; k0 < 128; k0 += 32) {
            int row_l = wr * 16 + lr;
            int koct = (k0 >> 3) + quad;
            int slot = row_l * 16 + (koct ^ lr);
            short8 af = *(const short8*)(A_s + slot * 8);
            short8 bf[4];
#pragma unroll
            for (int nt = 0; nt < 4; nt++) {
                size_t off = ((size_t)(wc * 12 + g3 * 4 + nt) * 4 + (k0 >> 5)) * 512 + lane * 8;
                bf[nt] = *(const short8*)(Wqkv + off);
            }
#pragma unroll
            for (int nt = 0; nt < 4; nt++)
                qacc[nt] = __builtin_amdgcn_mfma_f32_16x16x32_bf16(af, bf[nt], qacc[nt], 0, 0, 0);
        }
#pragma unroll
        for (int nt = 0; nt < 4; nt++) {
            int colg = wc * 192 + (g3 * 4 + nt) * 16 + lr;
            unsigned short* dstbuf;
            int col;
            if (colg < 128)      { dstbuf = Qc; col = colg; }
            else if (colg < 256) { dstbuf = Kc; col = colg - 128; }
            else                 { dstbuf = Vc; col = colg - 256; }
#pragma unroll
            for (int i = 0; i < 4; i++)
                dstbuf[rowp4[i] * 128 + col] = f2b(qacc[nt][i]);
        }
    }
}

// ---------------- fused hm chain: hm = f2b(mBb@WoT + mA + bo) -> P12 = hm@W12 ----------------

__global__ __launch_bounds__(256) void gemm_hm12_k(
    const unsigned short* __restrict__ A,    // mBb
    const unsigned short* __restrict__ WT,   // WoT layer slice [c][k]
    const float* __restrict__ mA, const float* __restrict__ bo,
    const unsigned short* __restrict__ W12,  // W12P layer slice [c][k]
    float* __restrict__ P12)
{
    __shared__ unsigned short A_s[32 * 16 * 8];
    const int M = NN, K = 128;
    int tid = threadIdx.x;
    int w = tid >> 6, lane = tid & 63;
    int wr = w & 1, wc = w >> 1;
    int r0 = blockIdx.x * 32 + wr * 16;
    int c0 = wc * 64;
    int lr = lane & 15, quad = lane >> 4;
    int kq = quad * 8;
    int arow = r0 + lr; if (arow >= M) arow = M - 1;
    const unsigned short* ap = A + (size_t)arow * K + kq;
    const unsigned short* wp = WT + (size_t)(c0 + lr) * K + kq;

    // phase 1: mBb @ WoT
    f32x4 acc[4];
#pragma unroll
    for (int t = 0; t < 4; t++) acc[t] = (f32x4){0.f, 0.f, 0.f, 0.f};
    for (int k0 = 0; k0 < K; k0 += 32) {
        short8 a = *(const short8*)(ap + k0);
#pragma unroll
        for (int t = 0; t < 4; t++) {
            short8 b = *(const short8*)(wp + (size_t)t * 16 * K + k0);
            acc[t] = __builtin_amdgcn_mfma_f32_16x16x32_bf16(a, b, acc[t], 0, 0, 0);
        }
    }
    // epilogue: + mA + bo -> f2b, staged into LDS (swizzled A-fragment layout)
#pragma unroll
    for (int t = 0; t < 4; t++) {
        int col = c0 + t * 16 + lr;
        int cchunk = col >> 3, celem = col & 7;
#pragma unroll
        for (int i = 0; i < 4; i++) {
            int row = r0 + quad * 4 + i;
            int rr = row < M ? row : M - 1;
            float x = acc[t][i] + mA[(size_t)rr * 128 + col] + bo[col];
            int rloc = wr * 16 + quad * 4 + i;
            int ks = cchunk ^ (rloc & 15);
            A_s[(rloc * 16 + ks) * 8 + celem] = f2b(x);
        }
    }
    __syncthreads();

    // phase 2: P12 = hm @ W12
    f32x4 acc2[4];
#pragma unroll
    for (int t = 0; t < 4; t++) acc2[t] = (f32x4){0.f, 0.f, 0.f, 0.f};
    const unsigned short* wp2 = W12 + (size_t)(c0 + lr) * 128 + kq;
#pragma unroll
    for (int k0 = 0; k0 < 128; k0 += 32) {
        int row_l = wr * 16 + lr;
        int koct = (k0 >> 3) + quad;
        int slot = row_l * 16 + (koct ^ lr);
        short8 af = *(const short8*)(A_s + slot * 8);
#pragma unroll
        for (int t = 0; t < 4; t++) {
            short8 b = *(const short8*)(wp2 + (size_t)t * 16 * 128 + k0);
            acc2[t] = __builtin_amdgcn_mfma_f32_16x16x32_bf16(af, b, acc2[t], 0, 0, 0);
        }
    }
#pragma unroll
    for (int t = 0; t < 4; t++) {
        int col = c0 + t * 16 + lr;
#pragma unroll
        for (int i = 0; i < 4; i++) {
            int row = r0 + quad * 4 + i;
            if (row < M) P12[(size_t)row * 128 + col] = acc2[t][i];
        }
    }
}

// ---------------- fused per-edge MLP (+ next-layer edge coefficients) ----------------

__global__ __launch_bounds__(256) void emlp_k(const float* __restrict__ P12,
                                              const int* __restrict__ dst, const int* __restrict__ src,
                                              const float* __restrict__ e1wE, const float* __restrict__ e1b_l,
                                              const float* __restrict__ e2w_l, const float* __restrict__ e2b_l,
                                              const float* __restrict__ g, const float* __restrict__ be,
                                              float* __restrict__ e,
                                              const int* __restrict__ epos,
                                              const float* __restrict__ WemN, const float* __restrict__ bemN,
                                              const float* __restrict__ WeaN, const float* __restrict__ beaN,
                                              float* __restrict__ ec, int doEc)
{
    __shared__ float tl[4][64];
    int wv = threadIdx.x >> 6, l = threadIdx.x & 63;
    int r = blockIdx.x * 4 + wv;           // EEC = 34000 = 8500*4, no remainder
    int d = dst[r], s = src[r];
    const float* ep = e + (size_t)r * DEC;
    float t = P12[(size_t)d * 128 + l] + P12[(size_t)s * 128 + 64 + l] + e1b_l[l];
#pragma unroll
    for (int k = 0; k < DEC; k++) t += ep[k] * e1wE[k * 64 + l];
    t = 0.5f * t * (1.f + erff(t * 0.70710678118654752f));
    tl[wv][l] = t;
    __syncthreads();
    int c = l & 15, kq = l >> 4;
    float p = 0.f;
#pragma unroll
    for (int j = 0; j < 16; j++) p += tl[wv][kq * 16 + j] * e2w_l[(kq * 16 + j) * 16 + c];
    p += __shfl_xor(p, 16, 64);
    p += __shfl_xor(p, 32, 64);
    float x = p + e2b_l[c] + ep[c];
    float s1 = x, s2 = x * x;
#pragma unroll
    for (int m = 1; m < 16; m <<= 1) {
        s1 += __shfl_xor(s1, m, 64);
        s2 += __shfl_xor(s2, m, 64);
    }
    float mu = s1 * (1.f / 16.f);
    float rstd = rsqrtf(s2 * (1.f / 16.f) - mu * mu + EPSLN);
    float y = (x - mu) * rstd * g[c] + be[c];
    if (l < 16) e[(size_t)r * DEC + c] = y;

    if (doEc) {
        int hh = l >> 4;      // head = replica group 0..3
        float pem = y * WemN[c * NHD + hh];
        float pea = y * WeaN[c * NHD + hh];
#pragma unroll
        for (int m = 1; m < 16; m <<= 1) {
            pem += __shfl_xor(pem, m, 64);
            pea += __shfl_xor(pea, m, 64);
        }
        if (c == 0) {
            int pos = epos[r];
            ec[(size_t)pos * 8 + hh * 2]     = (pem + bemN[hh] + 1.f) * SCALEQK;
            ec[(size_t)pos * 8 + hh * 2 + 1] = pea + beaN[hh];
        }
    }
}

// ---------------- graph precompute ----------------

__global__ __launch_bounds__(256) void zero_deg_k(int* __restrict__ degi)
{
    int i = blockIdx.x * blockDim.x + threadIdx.x;
    if (i < NN) degi[i] = 0;
}

__global__ __launch_bounds__(256) void build_edges_k(const int* __restrict__ eidx,
                                                     int* __restrict__ dst, int* __restrict__ src,
                                                     int* __restrict__ degi)
{
    int e = blockIdx.x * blockDim.x + threadIdx.x;
    if (e >= EEC) return;
    int d, s;
    if (e < E0C) { d = eidx[e]; s = eidx[E0C + e]; }
    else { d = e - E0C; s = e - E0C; }
    dst[e] = d;
    src[e] = s;
    atomicAdd(&degi[d], 1);
}

__global__ __launch_bounds__(256) void scan_k(const int* __restrict__ degi, int* __restrict__ rowptr,
                                              int* __restrict__ cursor, float* __restrict__ degmaxf)
{
    __shared__ int ssum[256];
    __shared__ int smx[256];
    int tid = threadIdx.x;
    int vals[8];
    int s = 0, mx = 0;
    int base = tid * 8;
#pragma unroll
    for (int j = 0; j < 8; j++) {
        int idx = base + j;
        int v = (idx < NN) ? degi[idx] : 0;
        vals[j] = v; s += v; mx = max(mx, v);
    }
    ssum[tid] = s; smx[tid] = mx;
    __syncthreads();
    for (int off = 1; off < 256; off <<= 1) {
        int t = (tid >= off) ? ssum[tid - off] : 0;
        __syncthreads();
        ssum[tid] += t;
        __syncthreads();
    }
    for (int off = 128; off > 0; off >>= 1) {
        if (tid < off) smx[tid] = max(smx[tid], smx[tid + off]);
        __syncthreads();
    }
    if (tid == 0) *degmaxf = fmaxf((float)smx[0], 1.f);
    int running = ssum[tid] - s;
#pragma unroll
    for (int j = 0; j < 8; j++) {
        int idx = base + j;
        if (idx < NN) { rowptr[idx] = running; cursor[idx] = running; running += vals[j]; }
    }
    if (tid == 255) rowptr[NN] = ssum[255];
}

// feat + layer-0 edge coefficients, fused
__global__ __launch_bounds__(256) void feat_k(const int* __restrict__ dst, const int* __restrict__ src,
                                              const int* __restrict__ degi, const float* __restrict__ degmaxf,
                                              int* __restrict__ cursor, int* __restrict__ srcCSR,
                                              int* __restrict__ epos,
                                              const float* __restrict__ We, const float* __restrict__ bE,
                                              float* __restrict__ e,
                                              const float* __restrict__ Wem0, const float* __restrict__ bem0,
                                              const float* __restrict__ Wea0, const float* __restrict__ bea0,
                                              float* __restrict__ ec)
{
    int ei = blockIdx.x * blockDim.x + threadIdx.x;
    if (ei >= EEC) return;
    int d = dst[ei], s = src[ei];
    int pos = atomicAdd(&cursor[d], 1);
    srcCSR[pos] = s;
    epos[ei] = pos;
    float dm = *degmaxf;
    float degd = (float)degi[d], degs = (float)degi[s];
    float f0 = 1.f / fmaxf(degd, 1.f);
    float f1 = degs / dm, f2 = degd / dm;
    float ev[DEC];
#pragma unroll
    for (int c = 0; c < DEC; c++) {
        float v = bE[c] + f0 * We[c] + f1 * We[DEC + c] + f2 * We[2 * DEC + c];
        ev[c] = v;
        e[ei * DEC + c] = v;
    }
#pragma unroll
    for (int hh = 0; hh < NHD; hh++) {
        float a = bem0[hh], b2 = bea0[hh];
#pragma unroll
        for (int k = 0; k < DEC; k++) { a += ev[k] * Wem0[k * NHD + hh]; b2 += ev[k] * Wea0[k * NHD + hh]; }
        ec[(size_t)pos * 8 + hh * 2]     = (a + 1.f) * SCALEQK;
        ec[(size_t)pos * 8 + hh * 2 + 1] = b2;
    }
}

// ---------------- embedding: wave-per-row, shfl-only reduction ----------------

__global__ __launch_bounds__(256) void embed_k(const float* __restrict__ Xk, const float* __restrict__ temb,
                                               const float* __restrict__ Win, const float* __restrict__ bin,
                                               const float* __restrict__ g, const float* __restrict__ be,
                                               const float* __restrict__ stepemb, const int* __restrict__ kidx,
                                               float* __restrict__ h, unsigned short* __restrict__ hb)
{
    int row = blockIdx.x * 4 + (threadIdx.x >> 6);
    int l = threadIdx.x & 63;
    int t = row % T1C;
    int bn = row / T1C;
    int b = bn / NN;
    const float* xk = Xk + (size_t)row * CINC;
    const float* tp = temb + t * TEC;
    float acc0 = bin[l], acc1 = bin[l + 64];
#pragma unroll
    for (int k = 0; k < CINC; k++) {
        float xv = xk[k];
        acc0 += xv * Win[k * HHC + l];
        acc1 += xv * Win[k * HHC + l + 64];
    }
#pragma unroll
    for (int k = 0; k < TEC; k++) {
        float xv = tp[k];
        acc0 += xv * Win[(CINC + k) * HHC + l];
        acc1 += xv * Win[(CINC + k) * HHC + l + 64];
    }
    float s = acc0 + acc1, s2 = acc0 * acc0 + acc1 * acc1;
#pragma unroll
    for (int m = 32; m >= 1; m >>= 1) {
        s  += __shfl_xor(s, m, 64);
        s2 += __shfl_xor(s2, m, 64);
    }
    float mu = s * (1.f / 128.f);
    float rstd = rsqrtf(s2 * (1.f / 128.f) - mu * mu + EPSLN);
    const float* se = stepemb + (size_t)kidx[b] * HHC;
    float v0 = (acc0 - mu) * rstd * g[l] + be[l] + se[l];
    float v1 = (acc1 - mu) * rstd * g[l + 64] + be[l + 64] + se[l + 64];
    size_t ob = (size_t)row * HHC;
    h[ob + l] = v0;
    h[ob + l + 64] = v1;
    hb[ob + l] = f2b(v0);
    hb[ob + l + 64] = f2b(v1);
}

// ---------------- temporal attention: raw-bf16 LDS staging ----------------

__global__ __launch_bounds__(128) void temporal_attn_k(const unsigned short* __restrict__ qkvb,
                                                       unsigned short* __restrict__ outb)
{
    int bn = blockIdx.x;
    __shared__ unsigned short qkv_s[T1C][408];
    __shared__ float s[NHD][T1C][T1C];
    int tid = threadIdx.x;
    int hh = tid >> 5, lane = tid & 31;
    const unsigned short* base = qkvb + (size_t)bn * T1C * 384;
    for (int cIdx = tid; cIdx < 576; cIdx += 128) {
        uint4 d = *(const uint4*)(base + cIdx * 8);
        int t = cIdx / 48;
        int c0 = (cIdx - t * 48) * 8;
        *(uint4*)(&qkv_s[t][c0]) = d;
    }
    __syncthreads();
    for (int idx = lane; idx < T1C * T1C; idx += 32) {
        int tq = idx / T1C, tk = idx - tq * T1C;
        const unsigned* qp = (const unsigned*)&qkv_s[tq][hh * 32];
        const unsigned* kp = (const unsigned*)&qkv_s[tk][128 + hh * 32];
        float acc = 0.f;
#pragma unroll
        for (int d = 0; d < 16; d++) {
            unsigned a = qp[d], b = kp[d];
            acc += __uint_as_float(a << 16) * __uint_as_float(b << 16);
            acc += __uint_as_float(a & 0xFFFF0000u) * __uint_as_float(b & 0xFFFF0000u);
        }
        s[hh][tq][tk] = acc * SCALEQK;
    }
    __syncthreads();
    if (tid < NHD * T1C) {
        int h2 = tid / T1C, tq = tid - h2 * T1C;
        float mx = -1e30f;
#pragma unroll
        for (int j = 0; j < T1C; j++) mx = fmaxf(mx, s[h2][tq][j]);
        float sum = 0.f;
#pragma unroll
        for (int j = 0; j < T1C; j++) { float ex = __expf(s[h2][tq][j] - mx); s[h2][tq][j] = ex; sum += ex; }
        float inv = 1.f / sum;
#pragma unroll
        for (int j = 0; j < T1C; j++) s[h2][tq][j] *= inv;
    }
    __syncthreads();
    int oc = hh * 32 + lane;
#pragma unroll
    for (int t = 0; t < T1C; t++) {
        float acc = 0.f;
#pragma unroll
        for (int tk = 0; tk < T1C; tk++) acc += s[hh][t][tk] * b2f(qkv_s[tk][256 + oc]);
        outb[((size_t)bn * T1C + t) * HHC + oc] = f2b(acc);
    }
}

// fused score+aggregate over CSR, wave-per-(bt,n): 4 waves/block share one bt
__global__ __launch_bounds__(256) void sagg_k(const unsigned short* __restrict__ Q,
                                              const unsigned short* __restrict__ K,
                                              const unsigned short* __restrict__ V,
                                              const int* __restrict__ rowptr, const int* __restrict__ srcCSR,
                                              const float* __restrict__ ec, unsigned short* __restrict__ outb)
{
    int wv = threadIdx.x >> 6;
    int lane = threadIdx.x & 63;
    int blk = blockIdx.x;
    int bt = blk % BTC;
    int n  = (blk / BTC) * 4 + wv;
    int cg = lane & 15;
    int es = lane >> 4;       // 0..3
    int hh = cg >> 2;
    size_t base = (size_t)bt * NN;
    uint4 qd = *(const uint4*)(Q + (base + n) * HHC + cg * 8);
    unsigned qv[4] = {qd.x, qd.y, qd.z, qd.w};
    float q[8];
#pragma unroll
    for (int jj = 0; jj < 4; jj++) {
        q[2 * jj]     = __uint_as_float(qv[jj] << 16);
        q[2 * jj + 1] = __uint_as_float(qv[jj] & 0xFFFF0000u);
    }
    int s0 = rowptr[n], s1 = rowptr[n + 1];
    float acc[8];
#pragma unroll
    for (int j = 0; j < 8; j++) acc[j] = 0.f;
    float den = 0.f;
    for (int i = s0 + es; i < s1; i += 4) {
        int sn = srcCSR[i];
        uint4 kd = *(const uint4*)(K + (base + sn) * HHC + cg * 8);
        uint4 vd = *(const uint4*)(V + (base + sn) * HHC + cg * 8);
        float2 c2 = *(const float2*)(ec + (size_t)i * 8 + hh * 2);
        unsigned kv[4] = {kd.x, kd.y, kd.z, kd.w};
        float p = 0.f;
#pragma unroll
        for (int jj = 0; jj < 4; jj++) {
            p += q[2 * jj]     * __uint_as_float(kv[jj] << 16);
            p += q[2 * jj + 1] * __uint_as_float(kv[jj] & 0xFFFF0000u);
        }
        p += __shfl_xor(p, 1, 64);
        p += __shfl_xor(p, 2, 64);
        float w = __expf(p * c2.x + c2.y);
        unsigned vv[4] = {vd.x, vd.y, vd.z, vd.w};
#pragma unroll
        for (int jj = 0; jj < 4; jj++) {
            acc[2 * jj]     += w * __uint_as_float(vv[jj] << 16);
            acc[2 * jj + 1] += w * __uint_as_float(vv[jj] & 0xFFFF0000u);
        }
        den += w;
    }
#pragma unroll
    for (int j = 0; j < 8; j++) {
        acc[j] += __shfl_xor(acc[j], 16, 64);
        acc[j] += __shfl_xor(acc[j], 32, 64);
    }
    den += __shfl_xor(den, 16, 64);
    den += __shfl_xor(den, 32, 64);
    if (es == 0) {
        float inv = den + 1e-9f;
        unsigned short r[8];
#pragma unroll
        for (int j = 0; j < 8; j++) r[j] = f2b(acc[j] / inv);
        *(uint4*)(outb + (base + n) * HHC + cg * 8) = *(uint4*)r;
    }
}

// means over bt of hBT (f32, pre-residual base) and agg output (bf16)
__global__ __launch_bounds__(128) void hmean2_k(const float* __restrict__ hBT,
                                                const unsigned short* __restrict__ aggb,
                                                float* __restrict__ mA, unsigned short* __restrict__ mBb)
{
    int n = blockIdx.x, c = threadIdx.x;
    float sA = 0.f, sB = 0.f;
#pragma unroll
    for (int bt = 0; bt < BTC; bt++) {
        size_t off = ((size_t)bt * NN + n) * HHC + c;
        sA += hBT[off];
        sB += b2f(aggb[off]);
    }
    mA[n * HHC + c] = sA * (1.f / BTC);
    mBb[n * HHC + c] = f2b(sB * (1.f / BTC));
}

// ---------------- launch ----------------

extern "C" void kernel_launch(void* const* d_in, const int* in_sizes, int n_in,
                              void* d_out, int out_size, void* d_ws, size_t ws_size,
                              hipStream_t stream)
{
    const float* Xk      = (const float*)d_in[0];
    const float* temb    = (const float*)d_in[1];
    const float* stepemb = (const float*)d_in[2];
    const float* Wtr     = (const float*)d_in[3];
    const float* btr     = (const float*)d_in[4];
    const float* Win     = (const float*)d_in[5];
    const float* bin     = (const float*)d_in[6];
    const float* gin     = (const float*)d_in[7];
    const float* bein    = (const float*)d_in[8];
    const float* We      = (const float*)d_in[9];
    const float* bE      = (const float*)d_in[10];
    const float* aw      = (const float*)d_in[11];
    const float* ab      = (const float*)d_in[12];
    const float* ow      = (const float*)d_in[13];
    const float* ob      = (const float*)d_in[14];
    const float* tng     = (const float*)d_in[15];
    const float* tnb     = (const float*)d_in[16];
    const float* f1w     = (const float*)d_in[17];
    const float* f1b     = (const float*)d_in[18];
    const float* f2w     = (const float*)d_in[19];
    const float* f2b_    = (const float*)d_in[20];
    const float* fng     = (const float*)d_in[21];
    const float* fnb     = (const float*)d_in[22];
    const float* Wq      = (const float*)d_in[23];
    const float* Wk      = (const float*)d_in[24];
    const float* Wv      = (const float*)d_in[25];
    const float* Wo      = (const float*)d_in[26];
    const float* bo      = (const float*)d_in[27];
    const float* Wem     = (const float*)d_in[28];
    const float* bem     = (const float*)d_in[29];
    const float* Wea     = (const float*)d_in[30];
    const float* bea     = (const float*)d_in[31];
    const float* e1w     = (const float*)d_in[32];
    const float* e1b     = (const float*)d_in[33];
    const float* e2w     = (const float*)d_in[34];
    const float* e2b     = (const float*)d_in[35];
    const float* gng     = (const float*)d_in[36];
    const float* gnb     = (const float*)d_in[37];
    const float* eng     = (const float*)d_in[38];
    const float* enb     = (const float*)d_in[39];
    const float* Wout    = (const float*)d_in[40];
    const float* bout    = (const float*)d_in[41];
    const int*   kidx    = (const int*)d_in[42];
    const int*   eidx    = (const int*)d_in[43];
    float* outp = (float*)d_out;

    char* wsp = (char*)d_ws;
    auto alloc = [&](size_t nbytes) -> void* {
        void* p = (void*)wsp;
        wsp += (nbytes + 255) & ~(size_t)255;
        return p;
    };
    float* h     = (float*)alloc((size_t)MROWS * HHC * 4);
    unsigned short* hb = (unsigned short*)alloc((size_t)MROWS * HHC * 2);
    float* hBT   = (float*)alloc((size_t)MROWS * HHC * 4);
    float* bufC  = (float*)alloc((size_t)MROWS * 384 * 4);
    unsigned short* bufDb = (unsigned short*)alloc((size_t)MROWS * HHC * 2);
    float* ebuf  = (float*)alloc((size_t)EEC * DEC * 4);
    float* ec    = (float*)alloc((size_t)EEC * NHD * 2 * 4);
    float* P12   = (float*)alloc((size_t)NN * HHC * 4);
    float* mA    = (float*)alloc((size_t)NN * HHC * 4);
    unsigned short* mBb = (unsigned short*)alloc((size_t)NN * HHC * 2);
    float* tre   = (float*)alloc((size_t)T1C * HHC * 4);
    float* degmaxf = (float*)alloc(4);
    int* degi   = (int*)alloc((size_t)NN * 4);
    int* dst    = (int*)alloc((size_t)EEC * 4);
    int* srcA   = (int*)alloc((size_t)EEC * 4);
    int* srcCSR = (int*)alloc((size_t)EEC * 4);
    int* epos   = (int*)alloc((size_t)EEC * 4);
    int* rowptr = (int*)alloc((size_t)(NN + 1) * 4);
    int* cursor = (int*)alloc((size_t)NN * 4);
    unsigned short* awP   = (unsigned short*)alloc((size_t)LLC * 384 * 128 * 2);
    unsigned short* owP   = (unsigned short*)alloc((size_t)LLC * 128 * 128 * 2);
    unsigned short* f1P   = (unsigned short*)alloc((size_t)LLC * 256 * 128 * 2);
    unsigned short* f2P   = (unsigned short*)alloc((size_t)LLC * 128 * 256 * 2);
    unsigned short* WqkvP = (unsigned short*)alloc((size_t)LLC * 384 * 128 * 2);
    unsigned short* WoP   = (unsigned short*)alloc((size_t)LLC * 128 * 128 * 2);
    unsigned short* WoT   = (unsigned short*)alloc((size_t)LLC * 128 * 128 * 2);
    unsigned short* W12P  = (unsigned short*)alloc((size_t)LLC * 128 * 128 * 2);

    unsigned short* bufCb = (unsigned short*)bufC;
    unsigned short* Qc    = (unsigned short*)bufC;
    unsigned short* Kc    = Qc + (size_t)MROWS * HHC;
    unsigned short* Vc    = Kc + (size_t)MROWS * HHC;

    // all weight conversions + t_re in one dispatch
    conv_all_k<<<(CA_A10 + 255) / 256, 256, 0, stream>>>(
        aw, ow, f1w, f2w, Wq, Wk, Wv, Wo, e1w, temb, Wtr, btr,
        awP, owP, f1P, f2P, WqkvP, WoP, WoT, W12P, tre);

    zero_deg_k<<<(NN + 255) / 256, 256, 0, stream>>>(degi);
    build_edges_k<<<(EEC + 255) / 256, 256, 0, stream>>>(eidx, dst, srcA, degi);
    scan_k<<<1, 256, 0, stream>>>(degi, rowptr, cursor, degmaxf);
    // feat + layer-0 edge coefficients fused
    feat_k<<<(EEC + 255) / 256, 256, 0, stream>>>(dst, srcA, degi, degmaxf, cursor, srcCSR, epos, We, bE, ebuf,
                                                  Wem, bem, Wea, bea, ec);

    embed_k<<<MROWS / 4, 256, 0, stream>>>(Xk, temb, Win, bin, gin, bein, stepemb, kidx, h, hb);

    for (int l = 0; l < LLC; l++) {
        const unsigned short* awP_l   = awP   + (size_t)l * 384 * 128;
        const unsigned short* owP_l   = owP   + (size_t)l * 128 * 128;
        const unsigned short* f1P_l   = f1P   + (size_t)l * 256 * 128;
        const unsigned short* f2P_l   = f2P   + (size_t)l * 128 * 256;
        const unsigned short* WqkvP_l = WqkvP + (size_t)l * 384 * 128;
        const unsigned short* WoP_l   = WoP   + (size_t)l * 128 * 128;
        const unsigned short* WoT_l   = WoT   + (size_t)l * 128 * 128;
        const unsigned short* W12P_l  = W12P  + (size_t)l * 128 * 128;
        const float* ab_l  = ab  + (size_t)l * 3 * HHC;
        const float* ob_l  = ob  + (size_t)l * HHC;
        const float* tng_l = tng + (size_t)l * HHC;
        const float* tnb_l = tnb + (size_t)l * HHC;
        const float* f1b_l = f1b + (size_t)l * 256;
        const float* f2b_l = f2b_ + (size_t)l * HHC;
        const float* fng_l = fng + (size_t)l * HHC;
        const float* fnb_l = fnb + (size_t)l * HHC;
        const float* bo_l  = bo  + (size_t)l * HHC;
        const float* e1wE_l = e1w + ((size_t)l * 272 + 256) * 64;
        const float* e1b_l = e1b + (size_t)l * 64;
        const float* e2w_l = e2w + (size_t)l * 64 * DEC;
        const float* e2b_l = e2b + (size_t)l * DEC;
        const float* gng_l = gng + (size_t)l * HHC;
        const float* gnb_l = gnb + (size_t)l * HHC;
        const float* eng_l = eng + (size_t)l * DEC;
        const float* enb_l = enb + (size_t)l * DEC;
        int ln = (l + 1 < LLC) ? l + 1 : l;
        const float* WemN = Wem + (size_t)ln * DEC * NHD;
        const float* bemN = bem + (size_t)ln * NHD;
        const float* WeaN = Wea + (size_t)ln * DEC * NHD;
        const float* beaN = bea + (size_t)ln * NHD;
        int doEc = (l + 1 < LLC) ? 1 : 0;

        // temporal attention (qkv in bf16)
        run_gemm2<128, 0, 2>(hb, awP_l, ab_l, nullptr, bufCb, nullptr, nullptr, nullptr, nullptr, MROWS, 384, stream);
        temporal_attn_k<<<BBC * NN, 128, 0, stream>>>(bufCb, bufDb);
        // fused Wo-proj + temporal LN + FFN + final LN + t_re + transpose + graph-QKV GEMM
        offn_k<<<MROWS / 32, 256, 0, stream>>>(bufDb, owP_l, ob_l, h, tng_l, tnb_l,
                                               f1P_l, f2P_l, f1b_l, f2b_l, fng_l, fnb_l,
                                               tre, WqkvP_l, hBT, Qc, Kc, Vc);
        // fused score + weighted aggregate (wave-per-(bt,n), 4 waves/block share bt)
        sagg_k<<<BTC * (NN / 4), 256, 0, stream>>>(Qc, Kc, Vc, rowptr, srcCSR, ec, bufDb);
        // hmean by linearity: mean(hBT) + mean(agg) @ Wo + bo
        hmean2_k<<<NN, 128, 0, stream>>>(hBT, bufDb, mA, mBb);
        // Wo + residual + final LN + transpose back to [B,N,T1,H]
        // last layer: fuse the output head (h @ Wout + bout -> softmax -> out), skip h/hb stores
        if (l + 1 < LLC) {
            run_gemm2<128, 5, 3>(bufDb, WoP_l, bo_l, h, hb, hBT, gng_l, gnb_l, nullptr, MROWS, 128, stream);
        } else {
            dim3 grid(MROWS / 128, 1);
            gemm2_k<128, 5, 0, 1><<<grid, 256, 0, stream>>>(bufDb, WoP_l, bo_l, nullptr, nullptr,
                                                            hBT, gng_l, gnb_l, nullptr,
                                                            Wout, bout, outp, MROWS, 128);
        }
        // fused edge head: (mBb@WoT + mA + bo) -> bf16 -> @W12 -> P12 (LDS-staged)
        gemm_hm12_k<<<(NN + 31) / 32, 256, 0, stream>>>(mBb, WoT_l, mA, bo_l, W12P_l, P12);
        // per-edge MLP (in-place on ebuf) + next-layer edge coefficients
        emlp_k<<<EEC / 4, 256, 0, stream>>>(P12, dst, srcA, e1wE_l, e1b_l, e2w_l, e2b_l, eng_l, enb_l, ebuf,
                                            epos, WemN, bemN, WeaN, beaN, ec, doEc);
    }
}